// Round 18
// baseline (269.403 us; speedup 1.0000x reference)
//
#include <hip/hip_runtime.h>
#include <math.h>

#define BB 4
#define HH 8
#define TT 4096
#define DD 64
#define NCC 64
#define WSZW 128
#define TPK 160          // widened f32 top-k; f64 rescore picks exact top-128
#define MEMN 1
#define KVW (MEMN + WSZW)   // 129
constexpr float EPSF = 1e-5f;
constexpr float SCALE = 0.125f;  // 64^-0.5

typedef __attribute__((ext_vector_type(8))) short bf16x8;
typedef __attribute__((ext_vector_type(4))) float f32x4;

// HW packed f32->bf16 (RNE), 1 instruction vs ~7 for the manual bit-twiddle
static __device__ __forceinline__ unsigned int pk2(float a, float b) {
    unsigned int r;
    asm("v_cvt_pk_bf16_f32 %0, %1, %2" : "=v"(r) : "v"(a), "v"(b));
    return r;
}
static __device__ __forceinline__ bf16x8 pack8(float4 a, float4 b) {
    union { unsigned int u[4]; bf16x8 v; } r;
    r.u[0] = pk2(a.x, a.y); r.u[1] = pk2(a.z, a.w);
    r.u[2] = pk2(b.x, b.y); r.u[3] = pk2(b.z, b.w);
    return r.v;
}
static __device__ __forceinline__ unsigned mono(float f) {
    unsigned b = __float_as_uint(f);
    return b ^ ((unsigned)(((int)b) >> 31) | 0x80000000u);
}
static __device__ __forceinline__ unsigned long long mono64(double d) {
    unsigned long long b = (unsigned long long)__double_as_longlong(d);
    return b ^ (((long long)b < 0) ? ~0ULL : 0x8000000000000000ULL);
}

// ---------------- Kernel A: dists f32 GEMM + argmax + aux + f64 invnorm ---------
__global__ __launch_bounds__(256, 4) void dists_kernel(
    const float* __restrict__ q, const float* __restrict__ k,
    const float* __restrict__ means,
    float* __restrict__ distsQ, float* __restrict__ distsK,
    float* __restrict__ aux_part, double* __restrict__ invn)
{
    __shared__ float xS[64][68];   // [d][tok]; reused as dS[tok][c] after GEMM
    __shared__ float mS[64][68];   // [d][cluster]
    __shared__ float mqS[64];      // per-cluster ||m||^2

    const int chunks = (2 * TT) / 64;          // 128
    int bid = blockIdx.x;                      // 4096
    int bh = bid / chunks;
    int chunk = bid % chunks;
    int h = bh % HH;
    bool isQ = chunk < (TT / 64);
    int tbase = (isQ ? chunk : chunk - 64) * 64;
    const float* src = (isQ ? q : k) + ((size_t)bh * TT + tbase) * DD;
    float* dst = isQ ? distsQ : distsK;
    double* invdst = invn + (isQ ? 0 : (size_t)BB * HH * TT) + (size_t)bh * TT + tbase;

    int tid = threadIdx.x;
    int tok = tid >> 2, part = tid & 3;        // tok doubles as cluster idx below

    // ---- stage means (transposed) + per-cluster sumsq ----
    {
        const float* mp = means + ((size_t)h * NCC + tok) * DD + part * 16;
        float4 va[4];
        #pragma unroll
        for (int i = 0; i < 4; ++i) va[i] = *(const float4*)(mp + i * 4);
        float msq = 0.f;
        #pragma unroll
        for (int i = 0; i < 4; ++i) {
            msq += va[i].x*va[i].x + va[i].y*va[i].y + va[i].z*va[i].z + va[i].w*va[i].w;
            int d = part * 16 + i * 4;
            mS[d][tok] = va[i].x; mS[d+1][tok] = va[i].y;
            mS[d+2][tok] = va[i].z; mS[d+3][tok] = va[i].w;
        }
        msq += __shfl_xor(msq, 1);
        msq += __shfl_xor(msq, 2);
        if (part == 0) mqS[tok] = msq;
    }
    // ---- stage x normalized (transposed); f64 norm, store invnorm ----
    float ssn;
    {
        const float* xp = src + (size_t)tok * DD + part * 16;
        float4 va[4];
        #pragma unroll
        for (int i = 0; i < 4; ++i) va[i] = *(const float4*)(xp + i * 4);
        double ssd = 0.0;
        #pragma unroll
        for (int i = 0; i < 4; ++i)
            ssd += (double)va[i].x*va[i].x + (double)va[i].y*va[i].y
                 + (double)va[i].z*va[i].z + (double)va[i].w*va[i].w;
        ssd += __shfl_xor(ssd, 1);
        ssd += __shfl_xor(ssd, 2);
        double invd = 1.0 / fmax(sqrt(ssd), 1e-12);
        if (part == 0) invdst[tok] = invd;
        float inv = (float)invd;
        ssn = (float)(ssd * invd * invd);
        #pragma unroll
        for (int i = 0; i < 4; ++i) {
            int d = part * 16 + i * 4;
            xS[d][tok] = va[i].x*inv; xS[d+1][tok] = va[i].y*inv;
            xS[d+2][tok] = va[i].z*inv; xS[d+3][tok] = va[i].w*inv;
        }
    }
    __syncthreads();

    // ---- GEMM: thread = 4 tokens x 4 clusters ----
    int l = tid & 63, w = tid >> 6;
    int ti = l & 15;                 // token tile 4*ti..
    int ci = w * 4 + (l >> 4);       // cluster tile 4*ci..
    float acc[4][4];
    #pragma unroll
    for (int i = 0; i < 4; ++i)
        #pragma unroll
        for (int j = 0; j < 4; ++j) acc[i][j] = 0.f;

    #pragma unroll 16
    for (int kk = 0; kk < 64; ++kk) {
        float4 xv = *(const float4*)(&xS[kk][ti * 4]);
        float4 mv = *(const float4*)(&mS[kk][ci * 4]);
        float xa[4] = {xv.x, xv.y, xv.z, xv.w};
        float ma[4] = {mv.x, mv.y, mv.z, mv.w};
        #pragma unroll
        for (int i = 0; i < 4; ++i)
            #pragma unroll
            for (int j = 0; j < 4; ++j) acc[i][j] += xa[i] * ma[j];
    }

    // ---- store dists to global (coalesced float4 over tokens) ----
    {
        size_t rowb = (size_t)(bh * NCC) * TT;
        #pragma unroll
        for (int j = 0; j < 4; ++j) {
            int c = ci * 4 + j;
            float4 o;
            o.x = acc[0][j]; o.y = acc[1][j]; o.z = acc[2][j]; o.w = acc[3][j];
            *(float4*)&dst[rowb + (size_t)c * TT + tbase + ti * 4] = o;
        }
    }

    // ---- argmax + aux via LDS round-trip (reuse xS as dS[tok][c]) ----
    __syncthreads();
    #pragma unroll
    for (int i = 0; i < 4; ++i)
        #pragma unroll
        for (int j = 0; j < 4; ++j)
            xS[ti * 4 + i][ci * 4 + j] = acc[i][j];
    __syncthreads();

    float bv = -1e30f; int bc = 0;
    #pragma unroll
    for (int j = 0; j < 16; ++j) {
        int c = part * 16 + j;
        float vv = xS[tok][c];
        if (vv > bv) { bv = vv; bc = c; }
    }
    #pragma unroll
    for (int off = 1; off <= 2; off <<= 1) {
        float ov = __shfl_xor(bv, off);
        int   oc = __shfl_xor(bc, off);
        if (ov > bv || (ov == bv && oc < bc)) { bv = ov; bc = oc; }
    }
    float auxv = (part == 0) ? (ssn + mqS[bc] - 2.f * bv) : 0.f;
    #pragma unroll
    for (int off = 32; off; off >>= 1) auxv += __shfl_xor(auxv, off);
    if (l == 0) aux_part[bid * 4 + w] = auxv;
}

// ---------------- Kernel A2: reduce 16384 aux partials -> out[N] ----------------
__global__ __launch_bounds__(256) void aux_reduce_kernel(
    const float* __restrict__ aux_part, float* __restrict__ out)
{
    int t = threadIdx.x;
    float s = 0.f;
    for (int i = t; i < 16384; i += 256) s += aux_part[i];
    #pragma unroll
    for (int off = 32; off; off >>= 1) s += __shfl_xor(s, off);
    __shared__ float wsum[4];
    if ((t & 63) == 0) wsum[t >> 6] = s;
    __syncthreads();
    if (t == 0)
        out[(size_t)BB * HH * TT * DD] =
            (wsum[0] + wsum[1] + wsum[2] + wsum[3]) *
            (1.0f / (float)(BB * HH * 2 * TT * DD));
}

// ---------------- Kernel B: top-TPK per row, 3-pass radix (12/12/8 bits) -------
__global__ __launch_bounds__(256) void topk_kernel(
    const float* __restrict__ dists, int* __restrict__ idxOut)
{
    int row = blockIdx.x;
    const float* dv = dists + (size_t)row * TT;
    int t = threadIdx.x;
    int lane = t & 63, w = t >> 6;

    unsigned u[16];
    #pragma unroll
    for (int j0 = 0; j0 < 4; ++j0) {
        float4 f = *(const float4*)(dv + t * 16 + j0 * 4);
        u[j0*4+0] = mono(f.x); u[j0*4+1] = mono(f.y);
        u[j0*4+2] = mono(f.z); u[j0*4+3] = mono(f.w);
    }

    __shared__ int hist[4096];
    __shared__ int wtot[4];
    __shared__ int binSel, tgtS;
    __shared__ int nGtS, posS, eqPos;

    int target = TPK;
    unsigned prefix = 0;

    // ---- passes 1,2: 12-bit digits over 4096 bins ----
    #pragma unroll
    for (int pass = 0; pass < 2; ++pass) {
        int4* hz = (int4*)&hist[t * 16];
        hz[0] = (int4){0,0,0,0}; hz[1] = (int4){0,0,0,0};
        hz[2] = (int4){0,0,0,0}; hz[3] = (int4){0,0,0,0};
        __syncthreads();
        if (pass == 0) {
            #pragma unroll
            for (int j = 0; j < 16; ++j) atomicAdd(&hist[u[j] >> 20], 1);
        } else {
            #pragma unroll
            for (int j = 0; j < 16; ++j)
                if ((u[j] >> 20) == (prefix >> 20))
                    atomicAdd(&hist[(u[j] >> 8) & 0xFFF], 1);
        }
        __syncthreads();
        int cnt[16], ls[16];
        {
            const int4* hp = (const int4*)&hist[t * 16];
            int4 c0 = hp[0], c1 = hp[1], c2 = hp[2], c3 = hp[3];
            cnt[0]=c0.x; cnt[1]=c0.y; cnt[2]=c0.z; cnt[3]=c0.w;
            cnt[4]=c1.x; cnt[5]=c1.y; cnt[6]=c1.z; cnt[7]=c1.w;
            cnt[8]=c2.x; cnt[9]=c2.y; cnt[10]=c2.z; cnt[11]=c2.w;
            cnt[12]=c3.x; cnt[13]=c3.y; cnt[14]=c3.z; cnt[15]=c3.w;
        }
        int run = 0;
        #pragma unroll
        for (int i = 15; i >= 0; --i) { run += cnt[i]; ls[i] = run; }
        int S = run;
        #pragma unroll
        for (int off = 1; off < 64; off <<= 1) {
            int o = __shfl_down(S, off);
            if (lane + off < 64) S += o;
        }
        if (lane == 0) wtot[w] = S;
        __syncthreads();
        int after = 0;
        for (int ww = w + 1; ww < 4; ++ww) after += wtot[ww];
        int St1 = S - run + after;      // suffix of bins owned by later threads
        #pragma unroll
        for (int i = 0; i < 16; ++i) {
            int sfxb = ls[i] + St1;
            if (sfxb >= target && sfxb - cnt[i] < target) {
                binSel = t * 16 + i; tgtS = target - (sfxb - cnt[i]);
            }
        }
        __syncthreads();
        prefix |= (pass == 0) ? ((unsigned)binSel << 20) : ((unsigned)binSel << 8);
        target = tgtS;
        __syncthreads();
    }

    // ---- pass 3: low 8 bits (256 bins) ----
    hist[t] = 0;
    __syncthreads();
    #pragma unroll
    for (int j = 0; j < 16; ++j)
        if ((u[j] >> 8) == (prefix >> 8))
            atomicAdd(&hist[u[j] & 0xFF], 1);
    __syncthreads();
    {
        int cnt = hist[t];
        int S = cnt;
        #pragma unroll
        for (int off = 1; off < 64; off <<= 1) {
            int o = __shfl_down(S, off);
            if (lane + off < 64) S += o;
        }
        if (lane == 0) wtot[w] = S;
        __syncthreads();
        int after = 0;
        for (int ww = w + 1; ww < 4; ++ww) after += wtot[ww];
        int sfx = S + after;
        if (sfx >= target && sfx - cnt < target) { binSel = t; tgtS = target - (sfx - cnt); }
    }
    __syncthreads();
    unsigned pivot = prefix | (unsigned)binSel;

    // ---- epilogue: compact >pivot, then ==pivot (unordered, capped) ----
    if (t == 0) { nGtS = 0; posS = 0; eqPos = 0; }
    __syncthreads();
    int myg = 0;
    #pragma unroll
    for (int j = 0; j < 16; ++j) myg += (u[j] > pivot) ? 1 : 0;
    if (myg) atomicAdd(&nGtS, myg);
    __syncthreads();
    int n_gt = nGtS;
    int n_need = TPK - n_gt;
    int* out = idxOut + (size_t)row * TPK;
    #pragma unroll
    for (int j = 0; j < 16; ++j) {
        if (u[j] > pivot) {
            int p = atomicAdd(&posS, 1);
            out[p] = t * 16 + j;
        } else if (u[j] == pivot) {
            int p = atomicAdd(&eqPos, 1);
            if (p < n_need) out[n_gt + p] = t * 16 + j;
        }
    }
}

// ---------------- Kernel B2: f64 rescore, u32-key rank, global means ----------
// LDS traffic cut ~2.2x: means read from global (L1-broadcast) + rank loop
// compares 32-bit key prefixes (full 64-bit + token tie-break only on
// hi-equality, exec-masked rare path). XCD-contiguous block remap for L2 reuse
// of the per-bh q/k slices.
__global__ __launch_bounds__(640) void rescore_kernel(
    const float* __restrict__ q, const float* __restrict__ k,
    const float* __restrict__ means, const double* __restrict__ invn,
    const int* __restrict__ candQ, const int* __restrict__ candK,
    int* __restrict__ idxQ, int* __restrict__ idxK,
    int* __restrict__ counts)
{
    int bid = blockIdx.x;
    int rid = (bid & 7) * 512 + (bid >> 3);   // 4096 % 8 == 0 -> bijective
    int side = rid >> 11;            // 0=Q, 1=K
    int row = rid & 2047;            // bh*NC + c
    int c = row & (NCC - 1);
    int bh = row >> 6;
    int h = bh % HH;

    const int* cand = (side ? candK : candQ) + (size_t)row * TPK;
    int* outIdx     = (side ? idxK : idxQ) + (size_t)row * WSZW;
    const float* xbase = (side ? k : q) + (size_t)bh * TT * DD;
    const double* invp = invn + (side ? (size_t)BB * HH * TT : 0) + (size_t)bh * TT;
    const float* mrow = means + ((size_t)h * NCC + c) * DD;

    __shared__ unsigned hiS[TPK];
    __shared__ unsigned loS[TPK];
    __shared__ int      kiS[TPK];

    int tid = threadIdx.x;
    int g = tid >> 2;                // candidate 0..159
    int qt = tid & 3;                // quarter-row 0..3
    int tok = cand[g];
    const float* xp = xbase + (size_t)tok * DD + qt * 16;
    const float* mp = mrow + qt * 16;
    double inv = invp[tok];          // 4 lanes same addr -> broadcast
    double d0 = 0.0, d1 = 0.0;
    #pragma unroll
    for (int i = 0; i < 2; ++i) {
        float4 va = *(const float4*)(xp + i * 4);
        float4 ma = *(const float4*)(mp + i * 4);
        d0 += (double)va.x * (double)ma.x + (double)va.y * (double)ma.y
            + (double)va.z * (double)ma.z + (double)va.w * (double)ma.w;
    }
    #pragma unroll
    for (int i = 2; i < 4; ++i) {
        float4 va = *(const float4*)(xp + i * 4);
        float4 ma = *(const float4*)(mp + i * 4);
        d1 += (double)va.x * (double)ma.x + (double)va.y * (double)ma.y
            + (double)va.z * (double)ma.z + (double)va.w * (double)ma.w;
    }
    double dot = d0 + d1;
    dot += __shfl_xor(dot, 1); dot += __shfl_xor(dot, 2);
    double v = dot * inv;            // identical across the 4-lane group
    unsigned long long key = mono64(v);
    unsigned myhi = (unsigned)(key >> 32), mylo = (unsigned)key;
    if (qt == 0) { hiS[g] = myhi; loS[g] = mylo; kiS[g] = tok; }
    __syncthreads();

    // rank: lane qt counts its 40-candidate quarter on 32-bit keys
    int rk = 0;
    #pragma unroll 8
    for (int i = 0; i < TPK / 4; ++i) {
        int j = qt * (TPK / 4) + i;
        unsigned hj = hiS[j];
        if (hj > myhi) {
            rk++;
        } else if (hj == myhi) {          // rare: resolve with lo + token
            unsigned lj = loS[j];
            if (lj > mylo || (lj == mylo && kiS[j] < tok)) rk++;
        }
    }
    rk += __shfl_xor(rk, 1); rk += __shfl_xor(rk, 2);

    if (qt == 0 && rk < WSZW) {
        outIdx[rk] = tok;
        if (side == 0) atomicAdd(&counts[bh * TT + tok], 1);
    }
}

// ---------------- Kernel C: bf16 MFMA attention, chase-free batched staging ----
__global__ __launch_bounds__(512, 2) void attn_kernel(
    const float* __restrict__ q, const float* __restrict__ k, const float* __restrict__ v,
    const float* __restrict__ mem_key, const float* __restrict__ mem_value,
    const int* __restrict__ idxQ, const int* __restrict__ idxK,
    float* __restrict__ so)
{
    // XCD-bijective swizzle (2048 % 8 == 0): 256 consecutive blks per XCD
    int bid = blockIdx.x;
    int blk = (bid & 7) * 256 + (bid >> 3);
    int c = blk % NCC;
    int bh = blk / NCC;
    int h = bh % HH;

    __shared__ __align__(16) unsigned short KsS[160 * 64];   // [kv][d] swizzled (temp V in P1/P2)
    __shared__ __align__(16) unsigned short VtS[64 * 168];   // [d][kv], pad 168

    int tid = threadIdx.x;
    int w = tid >> 6, l = tid & 63;
    int lr = l & 15, lg = l >> 4;

    const float* memK = mem_key   + ((size_t)h * NCC + c) * (MEMN * DD);
    const float* memV = mem_value + ((size_t)h * NCC + c) * (MEMN * DD);

    // ---- entry: resolve staging rows + issue ALL token-index gathers ----
    int stRow[3], stCh[3];
    bool stOk[3];
    const float *vsrcR[3], *ksrcR[3];
    #pragma unroll
    for (int s = 0; s < 3; ++s) {
        int idx = tid + s * 512;
        stOk[s] = idx < 1280;
        stRow[s] = idx >> 3; stCh[s] = idx & 7;
        vsrcR[s] = nullptr; ksrcR[s] = nullptr;
        if (stOk[s] && stRow[s] < KVW) {
            if (stRow[s] == 0) { vsrcR[s] = memV; ksrcR[s] = memK; }
            else {
                int tk = idxK[(size_t)blk * WSZW + stRow[s] - 1];
                vsrcR[s] = v + ((size_t)bh * TT + tk) * DD;
                ksrcR[s] = k + ((size_t)bh * TT + tk) * DD;
            }
        }
    }

    // ---- Q frags (independent chase, overlaps everything) ----
    bf16x8 qf[2];
    {
        int tq = idxQ[(size_t)blk * WSZW + w * 16 + lr];
        const float* qp = q + ((size_t)bh * TT + tq) * DD;
        #pragma unroll
        for (int ks = 0; ks < 2; ++ks) {
            float4 a = *(const float4*)(qp + ks * 32 + lg * 8);
            float4 b = *(const float4*)(qp + ks * 32 + lg * 8 + 4);
            qf[ks] = pack8(a, b);
        }
    }

    // ---- V gather window (batched) ----
    uint4 vw[3];
    #pragma unroll
    for (int s = 0; s < 3; ++s) {
        vw[s] = (uint4){0,0,0,0};
        if (vsrcR[s]) {
            float4 a = *(const float4*)(vsrcR[s] + stCh[s] * 8);
            float4 b = *(const float4*)(vsrcR[s] + stCh[s] * 8 + 4);
            vw[s].x = pk2(a.x, a.y); vw[s].y = pk2(a.z, a.w);
            vw[s].z = pk2(b.x, b.y); vw[s].w = pk2(b.z, b.w);
        }
    }
    // ---- K gather window (batched) ----
    uint4 kw[3];
    #pragma unroll
    for (int s = 0; s < 3; ++s) {
        kw[s] = (uint4){0,0,0,0};
        if (ksrcR[s]) {
            float4 a = *(const float4*)(ksrcR[s] + stCh[s] * 8);
            float4 b = *(const float4*)(ksrcR[s] + stCh[s] * 8 + 4);
            kw[s].x = pk2(a.x, a.y); kw[s].y = pk2(a.z, a.w);
            kw[s].z = pk2(b.x, b.y); kw[s].w = pk2(b.z, b.w);
        }
    }

    // ---- P1: V -> row-major swizzled (in KsS space) ----
    #pragma unroll
    for (int s = 0; s < 3; ++s)
        if (stOk[s])
            *reinterpret_cast<uint4*>(
                &KsS[stRow[s] * 64 + ((stCh[s] ^ (stRow[s] & 7)) * 8)]) = vw[s];
    __syncthreads();

    // ---- P2: Vt column segments -> regs (scalar broadcast-class reads) ----
    unsigned short vreg[3][8];
    #pragma unroll
    for (int s = 0; s < 3; ++s) {
        int idx = tid + s * 512;
        if (idx < 1280) {
            int d = idx & 63, rowblk = idx >> 6;
            #pragma unroll
            for (int i = 0; i < 8; ++i) {
                int row = rowblk * 8 + i;
                vreg[s][i] = KsS[row * 64 + (((d >> 3) ^ (row & 7)) * 8) + (d & 7)];
            }
        }
    }
    __syncthreads();

    // ---- P3: write Vt (b128 rows) + K (b128 swizzled) ----
    #pragma unroll
    for (int s = 0; s < 3; ++s) {
        int idx = tid + s * 512;
        if (idx < 1280) {
            int d = idx & 63, rowblk = idx >> 6;
            uint4 ow;
            ow.x = (unsigned)vreg[s][0] | ((unsigned)vreg[s][1] << 16);
            ow.y = (unsigned)vreg[s][2] | ((unsigned)vreg[s][3] << 16);
            ow.z = (unsigned)vreg[s][4] | ((unsigned)vreg[s][5] << 16);
            ow.w = (unsigned)vreg[s][6] | ((unsigned)vreg[s][7] << 16);
            *reinterpret_cast<uint4*>(&VtS[d * 168 + rowblk * 8]) = ow;
        }
    }
    #pragma unroll
    for (int s = 0; s < 3; ++s)
        if (stOk[s])
            *reinterpret_cast<uint4*>(
                &KsS[stRow[s] * 64 + ((stCh[s] ^ (stRow[s] & 7)) * 8)]) = kw[s];
    __syncthreads();

    // ---- compute (swapped QK^T, P in regs, Vt b128 B-frags) ----
    f32x4 acc[4];
    #pragma unroll
    for (int dt = 0; dt < 4; ++dt) acc[dt] = (f32x4){0.f, 0.f, 0.f, 0.f};
    float s_sum = 0.f;

    int src0 = lr + ((lg & 1) * 2) * 16;
    int src1 = src0 + 16;
    bool hi = (lg >> 1) != 0;

    for (int kb = 0; kb < 5; ++kb) {
        bf16x8 kf[2][2];
        #pragma unroll
        for (int kvt = 0; kvt < 2; ++kvt)
            #pragma unroll
            for (int ks = 0; ks < 2; ++ks) {
                int row = kb * 32 + kvt * 16 + lr;
                int chunk = ks * 4 + lg;
                int phys = chunk ^ (row & 7);
                kf[kvt][ks] = *reinterpret_cast<const bf16x8*>(&KsS[row * 64 + phys * 8]);
            }
        __builtin_amdgcn_s_setprio(1);
        unsigned pk[2][2];
        #pragma unroll
        for (int kvt = 0; kvt < 2; ++kvt) {
            f32x4 sf = __builtin_amdgcn_mfma_f32_16x16x32_bf16(
                kf[kvt][0], qf[0], (f32x4){0.f,0.f,0.f,0.f}, 0, 0, 0);
            sf = __builtin_amdgcn_mfma_f32_16x16x32_bf16(kf[kvt][1], qf[1], sf, 0, 0, 0);
            float e[4];
            #pragma unroll
            for (int r = 0; r < 4; ++r) {
                int kv = kb * 32 + kvt * 16 + lg * 4 + r;
                e[r] = (kv < KVW) ? __expf(sf[r] * SCALE) : 0.f;
                s_sum += e[r];
            }
            pk[kvt][0] = pk2(e[0], e[1]);
            pk[kvt][1] = pk2(e[2], e[3]);
        }
        unsigned a00 = __shfl(pk[0][0], src0), a01 = __shfl(pk[0][1], src0);
        unsigned a10 = __shfl(pk[1][0], src0), a11 = __shfl(pk[1][1], src0);
        unsigned b00 = __shfl(pk[0][0], src1), b01 = __shfl(pk[0][1], src1);
        unsigned b10 = __shfl(pk[1][0], src1), b11 = __shfl(pk[1][1], src1);
        union { unsigned u[4]; bf16x8 v; } pu;
        pu.u[0] = hi ? a10 : a00;
        pu.u[1] = hi ? a11 : a01;
        pu.u[2] = hi ? b10 : b00;
        pu.u[3] = hi ? b11 : b01;
        #pragma unroll
        for (int dt = 0; dt < 4; ++dt) {
            bf16x8 vf = *reinterpret_cast<const bf16x8*>(
                &VtS[(dt * 16 + lr) * 168 + kb * 32 + lg * 8]);
            acc[dt] = __builtin_amdgcn_mfma_f32_16x16x32_bf16(pu.v, vf, acc[dt], 0, 0, 0);
        }
        __builtin_amdgcn_s_setprio(0);
    }

    s_sum += __shfl_xor(s_sum, 16);
    s_sum += __shfl_xor(s_sum, 32);
    float sinv[4];
    #pragma unroll
    for (int r = 0; r < 4; ++r)
        sinv[r] = 1.f / __shfl(s_sum, lg * 4 + r);

    #pragma unroll
    for (int r = 0; r < 4; ++r) {
        int row = w * 16 + lg * 4 + r;
        float* op = so + (((size_t)blk * WSZW + row) * DD);
        #pragma unroll
        for (int dt = 0; dt < 4; ++dt)
            op[dt * 16 + lr] = acc[dt][r] * sinv[r];
    }
}

// ---------------- Kernel F: per-bh exclusive scan (4096 ints) ----------------
__global__ __launch_bounds__(256) void scan_kernel(
    const int* __restrict__ counts, int* __restrict__ offs)
{
    int bh = blockIdx.x;
    int t = threadIdx.x;
    const int* cb = counts + (size_t)bh * TT;
    int* ob = offs + (size_t)bh * TT;

    int loc[16]; int sum = 0;
    #pragma unroll
    for (int i = 0; i < 16; ++i) { loc[i] = sum; sum += cb[t * 16 + i]; }

    __shared__ int wsum[256];
    wsum[t] = sum;
    __syncthreads();
    for (int off = 1; off < 256; off <<= 1) {
        int vv = (t >= off) ? wsum[t - off] : 0;
        __syncthreads();
        wsum[t] += vv;
        __syncthreads();
    }
    int ex = (t == 0) ? 0 : wsum[t - 1];
    #pragma unroll
    for (int i = 0; i < 16; ++i) ob[t * 16 + i] = ex + loc[i];
}

// ---------------- Kernel G: fill CSR slot lists ----------------
__global__ __launch_bounds__(256) void fill_kernel(
    const int* __restrict__ idxQ, const int* __restrict__ offs,
    int* __restrict__ cur, int* __restrict__ csr)
{
    int i = blockIdx.x * 256 + threadIdx.x;
    int bh = i >> 13;
    int within = i & 8191;
    int tok = idxQ[i];
    int p = offs[bh * TT + tok] + atomicAdd(&cur[bh * TT + tok], 1);
    csr[((size_t)bh << 13) + p] = within;
}

// ---------------- Kernel H: gather-reduce + finalize ----------------
__global__ __launch_bounds__(256) void reduce_kernel(
    const float* __restrict__ so, const int* __restrict__ counts,
    const int* __restrict__ offs, const int* __restrict__ csr,
    float* __restrict__ out)
{
    int gt = blockIdx.x * 4 + (threadIdx.x >> 6);
    int lane = threadIdx.x & 63;
    int bh = gt >> 12;
    int n = counts[gt];
    int st = offs[gt];
    const int* cs = csr + ((size_t)bh << 13);
    float acc = 0.f;
    for (int j = 0; j < n; ++j) {
        int slot = cs[st + j];
        acc += so[(((size_t)bh << 13) + slot) * DD + lane];
    }
    out[(size_t)gt * DD + lane] = acc / ((float)n + EPSF);
}

extern "C" void kernel_launch(void* const* d_in, const int* in_sizes, int n_in,
                              void* d_out, int out_size, void* d_ws, size_t ws_size,
                              hipStream_t stream) {
    const float* q        = (const float*)d_in[0];
    const float* k        = (const float*)d_in[1];
    const float* v        = (const float*)d_in[2];
    const float* means    = (const float*)d_in[3];
    const float* mem_key  = (const float*)d_in[4];
    const float* mem_val  = (const float*)d_in[5];
    float* out = (float*)d_out;

    const size_t nRows = (size_t)BB * HH * NCC;             // 2048
    const size_t nTok  = (size_t)BB * HH * TT;              // 131072
    float* wsf    = (float*)d_ws;
    float* distsQ = wsf;                                    // 8388608 f
    float* distsK = distsQ + (size_t)BB * HH * NCC * TT;    // 8388608 f (contiguous after distsQ)
    float* so     = wsf;                                    // aliases dists; written after rescore
    int*   idxQ   = (int*)(distsK + (size_t)BB * HH * NCC * TT);  // 262144 i
    int*   idxK   = idxQ + nRows * WSZW;                    // 262144 i
    int*   counts = idxK + nRows * WSZW;                    // 131072 i
    int*   cur    = counts + nTok;                          // 131072 i
    float* auxp   = (float*)(cur + nTok);                   // 16384 f (per-wave partials)
    int*   offs   = (int*)(auxp + 16384);                   // 131072 i
    int*   csr    = offs + nTok;                            // 262144 i
    int*   candQ  = csr + nTok * 2;                         // 2048*160 i
    int*   candK  = candQ + nRows * TPK;                    // 2048*160 i (contiguous after candQ)
    uintptr_t ip  = (uintptr_t)(candK + nRows * TPK);
    ip = (ip + 15) & ~(uintptr_t)15;
    double* invn  = (double*)ip;                            // 2*131072 d (Q then K)

    hipMemsetAsync(counts, 0, 2 * nTok * sizeof(int), stream);

    dists_kernel<<<dim3(BB * HH * (2 * TT / 64)), dim3(256), 0, stream>>>(
        q, k, means, distsQ, distsK, auxp, invn);
    aux_reduce_kernel<<<dim3(1), dim3(256), 0, stream>>>(auxp, out);
    // single launch covers Q rows (0..2047 over distsQ/candQ) and K rows
    // (2048..4095 over distsK/candK) via buffer contiguity
    topk_kernel<<<dim3((unsigned)(2 * nRows)), dim3(256), 0, stream>>>(distsQ, candQ);
    rescore_kernel<<<dim3((unsigned)(2 * nRows)), dim3(640), 0, stream>>>(
        q, k, means, invn, candQ, candK, idxQ, idxK, counts);
    scan_kernel<<<dim3(BB * HH), dim3(256), 0, stream>>>(counts, offs);
    fill_kernel<<<dim3(1024), dim3(256), 0, stream>>>(idxQ, offs, cur, csr);
    attn_kernel<<<dim3((unsigned)nRows), dim3(512), 0, stream>>>(
        q, k, v, mem_key, mem_val, idxQ, idxK, so);
    reduce_kernel<<<dim3((unsigned)(nTok / 4)), dim3(256), 0, stream>>>(
        so, counts, offs, csr, out);
}

// Round 19
// 240.228 us; speedup vs baseline: 1.1214x; 1.1214x over previous
//
#include <hip/hip_runtime.h>
#include <math.h>

#define BB 4
#define HH 8
#define TT 4096
#define DD 64
#define NCC 64
#define WSZW 128
#define TPK 160          // widened f32 top-k; f64 rescore picks exact top-128
#define MEMN 1
#define KVW (MEMN + WSZW)   // 129
constexpr float EPSF = 1e-5f;
constexpr float SCALE = 0.125f;  // 64^-0.5

typedef __attribute__((ext_vector_type(8))) short bf16x8;
typedef __attribute__((ext_vector_type(4))) float f32x4;

// HW packed f32->bf16 (RNE), 1 instruction vs ~7 for the manual bit-twiddle
static __device__ __forceinline__ unsigned int pk2(float a, float b) {
    unsigned int r;
    asm("v_cvt_pk_bf16_f32 %0, %1, %2" : "=v"(r) : "v"(a), "v"(b));
    return r;
}
static __device__ __forceinline__ bf16x8 pack8(float4 a, float4 b) {
    union { unsigned int u[4]; bf16x8 v; } r;
    r.u[0] = pk2(a.x, a.y); r.u[1] = pk2(a.z, a.w);
    r.u[2] = pk2(b.x, b.y); r.u[3] = pk2(b.z, b.w);
    return r.v;
}
static __device__ __forceinline__ unsigned mono(float f) {
    unsigned b = __float_as_uint(f);
    return b ^ ((unsigned)(((int)b) >> 31) | 0x80000000u);
}
static __device__ __forceinline__ unsigned long long mono64(double d) {
    unsigned long long b = (unsigned long long)__double_as_longlong(d);
    return b ^ (((long long)b < 0) ? ~0ULL : 0x8000000000000000ULL);
}

// ---------------- Kernel A: dists f32 GEMM + argmax + aux + f64 invnorm ---------
__global__ __launch_bounds__(256, 4) void dists_kernel(
    const float* __restrict__ q, const float* __restrict__ k,
    const float* __restrict__ means,
    float* __restrict__ distsQ, float* __restrict__ distsK,
    float* __restrict__ aux_part, double* __restrict__ invn)
{
    __shared__ float xS[64][68];   // [d][tok]; reused as dS[tok][c] after GEMM
    __shared__ float mS[64][68];   // [d][cluster]
    __shared__ float mqS[64];      // per-cluster ||m||^2

    const int chunks = (2 * TT) / 64;          // 128
    int bid = blockIdx.x;                      // 4096
    int bh = bid / chunks;
    int chunk = bid % chunks;
    int h = bh % HH;
    bool isQ = chunk < (TT / 64);
    int tbase = (isQ ? chunk : chunk - 64) * 64;
    const float* src = (isQ ? q : k) + ((size_t)bh * TT + tbase) * DD;
    float* dst = isQ ? distsQ : distsK;
    double* invdst = invn + (isQ ? 0 : (size_t)BB * HH * TT) + (size_t)bh * TT + tbase;

    int tid = threadIdx.x;
    int tok = tid >> 2, part = tid & 3;        // tok doubles as cluster idx below

    // ---- stage means (transposed) + per-cluster sumsq ----
    {
        const float* mp = means + ((size_t)h * NCC + tok) * DD + part * 16;
        float4 va[4];
        #pragma unroll
        for (int i = 0; i < 4; ++i) va[i] = *(const float4*)(mp + i * 4);
        float msq = 0.f;
        #pragma unroll
        for (int i = 0; i < 4; ++i) {
            msq += va[i].x*va[i].x + va[i].y*va[i].y + va[i].z*va[i].z + va[i].w*va[i].w;
            int d = part * 16 + i * 4;
            mS[d][tok] = va[i].x; mS[d+1][tok] = va[i].y;
            mS[d+2][tok] = va[i].z; mS[d+3][tok] = va[i].w;
        }
        msq += __shfl_xor(msq, 1);
        msq += __shfl_xor(msq, 2);
        if (part == 0) mqS[tok] = msq;
    }
    // ---- stage x normalized (transposed); f64 norm, store invnorm ----
    float ssn;
    {
        const float* xp = src + (size_t)tok * DD + part * 16;
        float4 va[4];
        #pragma unroll
        for (int i = 0; i < 4; ++i) va[i] = *(const float4*)(xp + i * 4);
        double ssd = 0.0;
        #pragma unroll
        for (int i = 0; i < 4; ++i)
            ssd += (double)va[i].x*va[i].x + (double)va[i].y*va[i].y
                 + (double)va[i].z*va[i].z + (double)va[i].w*va[i].w;
        ssd += __shfl_xor(ssd, 1);
        ssd += __shfl_xor(ssd, 2);
        double invd = 1.0 / fmax(sqrt(ssd), 1e-12);
        if (part == 0) invdst[tok] = invd;
        float inv = (float)invd;
        ssn = (float)(ssd * invd * invd);
        #pragma unroll
        for (int i = 0; i < 4; ++i) {
            int d = part * 16 + i * 4;
            xS[d][tok] = va[i].x*inv; xS[d+1][tok] = va[i].y*inv;
            xS[d+2][tok] = va[i].z*inv; xS[d+3][tok] = va[i].w*inv;
        }
    }
    __syncthreads();

    // ---- GEMM: thread = 4 tokens x 4 clusters ----
    int l = tid & 63, w = tid >> 6;
    int ti = l & 15;                 // token tile 4*ti..
    int ci = w * 4 + (l >> 4);       // cluster tile 4*ci..
    float acc[4][4];
    #pragma unroll
    for (int i = 0; i < 4; ++i)
        #pragma unroll
        for (int j = 0; j < 4; ++j) acc[i][j] = 0.f;

    #pragma unroll 16
    for (int kk = 0; kk < 64; ++kk) {
        float4 xv = *(const float4*)(&xS[kk][ti * 4]);
        float4 mv = *(const float4*)(&mS[kk][ci * 4]);
        float xa[4] = {xv.x, xv.y, xv.z, xv.w};
        float ma[4] = {mv.x, mv.y, mv.z, mv.w};
        #pragma unroll
        for (int i = 0; i < 4; ++i)
            #pragma unroll
            for (int j = 0; j < 4; ++j) acc[i][j] += xa[i] * ma[j];
    }

    // ---- store dists to global (coalesced float4 over tokens) ----
    {
        size_t rowb = (size_t)(bh * NCC) * TT;
        #pragma unroll
        for (int j = 0; j < 4; ++j) {
            int c = ci * 4 + j;
            float4 o;
            o.x = acc[0][j]; o.y = acc[1][j]; o.z = acc[2][j]; o.w = acc[3][j];
            *(float4*)&dst[rowb + (size_t)c * TT + tbase + ti * 4] = o;
        }
    }

    // ---- argmax + aux via LDS round-trip (reuse xS as dS[tok][c]) ----
    __syncthreads();
    #pragma unroll
    for (int i = 0; i < 4; ++i)
        #pragma unroll
        for (int j = 0; j < 4; ++j)
            xS[ti * 4 + i][ci * 4 + j] = acc[i][j];
    __syncthreads();

    float bv = -1e30f; int bc = 0;
    #pragma unroll
    for (int j = 0; j < 16; ++j) {
        int c = part * 16 + j;
        float vv = xS[tok][c];
        if (vv > bv) { bv = vv; bc = c; }
    }
    #pragma unroll
    for (int off = 1; off <= 2; off <<= 1) {
        float ov = __shfl_xor(bv, off);
        int   oc = __shfl_xor(bc, off);
        if (ov > bv || (ov == bv && oc < bc)) { bv = ov; bc = oc; }
    }
    float auxv = (part == 0) ? (ssn + mqS[bc] - 2.f * bv) : 0.f;
    #pragma unroll
    for (int off = 32; off; off >>= 1) auxv += __shfl_xor(auxv, off);
    if (l == 0) aux_part[bid * 4 + w] = auxv;
}

// ---------------- Kernel A2: reduce 16384 aux partials -> out[N] ----------------
__global__ __launch_bounds__(256) void aux_reduce_kernel(
    const float* __restrict__ aux_part, float* __restrict__ out)
{
    int t = threadIdx.x;
    float s = 0.f;
    for (int i = t; i < 16384; i += 256) s += aux_part[i];
    #pragma unroll
    for (int off = 32; off; off >>= 1) s += __shfl_xor(s, off);
    __shared__ float wsum[4];
    if ((t & 63) == 0) wsum[t >> 6] = s;
    __syncthreads();
    if (t == 0)
        out[(size_t)BB * HH * TT * DD] =
            (wsum[0] + wsum[1] + wsum[2] + wsum[3]) *
            (1.0f / (float)(BB * HH * 2 * TT * DD));
}

// ---------------- Kernel B: top-TPK per row, 3-pass radix (12/12/8 bits) -------
__global__ __launch_bounds__(256) void topk_kernel(
    const float* __restrict__ dists, int* __restrict__ idxOut)
{
    int row = blockIdx.x;
    const float* dv = dists + (size_t)row * TT;
    int t = threadIdx.x;
    int lane = t & 63, w = t >> 6;

    unsigned u[16];
    #pragma unroll
    for (int j0 = 0; j0 < 4; ++j0) {
        float4 f = *(const float4*)(dv + t * 16 + j0 * 4);
        u[j0*4+0] = mono(f.x); u[j0*4+1] = mono(f.y);
        u[j0*4+2] = mono(f.z); u[j0*4+3] = mono(f.w);
    }

    __shared__ int hist[4096];
    __shared__ int wtot[4];
    __shared__ int binSel, tgtS;
    __shared__ int nGtS, posS, eqPos;

    int target = TPK;
    unsigned prefix = 0;

    // ---- passes 1,2: 12-bit digits over 4096 bins ----
    #pragma unroll
    for (int pass = 0; pass < 2; ++pass) {
        int4* hz = (int4*)&hist[t * 16];
        hz[0] = (int4){0,0,0,0}; hz[1] = (int4){0,0,0,0};
        hz[2] = (int4){0,0,0,0}; hz[3] = (int4){0,0,0,0};
        __syncthreads();
        if (pass == 0) {
            #pragma unroll
            for (int j = 0; j < 16; ++j) atomicAdd(&hist[u[j] >> 20], 1);
        } else {
            #pragma unroll
            for (int j = 0; j < 16; ++j)
                if ((u[j] >> 20) == (prefix >> 20))
                    atomicAdd(&hist[(u[j] >> 8) & 0xFFF], 1);
        }
        __syncthreads();
        int cnt[16], ls[16];
        {
            const int4* hp = (const int4*)&hist[t * 16];
            int4 c0 = hp[0], c1 = hp[1], c2 = hp[2], c3 = hp[3];
            cnt[0]=c0.x; cnt[1]=c0.y; cnt[2]=c0.z; cnt[3]=c0.w;
            cnt[4]=c1.x; cnt[5]=c1.y; cnt[6]=c1.z; cnt[7]=c1.w;
            cnt[8]=c2.x; cnt[9]=c2.y; cnt[10]=c2.z; cnt[11]=c2.w;
            cnt[12]=c3.x; cnt[13]=c3.y; cnt[14]=c3.z; cnt[15]=c3.w;
        }
        int run = 0;
        #pragma unroll
        for (int i = 15; i >= 0; --i) { run += cnt[i]; ls[i] = run; }
        int S = run;
        #pragma unroll
        for (int off = 1; off < 64; off <<= 1) {
            int o = __shfl_down(S, off);
            if (lane + off < 64) S += o;
        }
        if (lane == 0) wtot[w] = S;
        __syncthreads();
        int after = 0;
        for (int ww = w + 1; ww < 4; ++ww) after += wtot[ww];
        int St1 = S - run + after;      // suffix of bins owned by later threads
        #pragma unroll
        for (int i = 0; i < 16; ++i) {
            int sfxb = ls[i] + St1;
            if (sfxb >= target && sfxb - cnt[i] < target) {
                binSel = t * 16 + i; tgtS = target - (sfxb - cnt[i]);
            }
        }
        __syncthreads();
        prefix |= (pass == 0) ? ((unsigned)binSel << 20) : ((unsigned)binSel << 8);
        target = tgtS;
        __syncthreads();
    }

    // ---- pass 3: low 8 bits (256 bins) ----
    hist[t] = 0;
    __syncthreads();
    #pragma unroll
    for (int j = 0; j < 16; ++j)
        if ((u[j] >> 8) == (prefix >> 8))
            atomicAdd(&hist[u[j] & 0xFF], 1);
    __syncthreads();
    {
        int cnt = hist[t];
        int S = cnt;
        #pragma unroll
        for (int off = 1; off < 64; off <<= 1) {
            int o = __shfl_down(S, off);
            if (lane + off < 64) S += o;
        }
        if (lane == 0) wtot[w] = S;
        __syncthreads();
        int after = 0;
        for (int ww = w + 1; ww < 4; ++ww) after += wtot[ww];
        int sfx = S + after;
        if (sfx >= target && sfx - cnt < target) { binSel = t; tgtS = target - (sfx - cnt); }
    }
    __syncthreads();
    unsigned pivot = prefix | (unsigned)binSel;

    // ---- epilogue: compact >pivot, then ==pivot (unordered, capped) ----
    if (t == 0) { nGtS = 0; posS = 0; eqPos = 0; }
    __syncthreads();
    int myg = 0;
    #pragma unroll
    for (int j = 0; j < 16; ++j) myg += (u[j] > pivot) ? 1 : 0;
    if (myg) atomicAdd(&nGtS, myg);
    __syncthreads();
    int n_gt = nGtS;
    int n_need = TPK - n_gt;
    int* out = idxOut + (size_t)row * TPK;
    #pragma unroll
    for (int j = 0; j < 16; ++j) {
        if (u[j] > pivot) {
            int p = atomicAdd(&posS, 1);
            out[p] = t * 16 + j;
        } else if (u[j] == pivot) {
            int p = atomicAdd(&eqPos, 1);
            if (p < n_need) out[n_gt + p] = t * 16 + j;
        }
    }
}

// ---------------- Kernel B2: f64 rescore, branchless u32-prefix rank ----------
// Keeps r18's wins (XCD remap, direct outIdx[rank] write) and reverts its
// losses (means back in LDS f64). Rank loop phase 1: 1x b32 LDS read/iter,
// branchless (rk: hi>myhi, eq: hi==myhi). Self always matches -> eq==1 means
// hi resolves all comparisons. Rare eq>1 falls back to exact 64-bit+token.
__global__ __launch_bounds__(640) void rescore_kernel(
    const float* __restrict__ q, const float* __restrict__ k,
    const float* __restrict__ means, const double* __restrict__ invn,
    const int* __restrict__ candQ, const int* __restrict__ candK,
    int* __restrict__ idxQ, int* __restrict__ idxK,
    int* __restrict__ counts)
{
    int bid = blockIdx.x;
    int rid = (bid & 7) * 512 + (bid >> 3);   // 4096 % 8 == 0 -> bijective
    int side = rid >> 11;            // 0=Q, 1=K
    int row = rid & 2047;            // bh*NC + c
    int c = row & (NCC - 1);
    int bh = row >> 6;
    int h = bh % HH;

    const int* cand = (side ? candK : candQ) + (size_t)row * TPK;
    int* outIdx     = (side ? idxK : idxQ) + (size_t)row * WSZW;
    const float* xbase = (side ? k : q) + (size_t)bh * TT * DD;
    const double* invp = invn + (side ? (size_t)BB * HH * TT : 0) + (size_t)bh * TT;

    __shared__ double   mD[DD];
    __shared__ unsigned hiS[TPK];
    __shared__ unsigned loS[TPK];
    __shared__ int      kiS[TPK];

    int tid = threadIdx.x;
    if (tid < DD) mD[tid] = (double)means[((size_t)h * NCC + c) * DD + tid];
    __syncthreads();

    int g = tid >> 2;                // candidate 0..159
    int qt = tid & 3;                // quarter-row 0..3
    int tok = cand[g];
    const float* xp = xbase + (size_t)tok * DD + qt * 16;
    double inv = invp[tok];          // 4 lanes same addr -> broadcast
    double d0 = 0.0, d1 = 0.0;
    #pragma unroll
    for (int i = 0; i < 2; ++i) {
        float4 va = *(const float4*)(xp + i * 4);
        int d = qt * 16 + i * 4;
        d0 += (double)va.x * mD[d]   + (double)va.y * mD[d+1]
            + (double)va.z * mD[d+2] + (double)va.w * mD[d+3];
    }
    #pragma unroll
    for (int i = 2; i < 4; ++i) {
        float4 va = *(const float4*)(xp + i * 4);
        int d = qt * 16 + i * 4;
        d1 += (double)va.x * mD[d]   + (double)va.y * mD[d+1]
            + (double)va.z * mD[d+2] + (double)va.w * mD[d+3];
    }
    double dot = d0 + d1;
    dot += __shfl_xor(dot, 1); dot += __shfl_xor(dot, 2);
    double v = dot * inv;            // identical across the 4-lane group
    unsigned long long key = mono64(v);
    unsigned myhi = (unsigned)(key >> 32), mylo = (unsigned)key;
    if (qt == 0) { hiS[g] = myhi; loS[g] = mylo; kiS[g] = tok; }
    __syncthreads();

    // phase 1: branchless rank on 32-bit prefixes (1 LDS b32 read per iter)
    int rk = 0, eq = 0;
    #pragma unroll 8
    for (int i = 0; i < TPK / 4; ++i) {
        unsigned hj = hiS[qt * (TPK / 4) + i];
        rk += (hj > myhi) ? 1 : 0;
        eq += (hj == myhi) ? 1 : 0;
    }
    rk += __shfl_xor(rk, 1); rk += __shfl_xor(rk, 2);
    eq += __shfl_xor(eq, 1); eq += __shfl_xor(eq, 2);

    // phase 2 (rare): exact 64-bit + token recount when hi-prefix ties exist
    if (eq > 1) {
        int rk2 = 0;
        for (int i = 0; i < TPK / 4; ++i) {
            int j = qt * (TPK / 4) + i;
            unsigned hj = hiS[j];
            if (hj > myhi) rk2++;
            else if (hj == myhi) {
                unsigned lj = loS[j];
                if (lj > mylo || (lj == mylo && kiS[j] < tok)) rk2++;
            }
        }
        rk2 += __shfl_xor(rk2, 1); rk2 += __shfl_xor(rk2, 2);
        rk = rk2;
    }

    if (qt == 0 && rk < WSZW) {
        outIdx[rk] = tok;
        if (side == 0) atomicAdd(&counts[bh * TT + tok], 1);
    }
}

// ---------------- Kernel C: bf16 MFMA attention, chase-free batched staging ----
__global__ __launch_bounds__(512, 2) void attn_kernel(
    const float* __restrict__ q, const float* __restrict__ k, const float* __restrict__ v,
    const float* __restrict__ mem_key, const float* __restrict__ mem_value,
    const int* __restrict__ idxQ, const int* __restrict__ idxK,
    float* __restrict__ so)
{
    // XCD-bijective swizzle (2048 % 8 == 0): 256 consecutive blks per XCD
    int bid = blockIdx.x;
    int blk = (bid & 7) * 256 + (bid >> 3);
    int c = blk % NCC;
    int bh = blk / NCC;
    int h = bh % HH;

    __shared__ __align__(16) unsigned short KsS[160 * 64];   // [kv][d] swizzled (temp V in P1/P2)
    __shared__ __align__(16) unsigned short VtS[64 * 168];   // [d][kv], pad 168

    int tid = threadIdx.x;
    int w = tid >> 6, l = tid & 63;
    int lr = l & 15, lg = l >> 4;

    const float* memK = mem_key   + ((size_t)h * NCC + c) * (MEMN * DD);
    const float* memV = mem_value + ((size_t)h * NCC + c) * (MEMN * DD);

    // ---- entry: resolve staging rows + issue ALL token-index gathers ----
    int stRow[3], stCh[3];
    bool stOk[3];
    const float *vsrcR[3], *ksrcR[3];
    #pragma unroll
    for (int s = 0; s < 3; ++s) {
        int idx = tid + s * 512;
        stOk[s] = idx < 1280;
        stRow[s] = idx >> 3; stCh[s] = idx & 7;
        vsrcR[s] = nullptr; ksrcR[s] = nullptr;
        if (stOk[s] && stRow[s] < KVW) {
            if (stRow[s] == 0) { vsrcR[s] = memV; ksrcR[s] = memK; }
            else {
                int tk = idxK[(size_t)blk * WSZW + stRow[s] - 1];
                vsrcR[s] = v + ((size_t)bh * TT + tk) * DD;
                ksrcR[s] = k + ((size_t)bh * TT + tk) * DD;
            }
        }
    }

    // ---- Q frags (independent chase, overlaps everything) ----
    bf16x8 qf[2];
    {
        int tq = idxQ[(size_t)blk * WSZW + w * 16 + lr];
        const float* qp = q + ((size_t)bh * TT + tq) * DD;
        #pragma unroll
        for (int ks = 0; ks < 2; ++ks) {
            float4 a = *(const float4*)(qp + ks * 32 + lg * 8);
            float4 b = *(const float4*)(qp + ks * 32 + lg * 8 + 4);
            qf[ks] = pack8(a, b);
        }
    }

    // ---- V gather window (batched) ----
    uint4 vw[3];
    #pragma unroll
    for (int s = 0; s < 3; ++s) {
        vw[s] = (uint4){0,0,0,0};
        if (vsrcR[s]) {
            float4 a = *(const float4*)(vsrcR[s] + stCh[s] * 8);
            float4 b = *(const float4*)(vsrcR[s] + stCh[s] * 8 + 4);
            vw[s].x = pk2(a.x, a.y); vw[s].y = pk2(a.z, a.w);
            vw[s].z = pk2(b.x, b.y); vw[s].w = pk2(b.z, b.w);
        }
    }
    // ---- K gather window (batched) ----
    uint4 kw[3];
    #pragma unroll
    for (int s = 0; s < 3; ++s) {
        kw[s] = (uint4){0,0,0,0};
        if (ksrcR[s]) {
            float4 a = *(const float4*)(ksrcR[s] + stCh[s] * 8);
            float4 b = *(const float4*)(ksrcR[s] + stCh[s] * 8 + 4);
            kw[s].x = pk2(a.x, a.y); kw[s].y = pk2(a.z, a.w);
            kw[s].z = pk2(b.x, b.y); kw[s].w = pk2(b.z, b.w);
        }
    }

    // ---- P1: V -> row-major swizzled (in KsS space) ----
    #pragma unroll
    for (int s = 0; s < 3; ++s)
        if (stOk[s])
            *reinterpret_cast<uint4*>(
                &KsS[stRow[s] * 64 + ((stCh[s] ^ (stRow[s] & 7)) * 8)]) = vw[s];
    __syncthreads();

    // ---- P2: Vt column segments -> regs (scalar broadcast-class reads) ----
    unsigned short vreg[3][8];
    #pragma unroll
    for (int s = 0; s < 3; ++s) {
        int idx = tid + s * 512;
        if (idx < 1280) {
            int d = idx & 63, rowblk = idx >> 6;
            #pragma unroll
            for (int i = 0; i < 8; ++i) {
                int row = rowblk * 8 + i;
                vreg[s][i] = KsS[row * 64 + (((d >> 3) ^ (row & 7)) * 8) + (d & 7)];
            }
        }
    }
    __syncthreads();

    // ---- P3: write Vt (b128 rows) + K (b128 swizzled) ----
    #pragma unroll
    for (int s = 0; s < 3; ++s) {
        int idx = tid + s * 512;
        if (idx < 1280) {
            int d = idx & 63, rowblk = idx >> 6;
            uint4 ow;
            ow.x = (unsigned)vreg[s][0] | ((unsigned)vreg[s][1] << 16);
            ow.y = (unsigned)vreg[s][2] | ((unsigned)vreg[s][3] << 16);
            ow.z = (unsigned)vreg[s][4] | ((unsigned)vreg[s][5] << 16);
            ow.w = (unsigned)vreg[s][6] | ((unsigned)vreg[s][7] << 16);
            *reinterpret_cast<uint4*>(&VtS[d * 168 + rowblk * 8]) = ow;
        }
    }
    #pragma unroll
    for (int s = 0; s < 3; ++s)
        if (stOk[s])
            *reinterpret_cast<uint4*>(
                &KsS[stRow[s] * 64 + ((stCh[s] ^ (stRow[s] & 7)) * 8)]) = kw[s];
    __syncthreads();

    // ---- compute (swapped QK^T, P in regs, Vt b128 B-frags) ----
    f32x4 acc[4];
    #pragma unroll
    for (int dt = 0; dt < 4; ++dt) acc[dt] = (f32x4){0.f, 0.f, 0.f, 0.f};
    float s_sum = 0.f;

    int src0 = lr + ((lg & 1) * 2) * 16;
    int src1 = src0 + 16;
    bool hi = (lg >> 1) != 0;

    for (int kb = 0; kb < 5; ++kb) {
        bf16x8 kf[2][2];
        #pragma unroll
        for (int kvt = 0; kvt < 2; ++kvt)
            #pragma unroll
            for (int ks = 0; ks < 2; ++ks) {
                int row = kb * 32 + kvt * 16 + lr;
                int chunk = ks * 4 + lg;
                int phys = chunk ^ (row & 7);
                kf[kvt][ks] = *reinterpret_cast<const bf16x8*>(&KsS[row * 64 + phys * 8]);
            }
        __builtin_amdgcn_s_setprio(1);
        unsigned pk[2][2];
        #pragma unroll
        for (int kvt = 0; kvt < 2; ++kvt) {
            f32x4 sf = __builtin_amdgcn_mfma_f32_16x16x32_bf16(
                kf[kvt][0], qf[0], (f32x4){0.f,0.f,0.f,0.f}, 0, 0, 0);
            sf = __builtin_amdgcn_mfma_f32_16x16x32_bf16(kf[kvt][1], qf[1], sf, 0, 0, 0);
            float e[4];
            #pragma unroll
            for (int r = 0; r < 4; ++r) {
                int kv = kb * 32 + kvt * 16 + lg * 4 + r;
                e[r] = (kv < KVW) ? __expf(sf[r] * SCALE) : 0.f;
                s_sum += e[r];
            }
            pk[kvt][0] = pk2(e[0], e[1]);
            pk[kvt][1] = pk2(e[2], e[3]);
        }
        unsigned a00 = __shfl(pk[0][0], src0), a01 = __shfl(pk[0][1], src0);
        unsigned a10 = __shfl(pk[1][0], src0), a11 = __shfl(pk[1][1], src0);
        unsigned b00 = __shfl(pk[0][0], src1), b01 = __shfl(pk[0][1], src1);
        unsigned b10 = __shfl(pk[1][0], src1), b11 = __shfl(pk[1][1], src1);
        union { unsigned u[4]; bf16x8 v; } pu;
        pu.u[0] = hi ? a10 : a00;
        pu.u[1] = hi ? a11 : a01;
        pu.u[2] = hi ? b10 : b00;
        pu.u[3] = hi ? b11 : b01;
        #pragma unroll
        for (int dt = 0; dt < 4; ++dt) {
            bf16x8 vf = *reinterpret_cast<const bf16x8*>(
                &VtS[(dt * 16 + lr) * 168 + kb * 32 + lg * 8]);
            acc[dt] = __builtin_amdgcn_mfma_f32_16x16x32_bf16(pu.v, vf, acc[dt], 0, 0, 0);
        }
        __builtin_amdgcn_s_setprio(0);
    }

    s_sum += __shfl_xor(s_sum, 16);
    s_sum += __shfl_xor(s_sum, 32);
    float sinv[4];
    #pragma unroll
    for (int r = 0; r < 4; ++r)
        sinv[r] = 1.f / __shfl(s_sum, lg * 4 + r);

    #pragma unroll
    for (int r = 0; r < 4; ++r) {
        int row = w * 16 + lg * 4 + r;
        float* op = so + (((size_t)blk * WSZW + row) * DD);
        #pragma unroll
        for (int dt = 0; dt < 4; ++dt)
            op[dt * 16 + lr] = acc[dt][r] * sinv[r];
    }
}

// ---------------- Kernel F: per-bh exclusive scan (4096 ints) ----------------
__global__ __launch_bounds__(256) void scan_kernel(
    const int* __restrict__ counts, int* __restrict__ offs)
{
    int bh = blockIdx.x;
    int t = threadIdx.x;
    const int* cb = counts + (size_t)bh * TT;
    int* ob = offs + (size_t)bh * TT;

    int loc[16]; int sum = 0;
    #pragma unroll
    for (int i = 0; i < 16; ++i) { loc[i] = sum; sum += cb[t * 16 + i]; }

    __shared__ int wsum[256];
    wsum[t] = sum;
    __syncthreads();
    for (int off = 1; off < 256; off <<= 1) {
        int vv = (t >= off) ? wsum[t - off] : 0;
        __syncthreads();
        wsum[t] += vv;
        __syncthreads();
    }
    int ex = (t == 0) ? 0 : wsum[t - 1];
    #pragma unroll
    for (int i = 0; i < 16; ++i) ob[t * 16 + i] = ex + loc[i];
}

// ---------------- Kernel G: fill CSR slot lists ----------------
__global__ __launch_bounds__(256) void fill_kernel(
    const int* __restrict__ idxQ, const int* __restrict__ offs,
    int* __restrict__ cur, int* __restrict__ csr)
{
    int i = blockIdx.x * 256 + threadIdx.x;
    int bh = i >> 13;
    int within = i & 8191;
    int tok = idxQ[i];
    int p = offs[bh * TT + tok] + atomicAdd(&cur[bh * TT + tok], 1);
    csr[((size_t)bh << 13) + p] = within;
}

// ---------------- Kernel H: gather-reduce + finalize ----------------
__global__ __launch_bounds__(256) void reduce_kernel(
    const float* __restrict__ so, const int* __restrict__ counts,
    const int* __restrict__ offs, const int* __restrict__ csr,
    float* __restrict__ out)
{
    int gt = blockIdx.x * 4 + (threadIdx.x >> 6);
    int lane = threadIdx.x & 63;
    int bh = gt >> 12;
    int n = counts[gt];
    int st = offs[gt];
    const int* cs = csr + ((size_t)bh << 13);
    float acc = 0.f;
    for (int j = 0; j < n; ++j) {
        int slot = cs[st + j];
        acc += so[(((size_t)bh << 13) + slot) * DD + lane];
    }
    out[(size_t)gt * DD + lane] = acc / ((float)n + EPSF);
}

extern "C" void kernel_launch(void* const* d_in, const int* in_sizes, int n_in,
                              void* d_out, int out_size, void* d_ws, size_t ws_size,
                              hipStream_t stream) {
    const float* q        = (const float*)d_in[0];
    const float* k        = (const float*)d_in[1];
    const float* v        = (const float*)d_in[2];
    const float* means    = (const float*)d_in[3];
    const float* mem_key  = (const float*)d_in[4];
    const float* mem_val  = (const float*)d_in[5];
    float* out = (float*)d_out;

    const size_t nRows = (size_t)BB * HH * NCC;             // 2048
    const size_t nTok  = (size_t)BB * HH * TT;              // 131072
    float* wsf    = (float*)d_ws;
    float* distsQ = wsf;                                    // 8388608 f
    float* distsK = distsQ + (size_t)BB * HH * NCC * TT;    // 8388608 f (contiguous after distsQ)
    float* so     = wsf;                                    // aliases dists; written after rescore
    int*   idxQ   = (int*)(distsK + (size_t)BB * HH * NCC * TT);  // 262144 i
    int*   idxK   = idxQ + nRows * WSZW;                    // 262144 i
    int*   counts = idxK + nRows * WSZW;                    // 131072 i
    int*   cur    = counts + nTok;                          // 131072 i
    float* auxp   = (float*)(cur + nTok);                   // 16384 f (per-wave partials)
    int*   offs   = (int*)(auxp + 16384);                   // 131072 i
    int*   csr    = offs + nTok;                            // 262144 i
    int*   candQ  = csr + nTok * 2;                         // 2048*160 i
    int*   candK  = candQ + nRows * TPK;                    // 2048*160 i (contiguous after candQ)
    uintptr_t ip  = (uintptr_t)(candK + nRows * TPK);
    ip = (ip + 15) & ~(uintptr_t)15;
    double* invn  = (double*)ip;                            // 2*131072 d (Q then K)

    hipMemsetAsync(counts, 0, 2 * nTok * sizeof(int), stream);

    dists_kernel<<<dim3(BB * HH * (2 * TT / 64)), dim3(256), 0, stream>>>(
        q, k, means, distsQ, distsK, auxp, invn);
    aux_reduce_kernel<<<dim3(1), dim3(256), 0, stream>>>(auxp, out);
    // single launch covers Q rows (0..2047 over distsQ/candQ) and K rows
    // (2048..4095 over distsK/candK) via buffer contiguity
    topk_kernel<<<dim3((unsigned)(2 * nRows)), dim3(256), 0, stream>>>(distsQ, candQ);
    rescore_kernel<<<dim3((unsigned)(2 * nRows)), dim3(640), 0, stream>>>(
        q, k, means, invn, candQ, candK, idxQ, idxK, counts);
    scan_kernel<<<dim3(BB * HH), dim3(256), 0, stream>>>(counts, offs);
    fill_kernel<<<dim3(1024), dim3(256), 0, stream>>>(idxQ, offs, cur, csr);
    attn_kernel<<<dim3((unsigned)nRows), dim3(512), 0, stream>>>(
        q, k, v, mem_key, mem_val, idxQ, idxK, so);
    reduce_kernel<<<dim3((unsigned)(nTok / 4)), dim3(256), 0, stream>>>(
        so, counts, offs, csr, out);
}

// Round 20
// 226.292 us; speedup vs baseline: 1.1905x; 1.0616x over previous
//
#include <hip/hip_runtime.h>
#include <math.h>

#define BB 4
#define HH 8
#define TT 4096
#define DD 64
#define NCC 64
#define WSZW 128
#define TPK 160          // widened f32 top-k; f64 rescore picks exact top-128
#define MEMN 1
#define KVW (MEMN + WSZW)   // 129
constexpr float EPSF = 1e-5f;
constexpr float SCALE = 0.125f;  // 64^-0.5

typedef __attribute__((ext_vector_type(8))) short bf16x8;
typedef __attribute__((ext_vector_type(4))) float f32x4;

// HW packed f32->bf16 (RNE), 1 instruction vs ~7 for the manual bit-twiddle
static __device__ __forceinline__ unsigned int pk2(float a, float b) {
    unsigned int r;
    asm("v_cvt_pk_bf16_f32 %0, %1, %2" : "=v"(r) : "v"(a), "v"(b));
    return r;
}
static __device__ __forceinline__ bf16x8 pack8(float4 a, float4 b) {
    union { unsigned int u[4]; bf16x8 v; } r;
    r.u[0] = pk2(a.x, a.y); r.u[1] = pk2(a.z, a.w);
    r.u[2] = pk2(b.x, b.y); r.u[3] = pk2(b.z, b.w);
    return r.v;
}
static __device__ __forceinline__ unsigned mono(float f) {
    unsigned b = __float_as_uint(f);
    return b ^ ((unsigned)(((int)b) >> 31) | 0x80000000u);
}
static __device__ __forceinline__ unsigned long long mono64(double d) {
    unsigned long long b = (unsigned long long)__double_as_longlong(d);
    return b ^ (((long long)b < 0) ? ~0ULL : 0x8000000000000000ULL);
}

// ---------------- Kernel A: dists f32 GEMM + shuffle-argmax + aux + invnorm -----
// argmax no longer round-trips through a strided LDS tile (was ~8-way
// conflicted + 2 barriers): per-thread 4x4 max -> xor16/32 shuffles combine the
// 16 lanes sharing a token -> stride-5-padded wave-winner array (<=2-way) ->
// wave 0 finalizes + one aux float per block. XCD-bijective remap for L2 reuse.
__global__ __launch_bounds__(256, 4) void dists_kernel(
    const float* __restrict__ q, const float* __restrict__ k,
    const float* __restrict__ means,
    float* __restrict__ distsQ, float* __restrict__ distsK,
    float* __restrict__ aux_part, double* __restrict__ invn)
{
    __shared__ float xS[64][68];   // [d][tok]
    __shared__ float mS[64][68];   // [d][cluster]
    __shared__ float mqS[64];      // per-cluster ||m||^2
    __shared__ float ssnS[64];     // per-token ||xn||^2
    __shared__ float wMaxS[64 * 5];
    __shared__ int   wIdxS[64 * 5];

    const int chunks = (2 * TT) / 64;          // 128
    int bid0 = blockIdx.x;                     // 4096
    int bid = (bid0 & 7) * 512 + (bid0 >> 3);  // XCD-contiguous (4096 % 8 == 0)
    int bh = bid / chunks;
    int chunk = bid % chunks;
    int h = bh % HH;
    bool isQ = chunk < (TT / 64);
    int tbase = (isQ ? chunk : chunk - 64) * 64;
    const float* src = (isQ ? q : k) + ((size_t)bh * TT + tbase) * DD;
    float* dst = isQ ? distsQ : distsK;
    double* invdst = invn + (isQ ? 0 : (size_t)BB * HH * TT) + (size_t)bh * TT + tbase;

    int tid = threadIdx.x;
    int tok = tid >> 2, part = tid & 3;        // tok doubles as cluster idx below

    // ---- stage means (transposed) + per-cluster sumsq ----
    {
        const float* mp = means + ((size_t)h * NCC + tok) * DD + part * 16;
        float4 va[4];
        #pragma unroll
        for (int i = 0; i < 4; ++i) va[i] = *(const float4*)(mp + i * 4);
        float msq = 0.f;
        #pragma unroll
        for (int i = 0; i < 4; ++i) {
            msq += va[i].x*va[i].x + va[i].y*va[i].y + va[i].z*va[i].z + va[i].w*va[i].w;
            int d = part * 16 + i * 4;
            mS[d][tok] = va[i].x; mS[d+1][tok] = va[i].y;
            mS[d+2][tok] = va[i].z; mS[d+3][tok] = va[i].w;
        }
        msq += __shfl_xor(msq, 1);
        msq += __shfl_xor(msq, 2);
        if (part == 0) mqS[tok] = msq;
    }
    // ---- stage x normalized (transposed); f64 norm, store invnorm + ssn ----
    {
        const float* xp = src + (size_t)tok * DD + part * 16;
        float4 va[4];
        #pragma unroll
        for (int i = 0; i < 4; ++i) va[i] = *(const float4*)(xp + i * 4);
        double ssd = 0.0;
        #pragma unroll
        for (int i = 0; i < 4; ++i)
            ssd += (double)va[i].x*va[i].x + (double)va[i].y*va[i].y
                 + (double)va[i].z*va[i].z + (double)va[i].w*va[i].w;
        ssd += __shfl_xor(ssd, 1);
        ssd += __shfl_xor(ssd, 2);
        double invd = 1.0 / fmax(sqrt(ssd), 1e-12);
        if (part == 0) {
            invdst[tok] = invd;
            ssnS[tok] = (float)(ssd * invd * invd);
        }
        float inv = (float)invd;
        #pragma unroll
        for (int i = 0; i < 4; ++i) {
            int d = part * 16 + i * 4;
            xS[d][tok] = va[i].x*inv; xS[d+1][tok] = va[i].y*inv;
            xS[d+2][tok] = va[i].z*inv; xS[d+3][tok] = va[i].w*inv;
        }
    }
    __syncthreads();

    // ---- GEMM: thread = 4 tokens x 4 clusters ----
    int l = tid & 63, w = tid >> 6;
    int ti = l & 15;                 // token tile 4*ti..
    int ci = w * 4 + (l >> 4);       // cluster tile 4*ci..
    float acc[4][4];
    #pragma unroll
    for (int i = 0; i < 4; ++i)
        #pragma unroll
        for (int j = 0; j < 4; ++j) acc[i][j] = 0.f;

    #pragma unroll 16
    for (int kk = 0; kk < 64; ++kk) {
        float4 xv = *(const float4*)(&xS[kk][ti * 4]);
        float4 mv = *(const float4*)(&mS[kk][ci * 4]);
        float xa[4] = {xv.x, xv.y, xv.z, xv.w};
        float ma[4] = {mv.x, mv.y, mv.z, mv.w};
        #pragma unroll
        for (int i = 0; i < 4; ++i)
            #pragma unroll
            for (int j = 0; j < 4; ++j) acc[i][j] += xa[i] * ma[j];
    }

    // ---- store dists to global (coalesced float4 over tokens) ----
    {
        size_t rowb = (size_t)(bh * NCC) * TT;
        #pragma unroll
        for (int j = 0; j < 4; ++j) {
            int c = ci * 4 + j;
            float4 o;
            o.x = acc[0][j]; o.y = acc[1][j]; o.z = acc[2][j]; o.w = acc[3][j];
            *(float4*)&dst[rowb + (size_t)c * TT + tbase + ti * 4] = o;
        }
    }

    // ---- argmax via shuffles (no LDS round-trip) ----
    #pragma unroll
    for (int i = 0; i < 4; ++i) {
        float bv = acc[i][0]; int bc = ci * 4;
        #pragma unroll
        for (int j = 1; j < 4; ++j)
            if (acc[i][j] > bv) { bv = acc[i][j]; bc = ci * 4 + j; }
        #pragma unroll
        for (int off = 16; off <= 32; off <<= 1) {
            float ov = __shfl_xor(bv, off);
            int   oc = __shfl_xor(bc, off);
            if (ov > bv || (ov == bv && oc < bc)) { bv = ov; bc = oc; }
        }
        if (l < 16) {                      // lane l == ti: wave winner
            wMaxS[(ti * 4 + i) * 5 + w] = bv;
            wIdxS[(ti * 4 + i) * 5 + w] = bc;
        }
    }
    __syncthreads();

    if (tid < 64) {
        int mytok = tid;
        float bv = -1e30f; int bc = 0;
        #pragma unroll
        for (int w2 = 0; w2 < 4; ++w2) {   // ascending cluster ranges
            float ov = wMaxS[mytok * 5 + w2];
            int   oc = wIdxS[mytok * 5 + w2];
            if (ov > bv || (ov == bv && oc < bc)) { bv = ov; bc = oc; }
        }
        float auxv = ssnS[mytok] + mqS[bc] - 2.f * bv;
        #pragma unroll
        for (int off = 32; off; off >>= 1) auxv += __shfl_xor(auxv, off);
        if (tid == 0) aux_part[bid] = auxv;
    }
}

// ---------------- Kernel B: top-TPK per row, 3-pass radix (12/12/8 bits) -------
__global__ __launch_bounds__(256) void topk_kernel(
    const float* __restrict__ dists, int* __restrict__ idxOut)
{
    int row = blockIdx.x;
    const float* dv = dists + (size_t)row * TT;
    int t = threadIdx.x;
    int lane = t & 63, w = t >> 6;

    unsigned u[16];
    #pragma unroll
    for (int j0 = 0; j0 < 4; ++j0) {
        float4 f = *(const float4*)(dv + t * 16 + j0 * 4);
        u[j0*4+0] = mono(f.x); u[j0*4+1] = mono(f.y);
        u[j0*4+2] = mono(f.z); u[j0*4+3] = mono(f.w);
    }

    __shared__ int hist[4096];
    __shared__ int wtot[4];
    __shared__ int binSel, tgtS;
    __shared__ int nGtS, posS, eqPos;

    int target = TPK;
    unsigned prefix = 0;

    // ---- passes 1,2: 12-bit digits over 4096 bins ----
    #pragma unroll
    for (int pass = 0; pass < 2; ++pass) {
        int4* hz = (int4*)&hist[t * 16];
        hz[0] = (int4){0,0,0,0}; hz[1] = (int4){0,0,0,0};
        hz[2] = (int4){0,0,0,0}; hz[3] = (int4){0,0,0,0};
        __syncthreads();
        if (pass == 0) {
            #pragma unroll
            for (int j = 0; j < 16; ++j) atomicAdd(&hist[u[j] >> 20], 1);
        } else {
            #pragma unroll
            for (int j = 0; j < 16; ++j)
                if ((u[j] >> 20) == (prefix >> 20))
                    atomicAdd(&hist[(u[j] >> 8) & 0xFFF], 1);
        }
        __syncthreads();
        int cnt[16], ls[16];
        {
            const int4* hp = (const int4*)&hist[t * 16];
            int4 c0 = hp[0], c1 = hp[1], c2 = hp[2], c3 = hp[3];
            cnt[0]=c0.x; cnt[1]=c0.y; cnt[2]=c0.z; cnt[3]=c0.w;
            cnt[4]=c1.x; cnt[5]=c1.y; cnt[6]=c1.z; cnt[7]=c1.w;
            cnt[8]=c2.x; cnt[9]=c2.y; cnt[10]=c2.z; cnt[11]=c2.w;
            cnt[12]=c3.x; cnt[13]=c3.y; cnt[14]=c3.z; cnt[15]=c3.w;
        }
        int run = 0;
        #pragma unroll
        for (int i = 15; i >= 0; --i) { run += cnt[i]; ls[i] = run; }
        int S = run;
        #pragma unroll
        for (int off = 1; off < 64; off <<= 1) {
            int o = __shfl_down(S, off);
            if (lane + off < 64) S += o;
        }
        if (lane == 0) wtot[w] = S;
        __syncthreads();
        int after = 0;
        for (int ww = w + 1; ww < 4; ++ww) after += wtot[ww];
        int St1 = S - run + after;      // suffix of bins owned by later threads
        #pragma unroll
        for (int i = 0; i < 16; ++i) {
            int sfxb = ls[i] + St1;
            if (sfxb >= target && sfxb - cnt[i] < target) {
                binSel = t * 16 + i; tgtS = target - (sfxb - cnt[i]);
            }
        }
        __syncthreads();
        prefix |= (pass == 0) ? ((unsigned)binSel << 20) : ((unsigned)binSel << 8);
        target = tgtS;
        __syncthreads();
    }

    // ---- pass 3: low 8 bits (256 bins) ----
    hist[t] = 0;
    __syncthreads();
    #pragma unroll
    for (int j = 0; j < 16; ++j)
        if ((u[j] >> 8) == (prefix >> 8))
            atomicAdd(&hist[u[j] & 0xFF], 1);
    __syncthreads();
    {
        int cnt = hist[t];
        int S = cnt;
        #pragma unroll
        for (int off = 1; off < 64; off <<= 1) {
            int o = __shfl_down(S, off);
            if (lane + off < 64) S += o;
        }
        if (lane == 0) wtot[w] = S;
        __syncthreads();
        int after = 0;
        for (int ww = w + 1; ww < 4; ++ww) after += wtot[ww];
        int sfx = S + after;
        if (sfx >= target && sfx - cnt < target) { binSel = t; tgtS = target - (sfx - cnt); }
    }
    __syncthreads();
    unsigned pivot = prefix | (unsigned)binSel;

    // ---- epilogue: compact >pivot, then ==pivot (unordered, capped) ----
    if (t == 0) { nGtS = 0; posS = 0; eqPos = 0; }
    __syncthreads();
    int myg = 0;
    #pragma unroll
    for (int j = 0; j < 16; ++j) myg += (u[j] > pivot) ? 1 : 0;
    if (myg) atomicAdd(&nGtS, myg);
    __syncthreads();
    int n_gt = nGtS;
    int n_need = TPK - n_gt;
    int* out = idxOut + (size_t)row * TPK;
    #pragma unroll
    for (int j = 0; j < 16; ++j) {
        if (u[j] > pivot) {
            int p = atomicAdd(&posS, 1);
            out[p] = t * 16 + j;
        } else if (u[j] == pivot) {
            int p = atomicAdd(&eqPos, 1);
            if (p < n_need) out[n_gt + p] = t * 16 + j;
        }
    }
}

// ---------------- Kernel B2: f64 rescore, branchless u32-prefix rank ----------
__global__ __launch_bounds__(640) void rescore_kernel(
    const float* __restrict__ q, const float* __restrict__ k,
    const float* __restrict__ means, const double* __restrict__ invn,
    const int* __restrict__ candQ, const int* __restrict__ candK,
    int* __restrict__ idxQ, int* __restrict__ idxK,
    int* __restrict__ counts)
{
    int bid = blockIdx.x;
    int rid = (bid & 7) * 512 + (bid >> 3);   // 4096 % 8 == 0 -> bijective
    int side = rid >> 11;            // 0=Q, 1=K
    int row = rid & 2047;            // bh*NC + c
    int c = row & (NCC - 1);
    int bh = row >> 6;
    int h = bh % HH;

    const int* cand = (side ? candK : candQ) + (size_t)row * TPK;
    int* outIdx     = (side ? idxK : idxQ) + (size_t)row * WSZW;
    const float* xbase = (side ? k : q) + (size_t)bh * TT * DD;
    const double* invp = invn + (side ? (size_t)BB * HH * TT : 0) + (size_t)bh * TT;

    __shared__ double   mD[DD];
    __shared__ unsigned hiS[TPK];
    __shared__ unsigned loS[TPK];
    __shared__ int      kiS[TPK];

    int tid = threadIdx.x;
    if (tid < DD) mD[tid] = (double)means[((size_t)h * NCC + c) * DD + tid];
    __syncthreads();

    int g = tid >> 2;                // candidate 0..159
    int qt = tid & 3;                // quarter-row 0..3
    int tok = cand[g];
    const float* xp = xbase + (size_t)tok * DD + qt * 16;
    double inv = invp[tok];          // 4 lanes same addr -> broadcast
    double d0 = 0.0, d1 = 0.0;
    #pragma unroll
    for (int i = 0; i < 2; ++i) {
        float4 va = *(const float4*)(xp + i * 4);
        int d = qt * 16 + i * 4;
        d0 += (double)va.x * mD[d]   + (double)va.y * mD[d+1]
            + (double)va.z * mD[d+2] + (double)va.w * mD[d+3];
    }
    #pragma unroll
    for (int i = 2; i < 4; ++i) {
        float4 va = *(const float4*)(xp + i * 4);
        int d = qt * 16 + i * 4;
        d1 += (double)va.x * mD[d]   + (double)va.y * mD[d+1]
            + (double)va.z * mD[d+2] + (double)va.w * mD[d+3];
    }
    double dot = d0 + d1;
    dot += __shfl_xor(dot, 1); dot += __shfl_xor(dot, 2);
    double v = dot * inv;            // identical across the 4-lane group
    unsigned long long key = mono64(v);
    unsigned myhi = (unsigned)(key >> 32), mylo = (unsigned)key;
    if (qt == 0) { hiS[g] = myhi; loS[g] = mylo; kiS[g] = tok; }
    __syncthreads();

    // phase 1: branchless rank on 32-bit prefixes (1 LDS b32 read per iter)
    int rk = 0, eq = 0;
    #pragma unroll 8
    for (int i = 0; i < TPK / 4; ++i) {
        unsigned hj = hiS[qt * (TPK / 4) + i];
        rk += (hj > myhi) ? 1 : 0;
        eq += (hj == myhi) ? 1 : 0;
    }
    rk += __shfl_xor(rk, 1); rk += __shfl_xor(rk, 2);
    eq += __shfl_xor(eq, 1); eq += __shfl_xor(eq, 2);

    // phase 2 (rare): exact 64-bit + token recount when hi-prefix ties exist
    if (eq > 1) {
        int rk2 = 0;
        for (int i = 0; i < TPK / 4; ++i) {
            int j = qt * (TPK / 4) + i;
            unsigned hj = hiS[j];
            if (hj > myhi) rk2++;
            else if (hj == myhi) {
                unsigned lj = loS[j];
                if (lj > mylo || (lj == mylo && kiS[j] < tok)) rk2++;
            }
        }
        rk2 += __shfl_xor(rk2, 1); rk2 += __shfl_xor(rk2, 2);
        rk = rk2;
    }

    if (qt == 0 && rk < WSZW) {
        outIdx[rk] = tok;
        if (side == 0) atomicAdd(&counts[bh * TT + tok], 1);
    }
}

// ---------------- Kernel C: bf16 MFMA attention, chase-free batched staging ----
__global__ __launch_bounds__(512, 2) void attn_kernel(
    const float* __restrict__ q, const float* __restrict__ k, const float* __restrict__ v,
    const float* __restrict__ mem_key, const float* __restrict__ mem_value,
    const int* __restrict__ idxQ, const int* __restrict__ idxK,
    float* __restrict__ so)
{
    // XCD-bijective swizzle (2048 % 8 == 0): 256 consecutive blks per XCD
    int bid = blockIdx.x;
    int blk = (bid & 7) * 256 + (bid >> 3);
    int c = blk % NCC;
    int bh = blk / NCC;
    int h = bh % HH;

    __shared__ __align__(16) unsigned short KsS[160 * 64];   // [kv][d] swizzled (temp V in P1/P2)
    __shared__ __align__(16) unsigned short VtS[64 * 168];   // [d][kv], pad 168

    int tid = threadIdx.x;
    int w = tid >> 6, l = tid & 63;
    int lr = l & 15, lg = l >> 4;

    const float* memK = mem_key   + ((size_t)h * NCC + c) * (MEMN * DD);
    const float* memV = mem_value + ((size_t)h * NCC + c) * (MEMN * DD);

    // ---- entry: resolve staging rows + issue ALL token-index gathers ----
    int stRow[3], stCh[3];
    bool stOk[3];
    const float *vsrcR[3], *ksrcR[3];
    #pragma unroll
    for (int s = 0; s < 3; ++s) {
        int idx = tid + s * 512;
        stOk[s] = idx < 1280;
        stRow[s] = idx >> 3; stCh[s] = idx & 7;
        vsrcR[s] = nullptr; ksrcR[s] = nullptr;
        if (stOk[s] && stRow[s] < KVW) {
            if (stRow[s] == 0) { vsrcR[s] = memV; ksrcR[s] = memK; }
            else {
                int tk = idxK[(size_t)blk * WSZW + stRow[s] - 1];
                vsrcR[s] = v + ((size_t)bh * TT + tk) * DD;
                ksrcR[s] = k + ((size_t)bh * TT + tk) * DD;
            }
        }
    }

    // ---- Q frags (independent chase, overlaps everything) ----
    bf16x8 qf[2];
    {
        int tq = idxQ[(size_t)blk * WSZW + w * 16 + lr];
        const float* qp = q + ((size_t)bh * TT + tq) * DD;
        #pragma unroll
        for (int ks = 0; ks < 2; ++ks) {
            float4 a = *(const float4*)(qp + ks * 32 + lg * 8);
            float4 b = *(const float4*)(qp + ks * 32 + lg * 8 + 4);
            qf[ks] = pack8(a, b);
        }
    }

    // ---- V gather window (batched) ----
    uint4 vw[3];
    #pragma unroll
    for (int s = 0; s < 3; ++s) {
        vw[s] = (uint4){0,0,0,0};
        if (vsrcR[s]) {
            float4 a = *(const float4*)(vsrcR[s] + stCh[s] * 8);
            float4 b = *(const float4*)(vsrcR[s] + stCh[s] * 8 + 4);
            vw[s].x = pk2(a.x, a.y); vw[s].y = pk2(a.z, a.w);
            vw[s].z = pk2(b.x, b.y); vw[s].w = pk2(b.z, b.w);
        }
    }
    // ---- K gather window (batched) ----
    uint4 kw[3];
    #pragma unroll
    for (int s = 0; s < 3; ++s) {
        kw[s] = (uint4){0,0,0,0};
        if (ksrcR[s]) {
            float4 a = *(const float4*)(ksrcR[s] + stCh[s] * 8);
            float4 b = *(const float4*)(ksrcR[s] + stCh[s] * 8 + 4);
            kw[s].x = pk2(a.x, a.y); kw[s].y = pk2(a.z, a.w);
            kw[s].z = pk2(b.x, b.y); kw[s].w = pk2(b.z, b.w);
        }
    }

    // ---- P1: V -> row-major swizzled (in KsS space) ----
    #pragma unroll
    for (int s = 0; s < 3; ++s)
        if (stOk[s])
            *reinterpret_cast<uint4*>(
                &KsS[stRow[s] * 64 + ((stCh[s] ^ (stRow[s] & 7)) * 8)]) = vw[s];
    __syncthreads();

    // ---- P2: Vt column segments -> regs (scalar broadcast-class reads) ----
    unsigned short vreg[3][8];
    #pragma unroll
    for (int s = 0; s < 3; ++s) {
        int idx = tid + s * 512;
        if (idx < 1280) {
            int d = idx & 63, rowblk = idx >> 6;
            #pragma unroll
            for (int i = 0; i < 8; ++i) {
                int row = rowblk * 8 + i;
                vreg[s][i] = KsS[row * 64 + (((d >> 3) ^ (row & 7)) * 8) + (d & 7)];
            }
        }
    }
    __syncthreads();

    // ---- P3: write Vt (b128 rows) + K (b128 swizzled) ----
    #pragma unroll
    for (int s = 0; s < 3; ++s) {
        int idx = tid + s * 512;
        if (idx < 1280) {
            int d = idx & 63, rowblk = idx >> 6;
            uint4 ow;
            ow.x = (unsigned)vreg[s][0] | ((unsigned)vreg[s][1] << 16);
            ow.y = (unsigned)vreg[s][2] | ((unsigned)vreg[s][3] << 16);
            ow.z = (unsigned)vreg[s][4] | ((unsigned)vreg[s][5] << 16);
            ow.w = (unsigned)vreg[s][6] | ((unsigned)vreg[s][7] << 16);
            *reinterpret_cast<uint4*>(&VtS[d * 168 + rowblk * 8]) = ow;
        }
    }
    #pragma unroll
    for (int s = 0; s < 3; ++s)
        if (stOk[s])
            *reinterpret_cast<uint4*>(
                &KsS[stRow[s] * 64 + ((stCh[s] ^ (stRow[s] & 7)) * 8)]) = kw[s];
    __syncthreads();

    // ---- compute (swapped QK^T, P in regs, Vt b128 B-frags) ----
    f32x4 acc[4];
    #pragma unroll
    for (int dt = 0; dt < 4; ++dt) acc[dt] = (f32x4){0.f, 0.f, 0.f, 0.f};
    float s_sum = 0.f;

    int src0 = lr + ((lg & 1) * 2) * 16;
    int src1 = src0 + 16;
    bool hi = (lg >> 1) != 0;

    for (int kb = 0; kb < 5; ++kb) {
        bf16x8 kf[2][2];
        #pragma unroll
        for (int kvt = 0; kvt < 2; ++kvt)
            #pragma unroll
            for (int ks = 0; ks < 2; ++ks) {
                int row = kb * 32 + kvt * 16 + lr;
                int chunk = ks * 4 + lg;
                int phys = chunk ^ (row & 7);
                kf[kvt][ks] = *reinterpret_cast<const bf16x8*>(&KsS[row * 64 + phys * 8]);
            }
        __builtin_amdgcn_s_setprio(1);
        unsigned pk[2][2];
        #pragma unroll
        for (int kvt = 0; kvt < 2; ++kvt) {
            f32x4 sf = __builtin_amdgcn_mfma_f32_16x16x32_bf16(
                kf[kvt][0], qf[0], (f32x4){0.f,0.f,0.f,0.f}, 0, 0, 0);
            sf = __builtin_amdgcn_mfma_f32_16x16x32_bf16(kf[kvt][1], qf[1], sf, 0, 0, 0);
            float e[4];
            #pragma unroll
            for (int r = 0; r < 4; ++r) {
                int kv = kb * 32 + kvt * 16 + lg * 4 + r;
                e[r] = (kv < KVW) ? __expf(sf[r] * SCALE) : 0.f;
                s_sum += e[r];
            }
            pk[kvt][0] = pk2(e[0], e[1]);
            pk[kvt][1] = pk2(e[2], e[3]);
        }
        unsigned a00 = __shfl(pk[0][0], src0), a01 = __shfl(pk[0][1], src0);
        unsigned a10 = __shfl(pk[1][0], src0), a11 = __shfl(pk[1][1], src0);
        unsigned b00 = __shfl(pk[0][0], src1), b01 = __shfl(pk[0][1], src1);
        unsigned b10 = __shfl(pk[1][0], src1), b11 = __shfl(pk[1][1], src1);
        union { unsigned u[4]; bf16x8 v; } pu;
        pu.u[0] = hi ? a10 : a00;
        pu.u[1] = hi ? a11 : a01;
        pu.u[2] = hi ? b10 : b00;
        pu.u[3] = hi ? b11 : b01;
        #pragma unroll
        for (int dt = 0; dt < 4; ++dt) {
            bf16x8 vf = *reinterpret_cast<const bf16x8*>(
                &VtS[(dt * 16 + lr) * 168 + kb * 32 + lg * 8]);
            acc[dt] = __builtin_amdgcn_mfma_f32_16x16x32_bf16(pu.v, vf, acc[dt], 0, 0, 0);
        }
        __builtin_amdgcn_s_setprio(0);
    }

    s_sum += __shfl_xor(s_sum, 16);
    s_sum += __shfl_xor(s_sum, 32);
    float sinv[4];
    #pragma unroll
    for (int r = 0; r < 4; ++r)
        sinv[r] = 1.f / __shfl(s_sum, lg * 4 + r);

    #pragma unroll
    for (int r = 0; r < 4; ++r) {
        int row = w * 16 + lg * 4 + r;
        float* op = so + (((size_t)blk * WSZW + row) * DD);
        #pragma unroll
        for (int dt = 0; dt < 4; ++dt)
            op[dt * 16 + lr] = acc[dt][r] * sinv[r];
    }
}

// ---------------- Kernel F: fused per-bh scan + CSR fill + aux finalize --------
// LDS-resident offs/cur (no global cur, no RAW). Block 0 also folds the 4096
// per-block aux partials into out[N]. Barrier counts identical across blocks.
__global__ __launch_bounds__(256) void scanfill_kernel(
    const int* __restrict__ counts, int* __restrict__ offs,
    const int* __restrict__ idxQ, int* __restrict__ csr,
    const float* __restrict__ auxp, float* __restrict__ out)
{
    __shared__ int offsL[TT];
    __shared__ int curL[TT];
    __shared__ int wsum[256];
    __shared__ float auxW[4];

    int bh = blockIdx.x;
    int t = threadIdx.x;

    // ---- aux fold (loads only on block 0; uniform barriers) ----
    float s = 0.f;
    if (bh == 0)
        for (int i = t; i < 4096; i += 256) s += auxp[i];
    #pragma unroll
    for (int off = 32; off; off >>= 1) s += __shfl_xor(s, off);
    if ((t & 63) == 0) auxW[t >> 6] = s;
    __syncthreads();
    if (bh == 0 && t == 0)
        out[(size_t)BB * HH * TT * DD] =
            (auxW[0] + auxW[1] + auxW[2] + auxW[3]) *
            (1.0f / (float)(BB * HH * 2 * TT * DD));

    // ---- exclusive scan over counts[bh] ----
    const int* cb = counts + (size_t)bh * TT;
    int* ob = offs + (size_t)bh * TT;
    int loc[16]; int sum = 0;
    #pragma unroll
    for (int i = 0; i < 16; ++i) { loc[i] = sum; sum += cb[t * 16 + i]; }
    wsum[t] = sum;
    __syncthreads();
    for (int off = 1; off < 256; off <<= 1) {
        int vv = (t >= off) ? wsum[t - off] : 0;
        __syncthreads();
        wsum[t] += vv;
        __syncthreads();
    }
    int ex = (t == 0) ? 0 : wsum[t - 1];
    #pragma unroll
    for (int i = 0; i < 16; ++i) {
        int o = ex + loc[i];
        ob[t * 16 + i] = o;
        offsL[t * 16 + i] = o;
        curL[t * 16 + i] = 0;
    }
    __syncthreads();

    // ---- CSR fill (LDS atomics) ----
    const int* iq = idxQ + ((size_t)bh << 13);
    int* cs = csr + ((size_t)bh << 13);
    for (int i = t; i < 8192; i += 256) {
        int tok = iq[i];
        int p = offsL[tok] + atomicAdd(&curL[tok], 1);
        cs[p] = i;
    }
}

// ---------------- Kernel H: gather-reduce + finalize ----------------
__global__ __launch_bounds__(256) void reduce_kernel(
    const float* __restrict__ so, const int* __restrict__ counts,
    const int* __restrict__ offs, const int* __restrict__ csr,
    float* __restrict__ out)
{
    int gt = blockIdx.x * 4 + (threadIdx.x >> 6);
    int lane = threadIdx.x & 63;
    int bh = gt >> 12;
    int n = counts[gt];
    int st = offs[gt];
    const int* cs = csr + ((size_t)bh << 13);
    float acc = 0.f;
    for (int j = 0; j < n; ++j) {
        int slot = cs[st + j];
        acc += so[(((size_t)bh << 13) + slot) * DD + lane];
    }
    out[(size_t)gt * DD + lane] = acc / ((float)n + EPSF);
}

extern "C" void kernel_launch(void* const* d_in, const int* in_sizes, int n_in,
                              void* d_out, int out_size, void* d_ws, size_t ws_size,
                              hipStream_t stream) {
    const float* q        = (const float*)d_in[0];
    const float* k        = (const float*)d_in[1];
    const float* v        = (const float*)d_in[2];
    const float* means    = (const float*)d_in[3];
    const float* mem_key  = (const float*)d_in[4];
    const float* mem_val  = (const float*)d_in[5];
    float* out = (float*)d_out;

    const size_t nRows = (size_t)BB * HH * NCC;             // 2048
    const size_t nTok  = (size_t)BB * HH * TT;              // 131072
    float* wsf    = (float*)d_ws;
    float* distsQ = wsf;                                    // 8388608 f
    float* distsK = distsQ + (size_t)BB * HH * NCC * TT;    // 8388608 f (contiguous after distsQ)
    float* so     = wsf;                                    // aliases dists; written after rescore
    int*   idxQ   = (int*)(distsK + (size_t)BB * HH * NCC * TT);  // 262144 i
    int*   idxK   = idxQ + nRows * WSZW;                    // 262144 i
    int*   counts = idxK + nRows * WSZW;                    // 131072 i
    float* auxp   = (float*)(counts + nTok);                // 4096 f (per-block partials)
    int*   offs   = (int*)(auxp + 4096);                    // 131072 i
    int*   csr    = offs + nTok;                            // 262144 i
    int*   candQ  = csr + nTok * 2;                         // 2048*160 i
    int*   candK  = candQ + nRows * TPK;                    // 2048*160 i (contiguous after candQ)
    uintptr_t ip  = (uintptr_t)(candK + nRows * TPK);
    ip = (ip + 15) & ~(uintptr_t)15;
    double* invn  = (double*)ip;                            // 2*131072 d (Q then K)

    hipMemsetAsync(counts, 0, nTok * sizeof(int), stream);

    dists_kernel<<<dim3(BB * HH * (2 * TT / 64)), dim3(256), 0, stream>>>(
        q, k, means, distsQ, distsK, auxp, invn);
    // single launch covers Q rows (0..2047 over distsQ/candQ) and K rows
    // (2048..4095 over distsK/candK) via buffer contiguity
    topk_kernel<<<dim3((unsigned)(2 * nRows)), dim3(256), 0, stream>>>(distsQ, candQ);
    rescore_kernel<<<dim3((unsigned)(2 * nRows)), dim3(640), 0, stream>>>(
        q, k, means, invn, candQ, candK, idxQ, idxK, counts);
    scanfill_kernel<<<dim3(BB * HH), dim3(256), 0, stream>>>(
        counts, offs, idxQ, csr, auxp, out);
    attn_kernel<<<dim3((unsigned)nRows), dim3(512), 0, stream>>>(
        q, k, v, mem_key, mem_val, idxQ, idxK, so);
    reduce_kernel<<<dim3((unsigned)(nTok / 4)), dim3(256), 0, stream>>>(
        so, counts, offs, csr, out);
}

// Round 21
// 210.058 us; speedup vs baseline: 1.2825x; 1.0773x over previous
//
#include <hip/hip_runtime.h>
#include <math.h>

#define BB 4
#define HH 8
#define TT 4096
#define DD 64
#define NCC 64
#define WSZW 128
#define TPK 160          // widened f32 top-k; f64 rescore picks exact top-128
#define MEMN 1
#define KVW (MEMN + WSZW)   // 129
constexpr float EPSF = 1e-5f;
constexpr float SCALE = 0.125f;  // 64^-0.5

typedef __attribute__((ext_vector_type(8))) short bf16x8;
typedef __attribute__((ext_vector_type(4))) float f32x4;

// HW packed f32->bf16 (RNE), 1 instruction vs ~7 for the manual bit-twiddle
static __device__ __forceinline__ unsigned int pk2(float a, float b) {
    unsigned int r;
    asm("v_cvt_pk_bf16_f32 %0, %1, %2" : "=v"(r) : "v"(a), "v"(b));
    return r;
}
static __device__ __forceinline__ bf16x8 pack8(float4 a, float4 b) {
    union { unsigned int u[4]; bf16x8 v; } r;
    r.u[0] = pk2(a.x, a.y); r.u[1] = pk2(a.z, a.w);
    r.u[2] = pk2(b.x, b.y); r.u[3] = pk2(b.z, b.w);
    return r.v;
}
static __device__ __forceinline__ unsigned mono(float f) {
    unsigned b = __float_as_uint(f);
    return b ^ ((unsigned)(((int)b) >> 31) | 0x80000000u);
}
static __device__ __forceinline__ unsigned long long mono64(double d) {
    unsigned long long b = (unsigned long long)__double_as_longlong(d);
    return b ^ (((long long)b < 0) ? ~0ULL : 0x8000000000000000ULL);
}

// ---------------- Kernel A: dists via split-bf16 MFMA + shuffle-argmax ----------
// dist = xh*mh + xh*ml + xl*mh (bf16 hi/lo split, err ~1e-5 << 32-rank capture
// margin ~2.5e-3; exact f64 rescore downstream). Frag layout identical to the
// verified attn kernel (A rows = clusters, B cols = tokens, XOR-swizzled LDS).
// Norm stays f64 (invn unchanged). One aux float per block.
__global__ __launch_bounds__(256, 4) void dists_kernel(
    const float* __restrict__ q, const float* __restrict__ k,
    const float* __restrict__ means,
    float* __restrict__ distsQ, float* __restrict__ distsK,
    float* __restrict__ aux_part, double* __restrict__ invn)
{
    __shared__ __align__(16) unsigned short mhS[64 * 64];   // [c][d] swizzled chunks
    __shared__ __align__(16) unsigned short mlS[64 * 64];
    __shared__ __align__(16) unsigned short xhS[64 * 64];   // [tok][d]
    __shared__ __align__(16) unsigned short xlS[64 * 64];
    __shared__ float mqS[64];      // per-cluster ||m||^2
    __shared__ float ssnS[64];     // per-token ||xn||^2
    __shared__ float wMaxS[64 * 5];
    __shared__ int   wIdxS[64 * 5];

    const int chunks = (2 * TT) / 64;          // 128
    int bid0 = blockIdx.x;                     // 4096
    int bid = (bid0 & 7) * 512 + (bid0 >> 3);  // XCD-contiguous (4096 % 8 == 0)
    int bh = bid / chunks;
    int chunk = bid % chunks;
    int h = bh % HH;
    bool isQ = chunk < (TT / 64);
    int tbase = (isQ ? chunk : chunk - 64) * 64;
    const float* src = (isQ ? q : k) + ((size_t)bh * TT + tbase) * DD;
    float* dst = isQ ? distsQ : distsK;
    double* invdst = invn + (isQ ? 0 : (size_t)BB * HH * TT) + (size_t)bh * TT + tbase;

    int tid = threadIdx.x;
    int row = tid >> 2, part = tid & 3;        // row = cluster idx AND token idx

    // ---- stage means hi/lo (swizzled) + ||m||^2 ----
    {
        const float* mp = means + ((size_t)h * NCC + row) * DD + part * 16;
        float f[16];
        float msq = 0.f;
        #pragma unroll
        for (int i = 0; i < 4; ++i) {
            float4 va = *(const float4*)(mp + i * 4);
            f[i*4] = va.x; f[i*4+1] = va.y; f[i*4+2] = va.z; f[i*4+3] = va.w;
            msq += va.x*va.x + va.y*va.y + va.z*va.z + va.w*va.w;
        }
        msq += __shfl_xor(msq, 1);
        msq += __shfl_xor(msq, 2);
        if (part == 0) mqS[row] = msq;
        #pragma unroll
        for (int cc = 0; cc < 2; ++cc) {
            unsigned hw[4], lw[4];
            #pragma unroll
            for (int j2 = 0; j2 < 4; ++j2) {
                float a = f[cc*8 + j2*2], b = f[cc*8 + j2*2 + 1];
                unsigned p = pk2(a, b);
                float ha = __uint_as_float(p << 16);
                float hb = __uint_as_float(p & 0xFFFF0000u);
                hw[j2] = p; lw[j2] = pk2(a - ha, b - hb);
            }
            int ch = part * 2 + cc;
            int phys = ch ^ (row & 7);
            *reinterpret_cast<uint4*>(&mhS[row * 64 + phys * 8]) = (uint4){hw[0],hw[1],hw[2],hw[3]};
            *reinterpret_cast<uint4*>(&mlS[row * 64 + phys * 8]) = (uint4){lw[0],lw[1],lw[2],lw[3]};
        }
    }
    // ---- stage xn hi/lo (swizzled); f64 norm -> invn + ssn ----
    {
        const float* xp = src + (size_t)row * DD + part * 16;
        float f[16];
        double ssd = 0.0;
        #pragma unroll
        for (int i = 0; i < 4; ++i) {
            float4 va = *(const float4*)(xp + i * 4);
            f[i*4] = va.x; f[i*4+1] = va.y; f[i*4+2] = va.z; f[i*4+3] = va.w;
            ssd += (double)va.x*va.x + (double)va.y*va.y
                 + (double)va.z*va.z + (double)va.w*va.w;
        }
        ssd += __shfl_xor(ssd, 1);
        ssd += __shfl_xor(ssd, 2);
        double invd = 1.0 / fmax(sqrt(ssd), 1e-12);
        if (part == 0) {
            invdst[row] = invd;
            ssnS[row] = (float)(ssd * invd * invd);
        }
        float inv = (float)invd;
        #pragma unroll
        for (int i = 0; i < 16; ++i) f[i] *= inv;
        #pragma unroll
        for (int cc = 0; cc < 2; ++cc) {
            unsigned hw[4], lw[4];
            #pragma unroll
            for (int j2 = 0; j2 < 4; ++j2) {
                float a = f[cc*8 + j2*2], b = f[cc*8 + j2*2 + 1];
                unsigned p = pk2(a, b);
                float ha = __uint_as_float(p << 16);
                float hb = __uint_as_float(p & 0xFFFF0000u);
                hw[j2] = p; lw[j2] = pk2(a - ha, b - hb);
            }
            int ch = part * 2 + cc;
            int phys = ch ^ (row & 7);
            *reinterpret_cast<uint4*>(&xhS[row * 64 + phys * 8]) = (uint4){hw[0],hw[1],hw[2],hw[3]};
            *reinterpret_cast<uint4*>(&xlS[row * 64 + phys * 8]) = (uint4){lw[0],lw[1],lw[2],lw[3]};
        }
    }
    __syncthreads();

    int l = tid & 63, w = tid >> 6;
    int lr = l & 15, lg = l >> 4;

    // ---- A frags: cluster tile w (reused across all 4 token tiles) ----
    bf16x8 mhF[2], mlF[2];
    #pragma unroll
    for (int ks = 0; ks < 2; ++ks) {
        int r2 = w * 16 + lr;
        int phys = (ks * 4 + lg) ^ (r2 & 7);
        mhF[ks] = *reinterpret_cast<const bf16x8*>(&mhS[r2 * 64 + phys * 8]);
        mlF[ks] = *reinterpret_cast<const bf16x8*>(&mlS[r2 * 64 + phys * 8]);
    }

    // ---- GEMM: D[c = w*16+lg*4+r][tok = tt*16+lr], 6 mfma per token tile ----
    f32x4 accT[4];
    size_t rowb = (size_t)(bh * NCC) * TT;
    #pragma unroll
    for (int tt = 0; tt < 4; ++tt) {
        bf16x8 xhF[2], xlF[2];
        #pragma unroll
        for (int ks = 0; ks < 2; ++ks) {
            int r2 = tt * 16 + lr;
            int phys = (ks * 4 + lg) ^ (r2 & 7);
            xhF[ks] = *reinterpret_cast<const bf16x8*>(&xhS[r2 * 64 + phys * 8]);
            xlF[ks] = *reinterpret_cast<const bf16x8*>(&xlS[r2 * 64 + phys * 8]);
        }
        f32x4 a = (f32x4){0.f, 0.f, 0.f, 0.f};
        #pragma unroll
        for (int ks = 0; ks < 2; ++ks)
            a = __builtin_amdgcn_mfma_f32_16x16x32_bf16(mhF[ks], xhF[ks], a, 0, 0, 0);
        #pragma unroll
        for (int ks = 0; ks < 2; ++ks)
            a = __builtin_amdgcn_mfma_f32_16x16x32_bf16(mhF[ks], xlF[ks], a, 0, 0, 0);
        #pragma unroll
        for (int ks = 0; ks < 2; ++ks)
            a = __builtin_amdgcn_mfma_f32_16x16x32_bf16(mlF[ks], xhF[ks], a, 0, 0, 0);
        accT[tt] = a;
        #pragma unroll
        for (int r2 = 0; r2 < 4; ++r2) {
            int c = w * 16 + lg * 4 + r2;
            dst[rowb + (size_t)c * TT + tbase + tt * 16 + lr] = a[r2];
        }
    }

    // ---- argmax via shuffles (lane: token tt*16+lr, clusters w*16+lg*4+r) ----
    #pragma unroll
    for (int tt = 0; tt < 4; ++tt) {
        float bv = accT[tt][0]; int bc = w * 16 + lg * 4;
        #pragma unroll
        for (int r2 = 1; r2 < 4; ++r2)
            if (accT[tt][r2] > bv) { bv = accT[tt][r2]; bc = w * 16 + lg * 4 + r2; }
        #pragma unroll
        for (int off = 16; off <= 32; off <<= 1) {
            float ov = __shfl_xor(bv, off);
            int   oc = __shfl_xor(bc, off);
            if (ov > bv || (ov == bv && oc < bc)) { bv = ov; bc = oc; }
        }
        if (lg == 0) {
            wMaxS[(tt * 16 + lr) * 5 + w] = bv;
            wIdxS[(tt * 16 + lr) * 5 + w] = bc;
        }
    }
    __syncthreads();

    if (tid < 64) {
        float bv = -1e30f; int bc = 0;
        #pragma unroll
        for (int w2 = 0; w2 < 4; ++w2) {   // ascending cluster ranges
            float ov = wMaxS[tid * 5 + w2];
            int   oc = wIdxS[tid * 5 + w2];
            if (ov > bv || (ov == bv && oc < bc)) { bv = ov; bc = oc; }
        }
        float auxv = ssnS[tid] + mqS[bc] - 2.f * bv;
        #pragma unroll
        for (int off = 32; off; off >>= 1) auxv += __shfl_xor(auxv, off);
        if (tid == 0) aux_part[bid] = auxv;
    }
}

// ---------------- Kernel B: top-TPK per row, 3-pass radix (12/12/8 bits) -------
__global__ __launch_bounds__(256) void topk_kernel(
    const float* __restrict__ dists, int* __restrict__ idxOut)
{
    int row = blockIdx.x;
    const float* dv = dists + (size_t)row * TT;
    int t = threadIdx.x;
    int lane = t & 63, w = t >> 6;

    unsigned u[16];
    #pragma unroll
    for (int j0 = 0; j0 < 4; ++j0) {
        float4 f = *(const float4*)(dv + t * 16 + j0 * 4);
        u[j0*4+0] = mono(f.x); u[j0*4+1] = mono(f.y);
        u[j0*4+2] = mono(f.z); u[j0*4+3] = mono(f.w);
    }

    __shared__ int hist[4096];
    __shared__ int wtot[4];
    __shared__ int binSel, tgtS;
    __shared__ int nGtS, posS, eqPos;

    int target = TPK;
    unsigned prefix = 0;

    // ---- passes 1,2: 12-bit digits over 4096 bins ----
    #pragma unroll
    for (int pass = 0; pass < 2; ++pass) {
        int4* hz = (int4*)&hist[t * 16];
        hz[0] = (int4){0,0,0,0}; hz[1] = (int4){0,0,0,0};
        hz[2] = (int4){0,0,0,0}; hz[3] = (int4){0,0,0,0};
        __syncthreads();
        if (pass == 0) {
            #pragma unroll
            for (int j = 0; j < 16; ++j) atomicAdd(&hist[u[j] >> 20], 1);
        } else {
            #pragma unroll
            for (int j = 0; j < 16; ++j)
                if ((u[j] >> 20) == (prefix >> 20))
                    atomicAdd(&hist[(u[j] >> 8) & 0xFFF], 1);
        }
        __syncthreads();
        int cnt[16], ls[16];
        {
            const int4* hp = (const int4*)&hist[t * 16];
            int4 c0 = hp[0], c1 = hp[1], c2 = hp[2], c3 = hp[3];
            cnt[0]=c0.x; cnt[1]=c0.y; cnt[2]=c0.z; cnt[3]=c0.w;
            cnt[4]=c1.x; cnt[5]=c1.y; cnt[6]=c1.z; cnt[7]=c1.w;
            cnt[8]=c2.x; cnt[9]=c2.y; cnt[10]=c2.z; cnt[11]=c2.w;
            cnt[12]=c3.x; cnt[13]=c3.y; cnt[14]=c3.z; cnt[15]=c3.w;
        }
        int run = 0;
        #pragma unroll
        for (int i = 15; i >= 0; --i) { run += cnt[i]; ls[i] = run; }
        int S = run;
        #pragma unroll
        for (int off = 1; off < 64; off <<= 1) {
            int o = __shfl_down(S, off);
            if (lane + off < 64) S += o;
        }
        if (lane == 0) wtot[w] = S;
        __syncthreads();
        int after = 0;
        for (int ww = w + 1; ww < 4; ++ww) after += wtot[ww];
        int St1 = S - run + after;      // suffix of bins owned by later threads
        #pragma unroll
        for (int i = 0; i < 16; ++i) {
            int sfxb = ls[i] + St1;
            if (sfxb >= target && sfxb - cnt[i] < target) {
                binSel = t * 16 + i; tgtS = target - (sfxb - cnt[i]);
            }
        }
        __syncthreads();
        prefix |= (pass == 0) ? ((unsigned)binSel << 20) : ((unsigned)binSel << 8);
        target = tgtS;
        __syncthreads();
    }

    // ---- pass 3: low 8 bits (256 bins) ----
    hist[t] = 0;
    __syncthreads();
    #pragma unroll
    for (int j = 0; j < 16; ++j)
        if ((u[j] >> 8) == (prefix >> 8))
            atomicAdd(&hist[u[j] & 0xFF], 1);
    __syncthreads();
    {
        int cnt = hist[t];
        int S = cnt;
        #pragma unroll
        for (int off = 1; off < 64; off <<= 1) {
            int o = __shfl_down(S, off);
            if (lane + off < 64) S += o;
        }
        if (lane == 0) wtot[w] = S;
        __syncthreads();
        int after = 0;
        for (int ww = w + 1; ww < 4; ++ww) after += wtot[ww];
        int sfx = S + after;
        if (sfx >= target && sfx - cnt < target) { binSel = t; tgtS = target - (sfx - cnt); }
    }
    __syncthreads();
    unsigned pivot = prefix | (unsigned)binSel;

    // ---- epilogue: compact >pivot, then ==pivot (unordered, capped) ----
    if (t == 0) { nGtS = 0; posS = 0; eqPos = 0; }
    __syncthreads();
    int myg = 0;
    #pragma unroll
    for (int j = 0; j < 16; ++j) myg += (u[j] > pivot) ? 1 : 0;
    if (myg) atomicAdd(&nGtS, myg);
    __syncthreads();
    int n_gt = nGtS;
    int n_need = TPK - n_gt;
    int* out = idxOut + (size_t)row * TPK;
    #pragma unroll
    for (int j = 0; j < 16; ++j) {
        if (u[j] > pivot) {
            int p = atomicAdd(&posS, 1);
            out[p] = t * 16 + j;
        } else if (u[j] == pivot) {
            int p = atomicAdd(&eqPos, 1);
            if (p < n_need) out[n_gt + p] = t * 16 + j;
        }
    }
}

// ---------------- Kernel B2: f64 rescore, branchless u32-prefix rank ----------
__global__ __launch_bounds__(640) void rescore_kernel(
    const float* __restrict__ q, const float* __restrict__ k,
    const float* __restrict__ means, const double* __restrict__ invn,
    const int* __restrict__ candQ, const int* __restrict__ candK,
    int* __restrict__ idxQ, int* __restrict__ idxK,
    int* __restrict__ counts)
{
    int bid = blockIdx.x;
    int rid = (bid & 7) * 512 + (bid >> 3);   // 4096 % 8 == 0 -> bijective
    int side = rid >> 11;            // 0=Q, 1=K
    int row = rid & 2047;            // bh*NC + c
    int c = row & (NCC - 1);
    int bh = row >> 6;
    int h = bh % HH;

    const int* cand = (side ? candK : candQ) + (size_t)row * TPK;
    int* outIdx     = (side ? idxK : idxQ) + (size_t)row * WSZW;
    const float* xbase = (side ? k : q) + (size_t)bh * TT * DD;
    const double* invp = invn + (side ? (size_t)BB * HH * TT : 0) + (size_t)bh * TT;

    __shared__ double   mD[DD];
    __shared__ unsigned hiS[TPK];
    __shared__ unsigned loS[TPK];
    __shared__ int      kiS[TPK];

    int tid = threadIdx.x;
    if (tid < DD) mD[tid] = (double)means[((size_t)h * NCC + c) * DD + tid];
    __syncthreads();

    int g = tid >> 2;                // candidate 0..159
    int qt = tid & 3;                // quarter-row 0..3
    int tok = cand[g];
    const float* xp = xbase + (size_t)tok * DD + qt * 16;
    double inv = invp[tok];          // 4 lanes same addr -> broadcast
    double d0 = 0.0, d1 = 0.0;
    #pragma unroll
    for (int i = 0; i < 2; ++i) {
        float4 va = *(const float4*)(xp + i * 4);
        int d = qt * 16 + i * 4;
        d0 += (double)va.x * mD[d]   + (double)va.y * mD[d+1]
            + (double)va.z * mD[d+2] + (double)va.w * mD[d+3];
    }
    #pragma unroll
    for (int i = 2; i < 4; ++i) {
        float4 va = *(const float4*)(xp + i * 4);
        int d = qt * 16 + i * 4;
        d1 += (double)va.x * mD[d]   + (double)va.y * mD[d+1]
            + (double)va.z * mD[d+2] + (double)va.w * mD[d+3];
    }
    double dot = d0 + d1;
    dot += __shfl_xor(dot, 1); dot += __shfl_xor(dot, 2);
    double v = dot * inv;            // identical across the 4-lane group
    unsigned long long key = mono64(v);
    unsigned myhi = (unsigned)(key >> 32), mylo = (unsigned)key;
    if (qt == 0) { hiS[g] = myhi; loS[g] = mylo; kiS[g] = tok; }
    __syncthreads();

    // phase 1: branchless rank on 32-bit prefixes (1 LDS b32 read per iter)
    int rk = 0, eq = 0;
    #pragma unroll 8
    for (int i = 0; i < TPK / 4; ++i) {
        unsigned hj = hiS[qt * (TPK / 4) + i];
        rk += (hj > myhi) ? 1 : 0;
        eq += (hj == myhi) ? 1 : 0;
    }
    rk += __shfl_xor(rk, 1); rk += __shfl_xor(rk, 2);
    eq += __shfl_xor(eq, 1); eq += __shfl_xor(eq, 2);

    // phase 2 (rare): exact 64-bit + token recount when hi-prefix ties exist
    if (eq > 1) {
        int rk2 = 0;
        for (int i = 0; i < TPK / 4; ++i) {
            int j = qt * (TPK / 4) + i;
            unsigned hj = hiS[j];
            if (hj > myhi) rk2++;
            else if (hj == myhi) {
                unsigned lj = loS[j];
                if (lj > mylo || (lj == mylo && kiS[j] < tok)) rk2++;
            }
        }
        rk2 += __shfl_xor(rk2, 1); rk2 += __shfl_xor(rk2, 2);
        rk = rk2;
    }

    if (qt == 0 && rk < WSZW) {
        outIdx[rk] = tok;
        if (side == 0) atomicAdd(&counts[bh * TT + tok], 1);
    }
}

// ---------------- Kernel C: bf16 MFMA attention, chase-free batched staging ----
__global__ __launch_bounds__(512, 2) void attn_kernel(
    const float* __restrict__ q, const float* __restrict__ k, const float* __restrict__ v,
    const float* __restrict__ mem_key, const float* __restrict__ mem_value,
    const int* __restrict__ idxQ, const int* __restrict__ idxK,
    float* __restrict__ so)
{
    // XCD-bijective swizzle (2048 % 8 == 0): 256 consecutive blks per XCD
    int bid = blockIdx.x;
    int blk = (bid & 7) * 256 + (bid >> 3);
    int c = blk % NCC;
    int bh = blk / NCC;
    int h = bh % HH;

    __shared__ __align__(16) unsigned short KsS[160 * 64];   // [kv][d] swizzled (temp V in P1/P2)
    __shared__ __align__(16) unsigned short VtS[64 * 168];   // [d][kv], pad 168

    int tid = threadIdx.x;
    int w = tid >> 6, l = tid & 63;
    int lr = l & 15, lg = l >> 4;

    const float* memK = mem_key   + ((size_t)h * NCC + c) * (MEMN * DD);
    const float* memV = mem_value + ((size_t)h * NCC + c) * (MEMN * DD);

    // ---- entry: resolve staging rows + issue ALL token-index gathers ----
    int stRow[3], stCh[3];
    bool stOk[3];
    const float *vsrcR[3], *ksrcR[3];
    #pragma unroll
    for (int s = 0; s < 3; ++s) {
        int idx = tid + s * 512;
        stOk[s] = idx < 1280;
        stRow[s] = idx >> 3; stCh[s] = idx & 7;
        vsrcR[s] = nullptr; ksrcR[s] = nullptr;
        if (stOk[s] && stRow[s] < KVW) {
            if (stRow[s] == 0) { vsrcR[s] = memV; ksrcR[s] = memK; }
            else {
                int tk = idxK[(size_t)blk * WSZW + stRow[s] - 1];
                vsrcR[s] = v + ((size_t)bh * TT + tk) * DD;
                ksrcR[s] = k + ((size_t)bh * TT + tk) * DD;
            }
        }
    }

    // ---- Q frags (independent chase, overlaps everything) ----
    bf16x8 qf[2];
    {
        int tq = idxQ[(size_t)blk * WSZW + w * 16 + lr];
        const float* qp = q + ((size_t)bh * TT + tq) * DD;
        #pragma unroll
        for (int ks = 0; ks < 2; ++ks) {
            float4 a = *(const float4*)(qp + ks * 32 + lg * 8);
            float4 b = *(const float4*)(qp + ks * 32 + lg * 8 + 4);
            qf[ks] = pack8(a, b);
        }
    }

    // ---- V gather window (batched) ----
    uint4 vw[3];
    #pragma unroll
    for (int s = 0; s < 3; ++s) {
        vw[s] = (uint4){0,0,0,0};
        if (vsrcR[s]) {
            float4 a = *(const float4*)(vsrcR[s] + stCh[s] * 8);
            float4 b = *(const float4*)(vsrcR[s] + stCh[s] * 8 + 4);
            vw[s].x = pk2(a.x, a.y); vw[s].y = pk2(a.z, a.w);
            vw[s].z = pk2(b.x, b.y); vw[s].w = pk2(b.z, b.w);
        }
    }
    // ---- K gather window (batched) ----
    uint4 kw[3];
    #pragma unroll
    for (int s = 0; s < 3; ++s) {
        kw[s] = (uint4){0,0,0,0};
        if (ksrcR[s]) {
            float4 a = *(const float4*)(ksrcR[s] + stCh[s] * 8);
            float4 b = *(const float4*)(ksrcR[s] + stCh[s] * 8 + 4);
            kw[s].x = pk2(a.x, a.y); kw[s].y = pk2(a.z, a.w);
            kw[s].z = pk2(b.x, b.y); kw[s].w = pk2(b.z, b.w);
        }
    }

    // ---- P1: V -> row-major swizzled (in KsS space) ----
    #pragma unroll
    for (int s = 0; s < 3; ++s)
        if (stOk[s])
            *reinterpret_cast<uint4*>(
                &KsS[stRow[s] * 64 + ((stCh[s] ^ (stRow[s] & 7)) * 8)]) = vw[s];
    __syncthreads();

    // ---- P2: Vt column segments -> regs (scalar broadcast-class reads) ----
    unsigned short vreg[3][8];
    #pragma unroll
    for (int s = 0; s < 3; ++s) {
        int idx = tid + s * 512;
        if (idx < 1280) {
            int d = idx & 63, rowblk = idx >> 6;
            #pragma unroll
            for (int i = 0; i < 8; ++i) {
                int row = rowblk * 8 + i;
                vreg[s][i] = KsS[row * 64 + (((d >> 3) ^ (row & 7)) * 8) + (d & 7)];
            }
        }
    }
    __syncthreads();

    // ---- P3: write Vt (b128 rows) + K (b128 swizzled) ----
    #pragma unroll
    for (int s = 0; s < 3; ++s) {
        int idx = tid + s * 512;
        if (idx < 1280) {
            int d = idx & 63, rowblk = idx >> 6;
            uint4 ow;
            ow.x = (unsigned)vreg[s][0] | ((unsigned)vreg[s][1] << 16);
            ow.y = (unsigned)vreg[s][2] | ((unsigned)vreg[s][3] << 16);
            ow.z = (unsigned)vreg[s][4] | ((unsigned)vreg[s][5] << 16);
            ow.w = (unsigned)vreg[s][6] | ((unsigned)vreg[s][7] << 16);
            *reinterpret_cast<uint4*>(&VtS[d * 168 + rowblk * 8]) = ow;
        }
    }
    #pragma unroll
    for (int s = 0; s < 3; ++s)
        if (stOk[s])
            *reinterpret_cast<uint4*>(
                &KsS[stRow[s] * 64 + ((stCh[s] ^ (stRow[s] & 7)) * 8)]) = kw[s];
    __syncthreads();

    // ---- compute (swapped QK^T, P in regs, Vt b128 B-frags) ----
    f32x4 acc[4];
    #pragma unroll
    for (int dt = 0; dt < 4; ++dt) acc[dt] = (f32x4){0.f, 0.f, 0.f, 0.f};
    float s_sum = 0.f;

    int src0 = lr + ((lg & 1) * 2) * 16;
    int src1 = src0 + 16;
    bool hi = (lg >> 1) != 0;

    for (int kb = 0; kb < 5; ++kb) {
        bf16x8 kf[2][2];
        #pragma unroll
        for (int kvt = 0; kvt < 2; ++kvt)
            #pragma unroll
            for (int ks = 0; ks < 2; ++ks) {
                int row = kb * 32 + kvt * 16 + lr;
                int chunk = ks * 4 + lg;
                int phys = chunk ^ (row & 7);
                kf[kvt][ks] = *reinterpret_cast<const bf16x8*>(&KsS[row * 64 + phys * 8]);
            }
        __builtin_amdgcn_s_setprio(1);
        unsigned pk[2][2];
        #pragma unroll
        for (int kvt = 0; kvt < 2; ++kvt) {
            f32x4 sf = __builtin_amdgcn_mfma_f32_16x16x32_bf16(
                kf[kvt][0], qf[0], (f32x4){0.f,0.f,0.f,0.f}, 0, 0, 0);
            sf = __builtin_amdgcn_mfma_f32_16x16x32_bf16(kf[kvt][1], qf[1], sf, 0, 0, 0);
            float e[4];
            #pragma unroll
            for (int r = 0; r < 4; ++r) {
                int kv = kb * 32 + kvt * 16 + lg * 4 + r;
                e[r] = (kv < KVW) ? __expf(sf[r] * SCALE) : 0.f;
                s_sum += e[r];
            }
            pk[kvt][0] = pk2(e[0], e[1]);
            pk[kvt][1] = pk2(e[2], e[3]);
        }
        unsigned a00 = __shfl(pk[0][0], src0), a01 = __shfl(pk[0][1], src0);
        unsigned a10 = __shfl(pk[1][0], src0), a11 = __shfl(pk[1][1], src0);
        unsigned b00 = __shfl(pk[0][0], src1), b01 = __shfl(pk[0][1], src1);
        unsigned b10 = __shfl(pk[1][0], src1), b11 = __shfl(pk[1][1], src1);
        union { unsigned u[4]; bf16x8 v; } pu;
        pu.u[0] = hi ? a10 : a00;
        pu.u[1] = hi ? a11 : a01;
        pu.u[2] = hi ? b10 : b00;
        pu.u[3] = hi ? b11 : b01;
        #pragma unroll
        for (int dt = 0; dt < 4; ++dt) {
            bf16x8 vf = *reinterpret_cast<const bf16x8*>(
                &VtS[(dt * 16 + lr) * 168 + kb * 32 + lg * 8]);
            acc[dt] = __builtin_amdgcn_mfma_f32_16x16x32_bf16(pu.v, vf, acc[dt], 0, 0, 0);
        }
        __builtin_amdgcn_s_setprio(0);
    }

    s_sum += __shfl_xor(s_sum, 16);
    s_sum += __shfl_xor(s_sum, 32);
    float sinv[4];
    #pragma unroll
    for (int r = 0; r < 4; ++r)
        sinv[r] = 1.f / __shfl(s_sum, lg * 4 + r);

    #pragma unroll
    for (int r = 0; r < 4; ++r) {
        int row = w * 16 + lg * 4 + r;
        float* op = so + (((size_t)blk * WSZW + row) * DD);
        #pragma unroll
        for (int dt = 0; dt < 4; ++dt)
            op[dt * 16 + lr] = acc[dt][r] * sinv[r];
    }
}

// ---------------- Kernel F: fused per-bh scan + CSR fill + aux finalize --------
__global__ __launch_bounds__(256) void scanfill_kernel(
    const int* __restrict__ counts, int* __restrict__ offs,
    const int* __restrict__ idxQ, int* __restrict__ csr,
    const float* __restrict__ auxp, float* __restrict__ out)
{
    __shared__ int offsL[TT];
    __shared__ int curL[TT];
    __shared__ int wsum[256];
    __shared__ float auxW[4];

    int bh = blockIdx.x;
    int t = threadIdx.x;

    // ---- aux fold (loads only on block 0; uniform barriers) ----
    float s = 0.f;
    if (bh == 0)
        for (int i = t; i < 4096; i += 256) s += auxp[i];
    #pragma unroll
    for (int off = 32; off; off >>= 1) s += __shfl_xor(s, off);
    if ((t & 63) == 0) auxW[t >> 6] = s;
    __syncthreads();
    if (bh == 0 && t == 0)
        out[(size_t)BB * HH * TT * DD] =
            (auxW[0] + auxW[1] + auxW[2] + auxW[3]) *
            (1.0f / (float)(BB * HH * 2 * TT * DD));

    // ---- exclusive scan over counts[bh] ----
    const int* cb = counts + (size_t)bh * TT;
    int* ob = offs + (size_t)bh * TT;
    int loc[16]; int sum = 0;
    #pragma unroll
    for (int i = 0; i < 16; ++i) { loc[i] = sum; sum += cb[t * 16 + i]; }
    wsum[t] = sum;
    __syncthreads();
    for (int off = 1; off < 256; off <<= 1) {
        int vv = (t >= off) ? wsum[t - off] : 0;
        __syncthreads();
        wsum[t] += vv;
        __syncthreads();
    }
    int ex = (t == 0) ? 0 : wsum[t - 1];
    #pragma unroll
    for (int i = 0; i < 16; ++i) {
        int o = ex + loc[i];
        ob[t * 16 + i] = o;
        offsL[t * 16 + i] = o;
        curL[t * 16 + i] = 0;
    }
    __syncthreads();

    // ---- CSR fill (LDS atomics) ----
    const int* iq = idxQ + ((size_t)bh << 13);
    int* cs = csr + ((size_t)bh << 13);
    for (int i = t; i < 8192; i += 256) {
        int tok = iq[i];
        int p = offsL[tok] + atomicAdd(&curL[tok], 1);
        cs[p] = i;
    }
}

// ---------------- Kernel H: gather-reduce + finalize ----------------
__global__ __launch_bounds__(256) void reduce_kernel(
    const float* __restrict__ so, const int* __restrict__ counts,
    const int* __restrict__ offs, const int* __restrict__ csr,
    float* __restrict__ out)
{
    int gt = blockIdx.x * 4 + (threadIdx.x >> 6);
    int lane = threadIdx.x & 63;
    int bh = gt >> 12;
    int n = counts[gt];
    int st = offs[gt];
    const int* cs = csr + ((size_t)bh << 13);
    float acc = 0.f;
    for (int j = 0; j < n; ++j) {
        int slot = cs[st + j];
        acc += so[(((size_t)bh << 13) + slot) * DD + lane];
    }
    out[(size_t)gt * DD + lane] = acc / ((float)n + EPSF);
}

extern "C" void kernel_launch(void* const* d_in, const int* in_sizes, int n_in,
                              void* d_out, int out_size, void* d_ws, size_t ws_size,
                              hipStream_t stream) {
    const float* q        = (const float*)d_in[0];
    const float* k        = (const float*)d_in[1];
    const float* v        = (const float*)d_in[2];
    const float* means    = (const float*)d_in[3];
    const float* mem_key  = (const float*)d_in[4];
    const float* mem_val  = (const float*)d_in[5];
    float* out = (float*)d_out;

    const size_t nRows = (size_t)BB * HH * NCC;             // 2048
    const size_t nTok  = (size_t)BB * HH * TT;              // 131072
    float* wsf    = (float*)d_ws;
    float* distsQ = wsf;                                    // 8388608 f
    float* distsK = distsQ + (size_t)BB * HH * NCC * TT;    // 8388608 f (contiguous after distsQ)
    float* so     = wsf;                                    // aliases dists; written after rescore
    int*   idxQ   = (int*)(distsK + (size_t)BB * HH * NCC * TT);  // 262144 i
    int*   idxK   = idxQ + nRows * WSZW;                    // 262144 i
    int*   counts = idxK + nRows * WSZW;                    // 131072 i
    float* auxp   = (float*)(counts + nTok);                // 4096 f (per-block partials)
    int*   offs   = (int*)(auxp + 4096);                    // 131072 i
    int*   csr    = offs + nTok;                            // 262144 i
    int*   candQ  = csr + nTok * 2;                         // 2048*160 i
    int*   candK  = candQ + nRows * TPK;                    // 2048*160 i (contiguous after candQ)
    uintptr_t ip  = (uintptr_t)(candK + nRows * TPK);
    ip = (ip + 15) & ~(uintptr_t)15;
    double* invn  = (double*)ip;                            // 2*131072 d (Q then K)

    hipMemsetAsync(counts, 0, nTok * sizeof(int), stream);

    dists_kernel<<<dim3(BB * HH * (2 * TT / 64)), dim3(256), 0, stream>>>(
        q, k, means, distsQ, distsK, auxp, invn);
    // single launch covers Q rows (0..2047 over distsQ/candQ) and K rows
    // (2048..4095 over distsK/candK) via buffer contiguity
    topk_kernel<<<dim3((unsigned)(2 * nRows)), dim3(256), 0, stream>>>(distsQ, candQ);
    rescore_kernel<<<dim3((unsigned)(2 * nRows)), dim3(640), 0, stream>>>(
        q, k, means, invn, candQ, candK, idxQ, idxK, counts);
    scanfill_kernel<<<dim3(BB * HH), dim3(256), 0, stream>>>(
        counts, offs, idxQ, csr, auxp, out);
    attn_kernel<<<dim3((unsigned)nRows), dim3(512), 0, stream>>>(
        q, k, v, mem_key, mem_val, idxQ, idxK, so);
    reduce_kernel<<<dim3((unsigned)(nTok / 4)), dim3(256), 0, stream>>>(
        so, counts, offs, csr, out);
}

// Round 22
// 195.827 us; speedup vs baseline: 1.3757x; 1.0727x over previous
//
#include <hip/hip_runtime.h>
#include <math.h>

#define BB 4
#define HH 8
#define TT 4096
#define DD 64
#define NCC 64
#define WSZW 128
#define TPK 160          // widened f32 top-k; f64 rescore picks exact top-128
#define MEMN 1
#define KVW (MEMN + WSZW)   // 129
constexpr float EPSF = 1e-5f;
constexpr float SCALE = 0.125f;  // 64^-0.5

typedef __attribute__((ext_vector_type(8))) short bf16x8;
typedef __attribute__((ext_vector_type(4))) float f32x4;

// HW packed f32->bf16 (RNE), 1 instruction vs ~7 for the manual bit-twiddle
static __device__ __forceinline__ unsigned int pk2(float a, float b) {
    unsigned int r;
    asm("v_cvt_pk_bf16_f32 %0, %1, %2" : "=v"(r) : "v"(a), "v"(b));
    return r;
}
static __device__ __forceinline__ bf16x8 pack8(float4 a, float4 b) {
    union { unsigned int u[4]; bf16x8 v; } r;
    r.u[0] = pk2(a.x, a.y); r.u[1] = pk2(a.z, a.w);
    r.u[2] = pk2(b.x, b.y); r.u[3] = pk2(b.z, b.w);
    return r.v;
}
static __device__ __forceinline__ unsigned mono(float f) {
    unsigned b = __float_as_uint(f);
    return b ^ ((unsigned)(((int)b) >> 31) | 0x80000000u);
}
static __device__ __forceinline__ unsigned long long mono64(double d) {
    unsigned long long b = (unsigned long long)__double_as_longlong(d);
    return b ^ (((long long)b < 0) ? ~0ULL : 0x8000000000000000ULL);
}

// ---------------- Kernel A: dists via split-bf16 MFMA + shuffle-argmax ----------
__global__ __launch_bounds__(256, 4) void dists_kernel(
    const float* __restrict__ q, const float* __restrict__ k,
    const float* __restrict__ means,
    float* __restrict__ distsQ, float* __restrict__ distsK,
    float* __restrict__ aux_part, double* __restrict__ invn)
{
    __shared__ __align__(16) unsigned short mhS[64 * 64];   // [c][d] swizzled chunks
    __shared__ __align__(16) unsigned short mlS[64 * 64];
    __shared__ __align__(16) unsigned short xhS[64 * 64];   // [tok][d]
    __shared__ __align__(16) unsigned short xlS[64 * 64];
    __shared__ float mqS[64];      // per-cluster ||m||^2
    __shared__ float ssnS[64];     // per-token ||xn||^2
    __shared__ float wMaxS[64 * 5];
    __shared__ int   wIdxS[64 * 5];

    const int chunks = (2 * TT) / 64;          // 128
    int bid0 = blockIdx.x;                     // 4096
    int bid = (bid0 & 7) * 512 + (bid0 >> 3);  // XCD-contiguous (4096 % 8 == 0)
    int bh = bid / chunks;
    int chunk = bid % chunks;
    int h = bh % HH;
    bool isQ = chunk < (TT / 64);
    int tbase = (isQ ? chunk : chunk - 64) * 64;
    const float* src = (isQ ? q : k) + ((size_t)bh * TT + tbase) * DD;
    float* dst = isQ ? distsQ : distsK;
    double* invdst = invn + (isQ ? 0 : (size_t)BB * HH * TT) + (size_t)bh * TT + tbase;

    int tid = threadIdx.x;
    int row = tid >> 2, part = tid & 3;        // row = cluster idx AND token idx

    // ---- stage means hi/lo (swizzled) + ||m||^2 ----
    {
        const float* mp = means + ((size_t)h * NCC + row) * DD + part * 16;
        float f[16];
        float msq = 0.f;
        #pragma unroll
        for (int i = 0; i < 4; ++i) {
            float4 va = *(const float4*)(mp + i * 4);
            f[i*4] = va.x; f[i*4+1] = va.y; f[i*4+2] = va.z; f[i*4+3] = va.w;
            msq += va.x*va.x + va.y*va.y + va.z*va.z + va.w*va.w;
        }
        msq += __shfl_xor(msq, 1);
        msq += __shfl_xor(msq, 2);
        if (part == 0) mqS[row] = msq;
        #pragma unroll
        for (int cc = 0; cc < 2; ++cc) {
            unsigned hw[4], lw[4];
            #pragma unroll
            for (int j2 = 0; j2 < 4; ++j2) {
                float a = f[cc*8 + j2*2], b = f[cc*8 + j2*2 + 1];
                unsigned p = pk2(a, b);
                float ha = __uint_as_float(p << 16);
                float hb = __uint_as_float(p & 0xFFFF0000u);
                hw[j2] = p; lw[j2] = pk2(a - ha, b - hb);
            }
            int ch = part * 2 + cc;
            int phys = ch ^ (row & 7);
            *reinterpret_cast<uint4*>(&mhS[row * 64 + phys * 8]) = (uint4){hw[0],hw[1],hw[2],hw[3]};
            *reinterpret_cast<uint4*>(&mlS[row * 64 + phys * 8]) = (uint4){lw[0],lw[1],lw[2],lw[3]};
        }
    }
    // ---- stage xn hi/lo (swizzled); f64 norm -> invn + ssn ----
    {
        const float* xp = src + (size_t)row * DD + part * 16;
        float f[16];
        double ssd = 0.0;
        #pragma unroll
        for (int i = 0; i < 4; ++i) {
            float4 va = *(const float4*)(xp + i * 4);
            f[i*4] = va.x; f[i*4+1] = va.y; f[i*4+2] = va.z; f[i*4+3] = va.w;
            ssd += (double)va.x*va.x + (double)va.y*va.y
                 + (double)va.z*va.z + (double)va.w*va.w;
        }
        ssd += __shfl_xor(ssd, 1);
        ssd += __shfl_xor(ssd, 2);
        double invd = 1.0 / fmax(sqrt(ssd), 1e-12);
        if (part == 0) {
            invdst[row] = invd;
            ssnS[row] = (float)(ssd * invd * invd);
        }
        float inv = (float)invd;
        #pragma unroll
        for (int i = 0; i < 16; ++i) f[i] *= inv;
        #pragma unroll
        for (int cc = 0; cc < 2; ++cc) {
            unsigned hw[4], lw[4];
            #pragma unroll
            for (int j2 = 0; j2 < 4; ++j2) {
                float a = f[cc*8 + j2*2], b = f[cc*8 + j2*2 + 1];
                unsigned p = pk2(a, b);
                float ha = __uint_as_float(p << 16);
                float hb = __uint_as_float(p & 0xFFFF0000u);
                hw[j2] = p; lw[j2] = pk2(a - ha, b - hb);
            }
            int ch = part * 2 + cc;
            int phys = ch ^ (row & 7);
            *reinterpret_cast<uint4*>(&xhS[row * 64 + phys * 8]) = (uint4){hw[0],hw[1],hw[2],hw[3]};
            *reinterpret_cast<uint4*>(&xlS[row * 64 + phys * 8]) = (uint4){lw[0],lw[1],lw[2],lw[3]};
        }
    }
    __syncthreads();

    int l = tid & 63, w = tid >> 6;
    int lr = l & 15, lg = l >> 4;

    // ---- A frags: cluster tile w (reused across all 4 token tiles) ----
    bf16x8 mhF[2], mlF[2];
    #pragma unroll
    for (int ks = 0; ks < 2; ++ks) {
        int r2 = w * 16 + lr;
        int phys = (ks * 4 + lg) ^ (r2 & 7);
        mhF[ks] = *reinterpret_cast<const bf16x8*>(&mhS[r2 * 64 + phys * 8]);
        mlF[ks] = *reinterpret_cast<const bf16x8*>(&mlS[r2 * 64 + phys * 8]);
    }

    // ---- GEMM: D[c = w*16+lg*4+r][tok = tt*16+lr], 6 mfma per token tile ----
    f32x4 accT[4];
    size_t rowb = (size_t)(bh * NCC) * TT;
    #pragma unroll
    for (int tt = 0; tt < 4; ++tt) {
        bf16x8 xhF[2], xlF[2];
        #pragma unroll
        for (int ks = 0; ks < 2; ++ks) {
            int r2 = tt * 16 + lr;
            int phys = (ks * 4 + lg) ^ (r2 & 7);
            xhF[ks] = *reinterpret_cast<const bf16x8*>(&xhS[r2 * 64 + phys * 8]);
            xlF[ks] = *reinterpret_cast<const bf16x8*>(&xlS[r2 * 64 + phys * 8]);
        }
        f32x4 a = (f32x4){0.f, 0.f, 0.f, 0.f};
        #pragma unroll
        for (int ks = 0; ks < 2; ++ks)
            a = __builtin_amdgcn_mfma_f32_16x16x32_bf16(mhF[ks], xhF[ks], a, 0, 0, 0);
        #pragma unroll
        for (int ks = 0; ks < 2; ++ks)
            a = __builtin_amdgcn_mfma_f32_16x16x32_bf16(mhF[ks], xlF[ks], a, 0, 0, 0);
        #pragma unroll
        for (int ks = 0; ks < 2; ++ks)
            a = __builtin_amdgcn_mfma_f32_16x16x32_bf16(mlF[ks], xhF[ks], a, 0, 0, 0);
        accT[tt] = a;
        #pragma unroll
        for (int r2 = 0; r2 < 4; ++r2) {
            int c = w * 16 + lg * 4 + r2;
            dst[rowb + (size_t)c * TT + tbase + tt * 16 + lr] = a[r2];
        }
    }

    // ---- argmax via shuffles (lane: token tt*16+lr, clusters w*16+lg*4+r) ----
    #pragma unroll
    for (int tt = 0; tt < 4; ++tt) {
        float bv = accT[tt][0]; int bc = w * 16 + lg * 4;
        #pragma unroll
        for (int r2 = 1; r2 < 4; ++r2)
            if (accT[tt][r2] > bv) { bv = accT[tt][r2]; bc = w * 16 + lg * 4 + r2; }
        #pragma unroll
        for (int off = 16; off <= 32; off <<= 1) {
            float ov = __shfl_xor(bv, off);
            int   oc = __shfl_xor(bc, off);
            if (ov > bv || (ov == bv && oc < bc)) { bv = ov; bc = oc; }
        }
        if (lg == 0) {
            wMaxS[(tt * 16 + lr) * 5 + w] = bv;
            wIdxS[(tt * 16 + lr) * 5 + w] = bc;
        }
    }
    __syncthreads();

    if (tid < 64) {
        float bv = -1e30f; int bc = 0;
        #pragma unroll
        for (int w2 = 0; w2 < 4; ++w2) {   // ascending cluster ranges
            float ov = wMaxS[tid * 5 + w2];
            int   oc = wIdxS[tid * 5 + w2];
            if (ov > bv || (ov == bv && oc < bc)) { bv = ov; bc = oc; }
        }
        float auxv = ssnS[tid] + mqS[bc] - 2.f * bv;
        #pragma unroll
        for (int off = 32; off; off >>= 1) auxv += __shfl_xor(auxv, off);
        if (tid == 0) aux_part[bid] = auxv;
    }
}

// ---------------- Kernel B: top-TPK per row, 3-pass radix (12/12/8 bits) -------
__global__ __launch_bounds__(256) void topk_kernel(
    const float* __restrict__ dists, int* __restrict__ idxOut)
{
    int row = blockIdx.x;
    const float* dv = dists + (size_t)row * TT;
    int t = threadIdx.x;
    int lane = t & 63, w = t >> 6;

    unsigned u[16];
    #pragma unroll
    for (int j0 = 0; j0 < 4; ++j0) {
        float4 f = *(const float4*)(dv + t * 16 + j0 * 4);
        u[j0*4+0] = mono(f.x); u[j0*4+1] = mono(f.y);
        u[j0*4+2] = mono(f.z); u[j0*4+3] = mono(f.w);
    }

    __shared__ int hist[4096];
    __shared__ int wtot[4];
    __shared__ int binSel, tgtS;
    __shared__ int nGtS, posS, eqPos;

    int target = TPK;
    unsigned prefix = 0;

    // ---- passes 1,2: 12-bit digits over 4096 bins ----
    #pragma unroll
    for (int pass = 0; pass < 2; ++pass) {
        int4* hz = (int4*)&hist[t * 16];
        hz[0] = (int4){0,0,0,0}; hz[1] = (int4){0,0,0,0};
        hz[2] = (int4){0,0,0,0}; hz[3] = (int4){0,0,0,0};
        __syncthreads();
        if (pass == 0) {
            #pragma unroll
            for (int j = 0; j < 16; ++j) atomicAdd(&hist[u[j] >> 20], 1);
        } else {
            #pragma unroll
            for (int j = 0; j < 16; ++j)
                if ((u[j] >> 20) == (prefix >> 20))
                    atomicAdd(&hist[(u[j] >> 8) & 0xFFF], 1);
        }
        __syncthreads();
        int cnt[16], ls[16];
        {
            const int4* hp = (const int4*)&hist[t * 16];
            int4 c0 = hp[0], c1 = hp[1], c2 = hp[2], c3 = hp[3];
            cnt[0]=c0.x; cnt[1]=c0.y; cnt[2]=c0.z; cnt[3]=c0.w;
            cnt[4]=c1.x; cnt[5]=c1.y; cnt[6]=c1.z; cnt[7]=c1.w;
            cnt[8]=c2.x; cnt[9]=c2.y; cnt[10]=c2.z; cnt[11]=c2.w;
            cnt[12]=c3.x; cnt[13]=c3.y; cnt[14]=c3.z; cnt[15]=c3.w;
        }
        int run = 0;
        #pragma unroll
        for (int i = 15; i >= 0; --i) { run += cnt[i]; ls[i] = run; }
        int S = run;
        #pragma unroll
        for (int off = 1; off < 64; off <<= 1) {
            int o = __shfl_down(S, off);
            if (lane + off < 64) S += o;
        }
        if (lane == 0) wtot[w] = S;
        __syncthreads();
        int after = 0;
        for (int ww = w + 1; ww < 4; ++ww) after += wtot[ww];
        int St1 = S - run + after;      // suffix of bins owned by later threads
        #pragma unroll
        for (int i = 0; i < 16; ++i) {
            int sfxb = ls[i] + St1;
            if (sfxb >= target && sfxb - cnt[i] < target) {
                binSel = t * 16 + i; tgtS = target - (sfxb - cnt[i]);
            }
        }
        __syncthreads();
        prefix |= (pass == 0) ? ((unsigned)binSel << 20) : ((unsigned)binSel << 8);
        target = tgtS;
        __syncthreads();
    }

    // ---- pass 3: low 8 bits (256 bins) ----
    hist[t] = 0;
    __syncthreads();
    #pragma unroll
    for (int j = 0; j < 16; ++j)
        if ((u[j] >> 8) == (prefix >> 8))
            atomicAdd(&hist[u[j] & 0xFF], 1);
    __syncthreads();
    {
        int cnt = hist[t];
        int S = cnt;
        #pragma unroll
        for (int off = 1; off < 64; off <<= 1) {
            int o = __shfl_down(S, off);
            if (lane + off < 64) S += o;
        }
        if (lane == 0) wtot[w] = S;
        __syncthreads();
        int after = 0;
        for (int ww = w + 1; ww < 4; ++ww) after += wtot[ww];
        int sfx = S + after;
        if (sfx >= target && sfx - cnt < target) { binSel = t; tgtS = target - (sfx - cnt); }
    }
    __syncthreads();
    unsigned pivot = prefix | (unsigned)binSel;

    // ---- epilogue: compact >pivot, then ==pivot (unordered, capped) ----
    if (t == 0) { nGtS = 0; posS = 0; eqPos = 0; }
    __syncthreads();
    int myg = 0;
    #pragma unroll
    for (int j = 0; j < 16; ++j) myg += (u[j] > pivot) ? 1 : 0;
    if (myg) atomicAdd(&nGtS, myg);
    __syncthreads();
    int n_gt = nGtS;
    int n_need = TPK - n_gt;
    int* out = idxOut + (size_t)row * TPK;
    #pragma unroll
    for (int j = 0; j < 16; ++j) {
        if (u[j] > pivot) {
            int p = atomicAdd(&posS, 1);
            out[p] = t * 16 + j;
        } else if (u[j] == pivot) {
            int p = atomicAdd(&eqPos, 1);
            if (p < n_need) out[n_gt + p] = t * 16 + j;
        }
    }
}

// ---------------- Kernel B2: f64 rescore, branchless u32-prefix rank ----------
__global__ __launch_bounds__(640) void rescore_kernel(
    const float* __restrict__ q, const float* __restrict__ k,
    const float* __restrict__ means, const double* __restrict__ invn,
    const int* __restrict__ candQ, const int* __restrict__ candK,
    int* __restrict__ idxQ, int* __restrict__ idxK,
    int* __restrict__ counts)
{
    int bid = blockIdx.x;
    int rid = (bid & 7) * 512 + (bid >> 3);   // 4096 % 8 == 0 -> bijective
    int side = rid >> 11;            // 0=Q, 1=K
    int row = rid & 2047;            // bh*NC + c
    int c = row & (NCC - 1);
    int bh = row >> 6;
    int h = bh % HH;

    const int* cand = (side ? candK : candQ) + (size_t)row * TPK;
    int* outIdx     = (side ? idxK : idxQ) + (size_t)row * WSZW;
    const float* xbase = (side ? k : q) + (size_t)bh * TT * DD;
    const double* invp = invn + (side ? (size_t)BB * HH * TT : 0) + (size_t)bh * TT;

    __shared__ double   mD[DD];
    __shared__ unsigned hiS[TPK];
    __shared__ unsigned loS[TPK];
    __shared__ int      kiS[TPK];

    int tid = threadIdx.x;
    if (tid < DD) mD[tid] = (double)means[((size_t)h * NCC + c) * DD + tid];
    __syncthreads();

    int g = tid >> 2;                // candidate 0..159
    int qt = tid & 3;                // quarter-row 0..3
    int tok = cand[g];
    const float* xp = xbase + (size_t)tok * DD + qt * 16;
    double inv = invp[tok];          // 4 lanes same addr -> broadcast
    double d0 = 0.0, d1 = 0.0;
    #pragma unroll
    for (int i = 0; i < 2; ++i) {
        float4 va = *(const float4*)(xp + i * 4);
        int d = qt * 16 + i * 4;
        d0 += (double)va.x * mD[d]   + (double)va.y * mD[d+1]
            + (double)va.z * mD[d+2] + (double)va.w * mD[d+3];
    }
    #pragma unroll
    for (int i = 2; i < 4; ++i) {
        float4 va = *(const float4*)(xp + i * 4);
        int d = qt * 16 + i * 4;
        d1 += (double)va.x * mD[d]   + (double)va.y * mD[d+1]
            + (double)va.z * mD[d+2] + (double)va.w * mD[d+3];
    }
    double dot = d0 + d1;
    dot += __shfl_xor(dot, 1); dot += __shfl_xor(dot, 2);
    double v = dot * inv;            // identical across the 4-lane group
    unsigned long long key = mono64(v);
    unsigned myhi = (unsigned)(key >> 32), mylo = (unsigned)key;
    if (qt == 0) { hiS[g] = myhi; loS[g] = mylo; kiS[g] = tok; }
    __syncthreads();

    // phase 1: branchless rank on 32-bit prefixes (1 LDS b32 read per iter)
    int rk = 0, eq = 0;
    #pragma unroll 8
    for (int i = 0; i < TPK / 4; ++i) {
        unsigned hj = hiS[qt * (TPK / 4) + i];
        rk += (hj > myhi) ? 1 : 0;
        eq += (hj == myhi) ? 1 : 0;
    }
    rk += __shfl_xor(rk, 1); rk += __shfl_xor(rk, 2);
    eq += __shfl_xor(eq, 1); eq += __shfl_xor(eq, 2);

    // phase 2 (rare): exact 64-bit + token recount when hi-prefix ties exist
    if (eq > 1) {
        int rk2 = 0;
        for (int i = 0; i < TPK / 4; ++i) {
            int j = qt * (TPK / 4) + i;
            unsigned hj = hiS[j];
            if (hj > myhi) rk2++;
            else if (hj == myhi) {
                unsigned lj = loS[j];
                if (lj > mylo || (lj == mylo && kiS[j] < tok)) rk2++;
            }
        }
        rk2 += __shfl_xor(rk2, 1); rk2 += __shfl_xor(rk2, 2);
        rk = rk2;
    }

    if (qt == 0 && rk < WSZW) {
        outIdx[rk] = tok;
        if (side == 0) atomicAdd(&counts[bh * TT + tok], 1);
    }
}

// ---------------- Kernel C: bf16 MFMA attention, 130-row LDS (4 blocks/CU) -----
// Pad rows kv>=129 are never stored: every LDS access clamps row->128 (their
// P weights are exactly 0, so values are irrelevant; clamped data is finite).
// LDS 38144 B -> 4 blocks/CU (was 41984 -> 2).
__global__ __launch_bounds__(512, 8) void attn_kernel(
    const float* __restrict__ q, const float* __restrict__ k, const float* __restrict__ v,
    const float* __restrict__ mem_key, const float* __restrict__ mem_value,
    const int* __restrict__ idxQ, const int* __restrict__ idxK,
    float* __restrict__ so)
{
    // XCD-bijective swizzle (2048 % 8 == 0): 256 consecutive blks per XCD
    int bid = blockIdx.x;
    int blk = (bid & 7) * 256 + (bid >> 3);
    int c = blk % NCC;
    int bh = blk / NCC;
    int h = bh % HH;

    __shared__ __align__(16) unsigned short KsS[130 * 64];   // [kv][d] swizzled (temp V in P1/P2)
    __shared__ __align__(16) unsigned short VtS[64 * 168];   // [d][kv], pad 168

    int tid = threadIdx.x;
    int w = tid >> 6, l = tid & 63;
    int lr = l & 15, lg = l >> 4;

    const float* memK = mem_key   + ((size_t)h * NCC + c) * (MEMN * DD);
    const float* memV = mem_value + ((size_t)h * NCC + c) * (MEMN * DD);

    // ---- entry: resolve staging rows + issue ALL token-index gathers ----
    int stRow[3], stCh[3];
    const float *vsrcR[3], *ksrcR[3];
    #pragma unroll
    for (int s = 0; s < 3; ++s) {
        int idx = tid + s * 512;
        stRow[s] = idx >> 3; stCh[s] = idx & 7;
        vsrcR[s] = nullptr; ksrcR[s] = nullptr;
        if (idx < 1280 && stRow[s] < KVW) {
            if (stRow[s] == 0) { vsrcR[s] = memV; ksrcR[s] = memK; }
            else {
                int tk = idxK[(size_t)blk * WSZW + stRow[s] - 1];
                vsrcR[s] = v + ((size_t)bh * TT + tk) * DD;
                ksrcR[s] = k + ((size_t)bh * TT + tk) * DD;
            }
        }
    }

    // ---- Q frags (independent chase, overlaps everything) ----
    bf16x8 qf[2];
    {
        int tq = idxQ[(size_t)blk * WSZW + w * 16 + lr];
        const float* qp = q + ((size_t)bh * TT + tq) * DD;
        #pragma unroll
        for (int ks = 0; ks < 2; ++ks) {
            float4 a = *(const float4*)(qp + ks * 32 + lg * 8);
            float4 b = *(const float4*)(qp + ks * 32 + lg * 8 + 4);
            qf[ks] = pack8(a, b);
        }
    }

    // ---- V gather window (batched) ----
    uint4 vw[3];
    #pragma unroll
    for (int s = 0; s < 3; ++s) {
        vw[s] = (uint4){0,0,0,0};
        if (vsrcR[s]) {
            float4 a = *(const float4*)(vsrcR[s] + stCh[s] * 8);
            float4 b = *(const float4*)(vsrcR[s] + stCh[s] * 8 + 4);
            vw[s].x = pk2(a.x, a.y); vw[s].y = pk2(a.z, a.w);
            vw[s].z = pk2(b.x, b.y); vw[s].w = pk2(b.z, b.w);
        }
    }
    // ---- K gather window (batched) ----
    uint4 kw[3];
    #pragma unroll
    for (int s = 0; s < 3; ++s) {
        kw[s] = (uint4){0,0,0,0};
        if (ksrcR[s]) {
            float4 a = *(const float4*)(ksrcR[s] + stCh[s] * 8);
            float4 b = *(const float4*)(ksrcR[s] + stCh[s] * 8 + 4);
            kw[s].x = pk2(a.x, a.y); kw[s].y = pk2(a.z, a.w);
            kw[s].z = pk2(b.x, b.y); kw[s].w = pk2(b.z, b.w);
        }
    }

    // ---- P1: V -> row-major swizzled (valid rows only) ----
    #pragma unroll
    for (int s = 0; s < 3; ++s)
        if (vsrcR[s])
            *reinterpret_cast<uint4*>(
                &KsS[stRow[s] * 64 + ((stCh[s] ^ (stRow[s] & 7)) * 8)]) = vw[s];
    __syncthreads();

    // ---- P2: Vt column segments -> regs (clamped rows; broadcast-class) ----
    unsigned short vreg[3][8];
    #pragma unroll
    for (int s = 0; s < 3; ++s) {
        int idx = tid + s * 512;
        if (idx < 1280) {
            int d = idx & 63, rowblk = idx >> 6;
            #pragma unroll
            for (int i = 0; i < 8; ++i) {
                int row = rowblk * 8 + i;
                int pr = (row < KVW) ? row : 128;
                vreg[s][i] = KsS[pr * 64 + (((d >> 3) ^ (pr & 7)) * 8) + (d & 7)];
            }
        }
    }
    __syncthreads();

    // ---- P3: write Vt (b128 rows) + K (valid rows only) ----
    #pragma unroll
    for (int s = 0; s < 3; ++s) {
        int idx = tid + s * 512;
        if (idx < 1280) {
            int d = idx & 63, rowblk = idx >> 6;
            uint4 ow;
            ow.x = (unsigned)vreg[s][0] | ((unsigned)vreg[s][1] << 16);
            ow.y = (unsigned)vreg[s][2] | ((unsigned)vreg[s][3] << 16);
            ow.z = (unsigned)vreg[s][4] | ((unsigned)vreg[s][5] << 16);
            ow.w = (unsigned)vreg[s][6] | ((unsigned)vreg[s][7] << 16);
            *reinterpret_cast<uint4*>(&VtS[d * 168 + rowblk * 8]) = ow;
        }
    }
    #pragma unroll
    for (int s = 0; s < 3; ++s)
        if (ksrcR[s])
            *reinterpret_cast<uint4*>(
                &KsS[stRow[s] * 64 + ((stCh[s] ^ (stRow[s] & 7)) * 8)]) = kw[s];
    __syncthreads();

    // ---- compute (swapped QK^T, P in regs, Vt b128 B-frags) ----
    f32x4 acc[4];
    #pragma unroll
    for (int dt = 0; dt < 4; ++dt) acc[dt] = (f32x4){0.f, 0.f, 0.f, 0.f};
    float s_sum = 0.f;

    int src0 = lr + ((lg & 1) * 2) * 16;
    int src1 = src0 + 16;
    bool hi = (lg >> 1) != 0;

    for (int kb = 0; kb < 5; ++kb) {
        bf16x8 kf[2][2];
        #pragma unroll
        for (int kvt = 0; kvt < 2; ++kvt)
            #pragma unroll
            for (int ks = 0; ks < 2; ++ks) {
                int row = kb * 32 + kvt * 16 + lr;
                int pr = (row < KVW) ? row : 128;
                int phys = (ks * 4 + lg) ^ (pr & 7);
                kf[kvt][ks] = *reinterpret_cast<const bf16x8*>(&KsS[pr * 64 + phys * 8]);
            }
        __builtin_amdgcn_s_setprio(1);
        unsigned pk[2][2];
        #pragma unroll
        for (int kvt = 0; kvt < 2; ++kvt) {
            f32x4 sf = __builtin_amdgcn_mfma_f32_16x16x32_bf16(
                kf[kvt][0], qf[0], (f32x4){0.f,0.f,0.f,0.f}, 0, 0, 0);
            sf = __builtin_amdgcn_mfma_f32_16x16x32_bf16(kf[kvt][1], qf[1], sf, 0, 0, 0);
            float e[4];
            #pragma unroll
            for (int r = 0; r < 4; ++r) {
                int kv = kb * 32 + kvt * 16 + lg * 4 + r;
                e[r] = (kv < KVW) ? __expf(sf[r] * SCALE) : 0.f;
                s_sum += e[r];
            }
            pk[kvt][0] = pk2(e[0], e[1]);
            pk[kvt][1] = pk2(e[2], e[3]);
        }
        unsigned a00 = __shfl(pk[0][0], src0), a01 = __shfl(pk[0][1], src0);
        unsigned a10 = __shfl(pk[1][0], src0), a11 = __shfl(pk[1][1], src0);
        unsigned b00 = __shfl(pk[0][0], src1), b01 = __shfl(pk[0][1], src1);
        unsigned b10 = __shfl(pk[1][0], src1), b11 = __shfl(pk[1][1], src1);
        union { unsigned u[4]; bf16x8 v; } pu;
        pu.u[0] = hi ? a10 : a00;
        pu.u[1] = hi ? a11 : a01;
        pu.u[2] = hi ? b10 : b00;
        pu.u[3] = hi ? b11 : b01;
        #pragma unroll
        for (int dt = 0; dt < 4; ++dt) {
            bf16x8 vf = *reinterpret_cast<const bf16x8*>(
                &VtS[(dt * 16 + lr) * 168 + kb * 32 + lg * 8]);
            acc[dt] = __builtin_amdgcn_mfma_f32_16x16x32_bf16(pu.v, vf, acc[dt], 0, 0, 0);
        }
        __builtin_amdgcn_s_setprio(0);
    }

    s_sum += __shfl_xor(s_sum, 16);
    s_sum += __shfl_xor(s_sum, 32);
    float sinv[4];
    #pragma unroll
    for (int r = 0; r < 4; ++r)
        sinv[r] = 1.f / __shfl(s_sum, lg * 4 + r);

    #pragma unroll
    for (int r = 0; r < 4; ++r) {
        int row = w * 16 + lg * 4 + r;
        float* op = so + (((size_t)blk * WSZW + row) * DD);
        #pragma unroll
        for (int dt = 0; dt < 4; ++dt)
            op[dt * 16 + lr] = acc[dt][r] * sinv[r];
    }
}

// ---------------- Kernel F: fused per-bh scan + CSR fill + aux finalize --------
__global__ __launch_bounds__(256) void scanfill_kernel(
    const int* __restrict__ counts, int* __restrict__ offs,
    const int* __restrict__ idxQ, int* __restrict__ csr,
    const float* __restrict__ auxp, float* __restrict__ out)
{
    __shared__ int offsL[TT];
    __shared__ int curL[TT];
    __shared__ int wsum[256];
    __shared__ float auxW[4];

    int bh = blockIdx.x;
    int t = threadIdx.x;

    // ---- aux fold (loads only on block 0; uniform barriers) ----
    float s = 0.f;
    if (bh == 0)
        for (int i = t; i < 4096; i += 256) s += auxp[i];
    #pragma unroll
    for (int off = 32; off; off >>= 1) s += __shfl_xor(s, off);
    if ((t & 63) == 0) auxW[t >> 6] = s;
    __syncthreads();
    if (bh == 0 && t == 0)
        out[(size_t)BB * HH * TT * DD] =
            (auxW[0] + auxW[1] + auxW[2] + auxW[3]) *
            (1.0f / (float)(BB * HH * 2 * TT * DD));

    // ---- exclusive scan over counts[bh] ----
    const int* cb = counts + (size_t)bh * TT;
    int* ob = offs + (size_t)bh * TT;
    int loc[16]; int sum = 0;
    #pragma unroll
    for (int i = 0; i < 16; ++i) { loc[i] = sum; sum += cb[t * 16 + i]; }
    wsum[t] = sum;
    __syncthreads();
    for (int off = 1; off < 256; off <<= 1) {
        int vv = (t >= off) ? wsum[t - off] : 0;
        __syncthreads();
        wsum[t] += vv;
        __syncthreads();
    }
    int ex = (t == 0) ? 0 : wsum[t - 1];
    #pragma unroll
    for (int i = 0; i < 16; ++i) {
        int o = ex + loc[i];
        ob[t * 16 + i] = o;
        offsL[t * 16 + i] = o;
        curL[t * 16 + i] = 0;
    }
    __syncthreads();

    // ---- CSR fill (LDS atomics) ----
    const int* iq = idxQ + ((size_t)bh << 13);
    int* cs = csr + ((size_t)bh << 13);
    for (int i = t; i < 8192; i += 256) {
        int tok = iq[i];
        int p = offsL[tok] + atomicAdd(&curL[tok], 1);
        cs[p] = i;
    }
}

// ---------------- Kernel H: gather-reduce, pair-batched + XCD swizzle ----------
__global__ __launch_bounds__(256) void reduce_kernel(
    const float* __restrict__ so, const int* __restrict__ counts,
    const int* __restrict__ offs, const int* __restrict__ csr,
    float* __restrict__ out)
{
    int b0 = blockIdx.x;
    int b = (b0 & 7) * 4096 + (b0 >> 3);     // 32768 % 8 == 0 -> bijective
    int gt = b * 4 + (threadIdx.x >> 6);
    int lane = threadIdx.x & 63;
    int bh = gt >> 12;
    int n = counts[gt];
    int st = offs[gt];
    const int* cs = csr + ((size_t)bh << 13);
    const float* sob = so + (((size_t)bh << 13) * DD);
    float acc = 0.f;
    int j = 0;
    for (; j + 2 <= n; j += 2) {             // pair-batched: 2 idx, then 2 rows
        int s0 = cs[st + j], s1 = cs[st + j + 1];
        float v0 = sob[(size_t)s0 * DD + lane];
        float v1 = sob[(size_t)s1 * DD + lane];
        acc += v0 + v1;
    }
    if (j < n) acc += sob[(size_t)cs[st + j] * DD + lane];
    out[(size_t)gt * DD + lane] = acc / ((float)n + EPSF);
}

extern "C" void kernel_launch(void* const* d_in, const int* in_sizes, int n_in,
                              void* d_out, int out_size, void* d_ws, size_t ws_size,
                              hipStream_t stream) {
    const float* q        = (const float*)d_in[0];
    const float* k        = (const float*)d_in[1];
    const float* v        = (const float*)d_in[2];
    const float* means    = (const float*)d_in[3];
    const float* mem_key  = (const float*)d_in[4];
    const float* mem_val  = (const float*)d_in[5];
    float* out = (float*)d_out;

    const size_t nRows = (size_t)BB * HH * NCC;             // 2048
    const size_t nTok  = (size_t)BB * HH * TT;              // 131072
    float* wsf    = (float*)d_ws;
    float* distsQ = wsf;                                    // 8388608 f
    float* distsK = distsQ + (size_t)BB * HH * NCC * TT;    // 8388608 f (contiguous after distsQ)
    float* so     = wsf;                                    // aliases dists; written after rescore
    int*   idxQ   = (int*)(distsK + (size_t)BB * HH * NCC * TT);  // 262144 i
    int*   idxK   = idxQ + nRows * WSZW;                    // 262144 i
    int*   counts = idxK + nRows * WSZW;                    // 131072 i
    float* auxp   = (float*)(counts + nTok);                // 4096 f (per-block partials)
    int*   offs   = (int*)(auxp + 4096);                    // 131072 i
    int*   csr    = offs + nTok;                            // 262144 i
    int*   candQ  = csr + nTok * 2;                         // 2048*160 i
    int*   candK  = candQ + nRows * TPK;                    // 2048*160 i (contiguous after candQ)
    uintptr_t ip  = (uintptr_t)(candK + nRows * TPK);
    ip = (ip + 15) & ~(uintptr_t)15;
    double* invn  = (double*)ip;                            // 2*131072 d (Q then K)

    hipMemsetAsync(counts, 0, nTok * sizeof(int), stream);

    dists_kernel<<<dim3(BB * HH * (2 * TT / 64)), dim3(256), 0, stream>>>(
        q, k, means, distsQ, distsK, auxp, invn);
    // single launch covers Q rows (0..2047 over distsQ/candQ) and K rows
    // (2048..4095 over distsK/candK) via buffer contiguity
    topk_kernel<<<dim3((unsigned)(2 * nRows)), dim3(256), 0, stream>>>(distsQ, candQ);
    rescore_kernel<<<dim3((unsigned)(2 * nRows)), dim3(640), 0, stream>>>(
        q, k, means, invn, candQ, candK, idxQ, idxK, counts);
    scanfill_kernel<<<dim3(BB * HH), dim3(256), 0, stream>>>(
        counts, offs, idxQ, csr, auxp, out);
    attn_kernel<<<dim3((unsigned)nRows), dim3(512), 0, stream>>>(
        q, k, v, mem_key, mem_val, idxQ, idxK, so);
    reduce_kernel<<<dim3((unsigned)(nTok / 4)), dim3(256), 0, stream>>>(
        so, counts, offs, csr, out);
}

// Round 23
// 191.878 us; speedup vs baseline: 1.4040x; 1.0206x over previous
//
#include <hip/hip_runtime.h>
#include <math.h>

#define BB 4
#define HH 8
#define TT 4096
#define DD 64
#define NCC 64
#define WSZW 128
#define TPK 160          // widened f32 top-k; f64 rescore picks exact top-128
#define MEMN 1
#define KVW (MEMN + WSZW)   // 129
constexpr float EPSF = 1e-5f;
constexpr float SCALE = 0.125f;  // 64^-0.5

typedef __attribute__((ext_vector_type(8))) short bf16x8;
typedef __attribute__((ext_vector_type(4))) float f32x4;

// HW packed f32->bf16 (RNE), 1 instruction vs ~7 for the manual bit-twiddle
static __device__ __forceinline__ unsigned int pk2(float a, float b) {
    unsigned int r;
    asm("v_cvt_pk_bf16_f32 %0, %1, %2" : "=v"(r) : "v"(a), "v"(b));
    return r;
}
static __device__ __forceinline__ bf16x8 pack8(float4 a, float4 b) {
    union { unsigned int u[4]; bf16x8 v; } r;
    r.u[0] = pk2(a.x, a.y); r.u[1] = pk2(a.z, a.w);
    r.u[2] = pk2(b.x, b.y); r.u[3] = pk2(b.z, b.w);
    return r.v;
}
static __device__ __forceinline__ unsigned mono(float f) {
    unsigned b = __float_as_uint(f);
    return b ^ ((unsigned)(((int)b) >> 31) | 0x80000000u);
}
static __device__ __forceinline__ unsigned long long mono64(double d) {
    unsigned long long b = (unsigned long long)__double_as_longlong(d);
    return b ^ (((long long)b < 0) ? ~0ULL : 0x8000000000000000ULL);
}
static __device__ __forceinline__ float bf2f(unsigned short u) {
    return __uint_as_float(((unsigned)u) << 16);
}

// ---------------- Kernel A: dists via split-bf16 MFMA + shuffle-argmax ----------
__global__ __launch_bounds__(256, 4) void dists_kernel(
    const float* __restrict__ q, const float* __restrict__ k,
    const float* __restrict__ means,
    float* __restrict__ distsQ, float* __restrict__ distsK,
    float* __restrict__ aux_part, double* __restrict__ invn)
{
    __shared__ __align__(16) unsigned short mhS[64 * 64];   // [c][d] swizzled chunks
    __shared__ __align__(16) unsigned short mlS[64 * 64];
    __shared__ __align__(16) unsigned short xhS[64 * 64];   // [tok][d]
    __shared__ __align__(16) unsigned short xlS[64 * 64];
    __shared__ float mqS[64];      // per-cluster ||m||^2
    __shared__ float ssnS[64];     // per-token ||xn||^2
    __shared__ float wMaxS[64 * 5];
    __shared__ int   wIdxS[64 * 5];

    const int chunks = (2 * TT) / 64;          // 128
    int bid0 = blockIdx.x;                     // 4096
    int bid = (bid0 & 7) * 512 + (bid0 >> 3);  // XCD-contiguous (4096 % 8 == 0)
    int bh = bid / chunks;
    int chunk = bid % chunks;
    int h = bh % HH;
    bool isQ = chunk < (TT / 64);
    int tbase = (isQ ? chunk : chunk - 64) * 64;
    const float* src = (isQ ? q : k) + ((size_t)bh * TT + tbase) * DD;
    float* dst = isQ ? distsQ : distsK;
    double* invdst = invn + (isQ ? 0 : (size_t)BB * HH * TT) + (size_t)bh * TT + tbase;

    int tid = threadIdx.x;
    int row = tid >> 2, part = tid & 3;        // row = cluster idx AND token idx

    // ---- stage means hi/lo (swizzled) + ||m||^2 ----
    {
        const float* mp = means + ((size_t)h * NCC + row) * DD + part * 16;
        float f[16];
        float msq = 0.f;
        #pragma unroll
        for (int i = 0; i < 4; ++i) {
            float4 va = *(const float4*)(mp + i * 4);
            f[i*4] = va.x; f[i*4+1] = va.y; f[i*4+2] = va.z; f[i*4+3] = va.w;
            msq += va.x*va.x + va.y*va.y + va.z*va.z + va.w*va.w;
        }
        msq += __shfl_xor(msq, 1);
        msq += __shfl_xor(msq, 2);
        if (part == 0) mqS[row] = msq;
        #pragma unroll
        for (int cc = 0; cc < 2; ++cc) {
            unsigned hw[4], lw[4];
            #pragma unroll
            for (int j2 = 0; j2 < 4; ++j2) {
                float a = f[cc*8 + j2*2], b = f[cc*8 + j2*2 + 1];
                unsigned p = pk2(a, b);
                float ha = __uint_as_float(p << 16);
                float hb = __uint_as_float(p & 0xFFFF0000u);
                hw[j2] = p; lw[j2] = pk2(a - ha, b - hb);
            }
            int ch = part * 2 + cc;
            int phys = ch ^ (row & 7);
            *reinterpret_cast<uint4*>(&mhS[row * 64 + phys * 8]) = (uint4){hw[0],hw[1],hw[2],hw[3]};
            *reinterpret_cast<uint4*>(&mlS[row * 64 + phys * 8]) = (uint4){lw[0],lw[1],lw[2],lw[3]};
        }
    }
    // ---- stage xn hi/lo (swizzled); f64 norm -> invn + ssn ----
    {
        const float* xp = src + (size_t)row * DD + part * 16;
        float f[16];
        double ssd = 0.0;
        #pragma unroll
        for (int i = 0; i < 4; ++i) {
            float4 va = *(const float4*)(xp + i * 4);
            f[i*4] = va.x; f[i*4+1] = va.y; f[i*4+2] = va.z; f[i*4+3] = va.w;
            ssd += (double)va.x*va.x + (double)va.y*va.y
                 + (double)va.z*va.z + (double)va.w*va.w;
        }
        ssd += __shfl_xor(ssd, 1);
        ssd += __shfl_xor(ssd, 2);
        double invd = 1.0 / fmax(sqrt(ssd), 1e-12);
        if (part == 0) {
            invdst[row] = invd;
            ssnS[row] = (float)(ssd * invd * invd);
        }
        float inv = (float)invd;
        #pragma unroll
        for (int i = 0; i < 16; ++i) f[i] *= inv;
        #pragma unroll
        for (int cc = 0; cc < 2; ++cc) {
            unsigned hw[4], lw[4];
            #pragma unroll
            for (int j2 = 0; j2 < 4; ++j2) {
                float a = f[cc*8 + j2*2], b = f[cc*8 + j2*2 + 1];
                unsigned p = pk2(a, b);
                float ha = __uint_as_float(p << 16);
                float hb = __uint_as_float(p & 0xFFFF0000u);
                hw[j2] = p; lw[j2] = pk2(a - ha, b - hb);
            }
            int ch = part * 2 + cc;
            int phys = ch ^ (row & 7);
            *reinterpret_cast<uint4*>(&xhS[row * 64 + phys * 8]) = (uint4){hw[0],hw[1],hw[2],hw[3]};
            *reinterpret_cast<uint4*>(&xlS[row * 64 + phys * 8]) = (uint4){lw[0],lw[1],lw[2],lw[3]};
        }
    }
    __syncthreads();

    int l = tid & 63, w = tid >> 6;
    int lr = l & 15, lg = l >> 4;

    // ---- A frags: cluster tile w (reused across all 4 token tiles) ----
    bf16x8 mhF[2], mlF[2];
    #pragma unroll
    for (int ks = 0; ks < 2; ++ks) {
        int r2 = w * 16 + lr;
        int phys = (ks * 4 + lg) ^ (r2 & 7);
        mhF[ks] = *reinterpret_cast<const bf16x8*>(&mhS[r2 * 64 + phys * 8]);
        mlF[ks] = *reinterpret_cast<const bf16x8*>(&mlS[r2 * 64 + phys * 8]);
    }

    // ---- GEMM: D[c = w*16+lg*4+r][tok = tt*16+lr], 6 mfma per token tile ----
    f32x4 accT[4];
    size_t rowb = (size_t)(bh * NCC) * TT;
    #pragma unroll
    for (int tt = 0; tt < 4; ++tt) {
        bf16x8 xhF[2], xlF[2];
        #pragma unroll
        for (int ks = 0; ks < 2; ++ks) {
            int r2 = tt * 16 + lr;
            int phys = (ks * 4 + lg) ^ (r2 & 7);
            xhF[ks] = *reinterpret_cast<const bf16x8*>(&xhS[r2 * 64 + phys * 8]);
            xlF[ks] = *reinterpret_cast<const bf16x8*>(&xlS[r2 * 64 + phys * 8]);
        }
        f32x4 a = (f32x4){0.f, 0.f, 0.f, 0.f};
        #pragma unroll
        for (int ks = 0; ks < 2; ++ks)
            a = __builtin_amdgcn_mfma_f32_16x16x32_bf16(mhF[ks], xhF[ks], a, 0, 0, 0);
        #pragma unroll
        for (int ks = 0; ks < 2; ++ks)
            a = __builtin_amdgcn_mfma_f32_16x16x32_bf16(mhF[ks], xlF[ks], a, 0, 0, 0);
        #pragma unroll
        for (int ks = 0; ks < 2; ++ks)
            a = __builtin_amdgcn_mfma_f32_16x16x32_bf16(mlF[ks], xhF[ks], a, 0, 0, 0);
        accT[tt] = a;
        #pragma unroll
        for (int r2 = 0; r2 < 4; ++r2) {
            int c = w * 16 + lg * 4 + r2;
            dst[rowb + (size_t)c * TT + tbase + tt * 16 + lr] = a[r2];
        }
    }

    // ---- argmax via shuffles (lane: token tt*16+lr, clusters w*16+lg*4+r) ----
    #pragma unroll
    for (int tt = 0; tt < 4; ++tt) {
        float bv = accT[tt][0]; int bc = w * 16 + lg * 4;
        #pragma unroll
        for (int r2 = 1; r2 < 4; ++r2)
            if (accT[tt][r2] > bv) { bv = accT[tt][r2]; bc = w * 16 + lg * 4 + r2; }
        #pragma unroll
        for (int off = 16; off <= 32; off <<= 1) {
            float ov = __shfl_xor(bv, off);
            int   oc = __shfl_xor(bc, off);
            if (ov > bv || (ov == bv && oc < bc)) { bv = ov; bc = oc; }
        }
        if (lg == 0) {
            wMaxS[(tt * 16 + lr) * 5 + w] = bv;
            wIdxS[(tt * 16 + lr) * 5 + w] = bc;
        }
    }
    __syncthreads();

    if (tid < 64) {
        float bv = -1e30f; int bc = 0;
        #pragma unroll
        for (int w2 = 0; w2 < 4; ++w2) {   // ascending cluster ranges
            float ov = wMaxS[tid * 5 + w2];
            int   oc = wIdxS[tid * 5 + w2];
            if (ov > bv || (ov == bv && oc < bc)) { bv = ov; bc = oc; }
        }
        float auxv = ssnS[tid] + mqS[bc] - 2.f * bv;
        #pragma unroll
        for (int off = 32; off; off >>= 1) auxv += __shfl_xor(auxv, off);
        if (tid == 0) aux_part[bid] = auxv;
    }
}

// ---------------- Kernel B: top-TPK per row, 3-pass radix (12/12/8 bits) -------
__global__ __launch_bounds__(256) void topk_kernel(
    const float* __restrict__ dists, int* __restrict__ idxOut)
{
    int row = blockIdx.x;
    const float* dv = dists + (size_t)row * TT;
    int t = threadIdx.x;
    int lane = t & 63, w = t >> 6;

    unsigned u[16];
    #pragma unroll
    for (int j0 = 0; j0 < 4; ++j0) {
        float4 f = *(const float4*)(dv + t * 16 + j0 * 4);
        u[j0*4+0] = mono(f.x); u[j0*4+1] = mono(f.y);
        u[j0*4+2] = mono(f.z); u[j0*4+3] = mono(f.w);
    }

    __shared__ int hist[4096];
    __shared__ int wtot[4];
    __shared__ int binSel, tgtS;
    __shared__ int nGtS, posS, eqPos;

    int target = TPK;
    unsigned prefix = 0;

    // ---- passes 1,2: 12-bit digits over 4096 bins ----
    #pragma unroll
    for (int pass = 0; pass < 2; ++pass) {
        int4* hz = (int4*)&hist[t * 16];
        hz[0] = (int4){0,0,0,0}; hz[1] = (int4){0,0,0,0};
        hz[2] = (int4){0,0,0,0}; hz[3] = (int4){0,0,0,0};
        __syncthreads();
        if (pass == 0) {
            #pragma unroll
            for (int j = 0; j < 16; ++j) atomicAdd(&hist[u[j] >> 20], 1);
        } else {
            #pragma unroll
            for (int j = 0; j < 16; ++j)
                if ((u[j] >> 20) == (prefix >> 20))
                    atomicAdd(&hist[(u[j] >> 8) & 0xFFF], 1);
        }
        __syncthreads();
        int cnt[16], ls[16];
        {
            const int4* hp = (const int4*)&hist[t * 16];
            int4 c0 = hp[0], c1 = hp[1], c2 = hp[2], c3 = hp[3];
            cnt[0]=c0.x; cnt[1]=c0.y; cnt[2]=c0.z; cnt[3]=c0.w;
            cnt[4]=c1.x; cnt[5]=c1.y; cnt[6]=c1.z; cnt[7]=c1.w;
            cnt[8]=c2.x; cnt[9]=c2.y; cnt[10]=c2.z; cnt[11]=c2.w;
            cnt[12]=c3.x; cnt[13]=c3.y; cnt[14]=c3.z; cnt[15]=c3.w;
        }
        int run = 0;
        #pragma unroll
        for (int i = 15; i >= 0; --i) { run += cnt[i]; ls[i] = run; }
        int S = run;
        #pragma unroll
        for (int off = 1; off < 64; off <<= 1) {
            int o = __shfl_down(S, off);
            if (lane + off < 64) S += o;
        }
        if (lane == 0) wtot[w] = S;
        __syncthreads();
        int after = 0;
        for (int ww = w + 1; ww < 4; ++ww) after += wtot[ww];
        int St1 = S - run + after;      // suffix of bins owned by later threads
        #pragma unroll
        for (int i = 0; i < 16; ++i) {
            int sfxb = ls[i] + St1;
            if (sfxb >= target && sfxb - cnt[i] < target) {
                binSel = t * 16 + i; tgtS = target - (sfxb - cnt[i]);
            }
        }
        __syncthreads();
        prefix |= (pass == 0) ? ((unsigned)binSel << 20) : ((unsigned)binSel << 8);
        target = tgtS;
        __syncthreads();
    }

    // ---- pass 3: low 8 bits (256 bins) ----
    hist[t] = 0;
    __syncthreads();
    #pragma unroll
    for (int j = 0; j < 16; ++j)
        if ((u[j] >> 8) == (prefix >> 8))
            atomicAdd(&hist[u[j] & 0xFF], 1);
    __syncthreads();
    {
        int cnt = hist[t];
        int S = cnt;
        #pragma unroll
        for (int off = 1; off < 64; off <<= 1) {
            int o = __shfl_down(S, off);
            if (lane + off < 64) S += o;
        }
        if (lane == 0) wtot[w] = S;
        __syncthreads();
        int after = 0;
        for (int ww = w + 1; ww < 4; ++ww) after += wtot[ww];
        int sfx = S + after;
        if (sfx >= target && sfx - cnt < target) { binSel = t; tgtS = target - (sfx - cnt); }
    }
    __syncthreads();
    unsigned pivot = prefix | (unsigned)binSel;

    // ---- epilogue: compact >pivot, then ==pivot (unordered, capped) ----
    if (t == 0) { nGtS = 0; posS = 0; eqPos = 0; }
    __syncthreads();
    int myg = 0;
    #pragma unroll
    for (int j = 0; j < 16; ++j) myg += (u[j] > pivot) ? 1 : 0;
    if (myg) atomicAdd(&nGtS, myg);
    __syncthreads();
    int n_gt = nGtS;
    int n_need = TPK - n_gt;
    int* out = idxOut + (size_t)row * TPK;
    #pragma unroll
    for (int j = 0; j < 16; ++j) {
        if (u[j] > pivot) {
            int p = atomicAdd(&posS, 1);
            out[p] = t * 16 + j;
        } else if (u[j] == pivot) {
            int p = atomicAdd(&eqPos, 1);
            if (p < n_need) out[n_gt + p] = t * 16 + j;
        }
    }
}

// ---------------- Kernel B2: f64 rescore, branchless u32-prefix rank ----------
__global__ __launch_bounds__(640) void rescore_kernel(
    const float* __restrict__ q, const float* __restrict__ k,
    const float* __restrict__ means, const double* __restrict__ invn,
    const int* __restrict__ candQ, const int* __restrict__ candK,
    int* __restrict__ idxQ, int* __restrict__ idxK,
    int* __restrict__ counts)
{
    int bid = blockIdx.x;
    int rid = (bid & 7) * 512 + (bid >> 3);   // 4096 % 8 == 0 -> bijective
    int side = rid >> 11;            // 0=Q, 1=K
    int row = rid & 2047;            // bh*NC + c
    int c = row & (NCC - 1);
    int bh = row >> 6;
    int h = bh % HH;

    const int* cand = (side ? candK : candQ) + (size_t)row * TPK;
    int* outIdx     = (side ? idxK : idxQ) + (size_t)row * WSZW;
    const float* xbase = (side ? k : q) + (size_t)bh * TT * DD;
    const double* invp = invn + (side ? (size_t)BB * HH * TT : 0) + (size_t)bh * TT;

    __shared__ double   mD[DD];
    __shared__ unsigned hiS[TPK];
    __shared__ unsigned loS[TPK];
    __shared__ int      kiS[TPK];

    int tid = threadIdx.x;
    if (tid < DD) mD[tid] = (double)means[((size_t)h * NCC + c) * DD + tid];
    __syncthreads();

    int g = tid >> 2;                // candidate 0..159
    int qt = tid & 3;                // quarter-row 0..3
    int tok = cand[g];
    const float* xp = xbase + (size_t)tok * DD + qt * 16;
    double inv = invp[tok];          // 4 lanes same addr -> broadcast
    double d0 = 0.0, d1 = 0.0;
    #pragma unroll
    for (int i = 0; i < 2; ++i) {
        float4 va = *(const float4*)(xp + i * 4);
        int d = qt * 16 + i * 4;
        d0 += (double)va.x * mD[d]   + (double)va.y * mD[d+1]
            + (double)va.z * mD[d+2] + (double)va.w * mD[d+3];
    }
    #pragma unroll
    for (int i = 2; i < 4; ++i) {
        float4 va = *(const float4*)(xp + i * 4);
        int d = qt * 16 + i * 4;
        d1 += (double)va.x * mD[d]   + (double)va.y * mD[d+1]
            + (double)va.z * mD[d+2] + (double)va.w * mD[d+3];
    }
    double dot = d0 + d1;
    dot += __shfl_xor(dot, 1); dot += __shfl_xor(dot, 2);
    double v = dot * inv;            // identical across the 4-lane group
    unsigned long long key = mono64(v);
    unsigned myhi = (unsigned)(key >> 32), mylo = (unsigned)key;
    if (qt == 0) { hiS[g] = myhi; loS[g] = mylo; kiS[g] = tok; }
    __syncthreads();

    // phase 1: branchless rank on 32-bit prefixes (1 LDS b32 read per iter)
    int rk = 0, eq = 0;
    #pragma unroll 8
    for (int i = 0; i < TPK / 4; ++i) {
        unsigned hj = hiS[qt * (TPK / 4) + i];
        rk += (hj > myhi) ? 1 : 0;
        eq += (hj == myhi) ? 1 : 0;
    }
    rk += __shfl_xor(rk, 1); rk += __shfl_xor(rk, 2);
    eq += __shfl_xor(eq, 1); eq += __shfl_xor(eq, 2);

    // phase 2 (rare): exact 64-bit + token recount when hi-prefix ties exist
    if (eq > 1) {
        int rk2 = 0;
        for (int i = 0; i < TPK / 4; ++i) {
            int j = qt * (TPK / 4) + i;
            unsigned hj = hiS[j];
            if (hj > myhi) rk2++;
            else if (hj == myhi) {
                unsigned lj = loS[j];
                if (lj > mylo || (lj == mylo && kiS[j] < tok)) rk2++;
            }
        }
        rk2 += __shfl_xor(rk2, 1); rk2 += __shfl_xor(rk2, 2);
        rk = rk2;
    }

    if (qt == 0 && rk < WSZW) {
        outIdx[rk] = tok;
        if (side == 0) atomicAdd(&counts[bh * TT + tok], 1);
    }
}

// ---------------- Kernel C: bf16 MFMA attention, 130-row LDS, bf16 so out ------
__global__ __launch_bounds__(512, 8) void attn_kernel(
    const float* __restrict__ q, const float* __restrict__ k, const float* __restrict__ v,
    const float* __restrict__ mem_key, const float* __restrict__ mem_value,
    const int* __restrict__ idxQ, const int* __restrict__ idxK,
    unsigned short* __restrict__ so)
{
    // XCD-bijective swizzle (2048 % 8 == 0): 256 consecutive blks per XCD
    int bid = blockIdx.x;
    int blk = (bid & 7) * 256 + (bid >> 3);
    int c = blk % NCC;
    int bh = blk / NCC;
    int h = bh % HH;

    __shared__ __align__(16) unsigned short KsS[130 * 64];   // [kv][d] swizzled (temp V in P1/P2)
    __shared__ __align__(16) unsigned short VtS[64 * 168];   // [d][kv], pad 168

    int tid = threadIdx.x;
    int w = tid >> 6, l = tid & 63;
    int lr = l & 15, lg = l >> 4;

    const float* memK = mem_key   + ((size_t)h * NCC + c) * (MEMN * DD);
    const float* memV = mem_value + ((size_t)h * NCC + c) * (MEMN * DD);

    // ---- entry: resolve staging rows + issue ALL token-index gathers ----
    int stRow[3], stCh[3];
    const float *vsrcR[3], *ksrcR[3];
    #pragma unroll
    for (int s = 0; s < 3; ++s) {
        int idx = tid + s * 512;
        stRow[s] = idx >> 3; stCh[s] = idx & 7;
        vsrcR[s] = nullptr; ksrcR[s] = nullptr;
        if (idx < 1280 && stRow[s] < KVW) {
            if (stRow[s] == 0) { vsrcR[s] = memV; ksrcR[s] = memK; }
            else {
                int tk = idxK[(size_t)blk * WSZW + stRow[s] - 1];
                vsrcR[s] = v + ((size_t)bh * TT + tk) * DD;
                ksrcR[s] = k + ((size_t)bh * TT + tk) * DD;
            }
        }
    }

    // ---- Q frags (independent chase, overlaps everything) ----
    bf16x8 qf[2];
    {
        int tq = idxQ[(size_t)blk * WSZW + w * 16 + lr];
        const float* qp = q + ((size_t)bh * TT + tq) * DD;
        #pragma unroll
        for (int ks = 0; ks < 2; ++ks) {
            float4 a = *(const float4*)(qp + ks * 32 + lg * 8);
            float4 b = *(const float4*)(qp + ks * 32 + lg * 8 + 4);
            qf[ks] = pack8(a, b);
        }
    }

    // ---- V gather window (batched) ----
    uint4 vw[3];
    #pragma unroll
    for (int s = 0; s < 3; ++s) {
        vw[s] = (uint4){0,0,0,0};
        if (vsrcR[s]) {
            float4 a = *(const float4*)(vsrcR[s] + stCh[s] * 8);
            float4 b = *(const float4*)(vsrcR[s] + stCh[s] * 8 + 4);
            vw[s].x = pk2(a.x, a.y); vw[s].y = pk2(a.z, a.w);
            vw[s].z = pk2(b.x, b.y); vw[s].w = pk2(b.z, b.w);
        }
    }
    // ---- K gather window (batched) ----
    uint4 kw[3];
    #pragma unroll
    for (int s = 0; s < 3; ++s) {
        kw[s] = (uint4){0,0,0,0};
        if (ksrcR[s]) {
            float4 a = *(const float4*)(ksrcR[s] + stCh[s] * 8);
            float4 b = *(const float4*)(ksrcR[s] + stCh[s] * 8 + 4);
            kw[s].x = pk2(a.x, a.y); kw[s].y = pk2(a.z, a.w);
            kw[s].z = pk2(b.x, b.y); kw[s].w = pk2(b.z, b.w);
        }
    }

    // ---- P1: V -> row-major swizzled (valid rows only) ----
    #pragma unroll
    for (int s = 0; s < 3; ++s)
        if (vsrcR[s])
            *reinterpret_cast<uint4*>(
                &KsS[stRow[s] * 64 + ((stCh[s] ^ (stRow[s] & 7)) * 8)]) = vw[s];
    __syncthreads();

    // ---- P2: Vt column segments -> regs (clamped rows; broadcast-class) ----
    unsigned short vreg[3][8];
    #pragma unroll
    for (int s = 0; s < 3; ++s) {
        int idx = tid + s * 512;
        if (idx < 1280) {
            int d = idx & 63, rowblk = idx >> 6;
            #pragma unroll
            for (int i = 0; i < 8; ++i) {
                int row = rowblk * 8 + i;
                int pr = (row < KVW) ? row : 128;
                vreg[s][i] = KsS[pr * 64 + (((d >> 3) ^ (pr & 7)) * 8) + (d & 7)];
            }
        }
    }
    __syncthreads();

    // ---- P3: write Vt (b128 rows) + K (valid rows only) ----
    #pragma unroll
    for (int s = 0; s < 3; ++s) {
        int idx = tid + s * 512;
        if (idx < 1280) {
            int d = idx & 63, rowblk = idx >> 6;
            uint4 ow;
            ow.x = (unsigned)vreg[s][0] | ((unsigned)vreg[s][1] << 16);
            ow.y = (unsigned)vreg[s][2] | ((unsigned)vreg[s][3] << 16);
            ow.z = (unsigned)vreg[s][4] | ((unsigned)vreg[s][5] << 16);
            ow.w = (unsigned)vreg[s][6] | ((unsigned)vreg[s][7] << 16);
            *reinterpret_cast<uint4*>(&VtS[d * 168 + rowblk * 8]) = ow;
        }
    }
    #pragma unroll
    for (int s = 0; s < 3; ++s)
        if (ksrcR[s])
            *reinterpret_cast<uint4*>(
                &KsS[stRow[s] * 64 + ((stCh[s] ^ (stRow[s] & 7)) * 8)]) = kw[s];
    __syncthreads();

    // ---- compute (swapped QK^T, P in regs, Vt b128 B-frags) ----
    f32x4 acc[4];
    #pragma unroll
    for (int dt = 0; dt < 4; ++dt) acc[dt] = (f32x4){0.f, 0.f, 0.f, 0.f};
    float s_sum = 0.f;

    int src0 = lr + ((lg & 1) * 2) * 16;
    int src1 = src0 + 16;
    bool hi = (lg >> 1) != 0;

    for (int kb = 0; kb < 5; ++kb) {
        bf16x8 kf[2][2];
        #pragma unroll
        for (int kvt = 0; kvt < 2; ++kvt)
            #pragma unroll
            for (int ks = 0; ks < 2; ++ks) {
                int row = kb * 32 + kvt * 16 + lr;
                int pr = (row < KVW) ? row : 128;
                int phys = (ks * 4 + lg) ^ (pr & 7);
                kf[kvt][ks] = *reinterpret_cast<const bf16x8*>(&KsS[pr * 64 + phys * 8]);
            }
        __builtin_amdgcn_s_setprio(1);
        unsigned pk[2][2];
        #pragma unroll
        for (int kvt = 0; kvt < 2; ++kvt) {
            f32x4 sf = __builtin_amdgcn_mfma_f32_16x16x32_bf16(
                kf[kvt][0], qf[0], (f32x4){0.f,0.f,0.f,0.f}, 0, 0, 0);
            sf = __builtin_amdgcn_mfma_f32_16x16x32_bf16(kf[kvt][1], qf[1], sf, 0, 0, 0);
            float e[4];
            #pragma unroll
            for (int r = 0; r < 4; ++r) {
                int kv = kb * 32 + kvt * 16 + lg * 4 + r;
                e[r] = (kv < KVW) ? __expf(sf[r] * SCALE) : 0.f;
                s_sum += e[r];
            }
            pk[kvt][0] = pk2(e[0], e[1]);
            pk[kvt][1] = pk2(e[2], e[3]);
        }
        unsigned a00 = __shfl(pk[0][0], src0), a01 = __shfl(pk[0][1], src0);
        unsigned a10 = __shfl(pk[1][0], src0), a11 = __shfl(pk[1][1], src0);
        unsigned b00 = __shfl(pk[0][0], src1), b01 = __shfl(pk[0][1], src1);
        unsigned b10 = __shfl(pk[1][0], src1), b11 = __shfl(pk[1][1], src1);
        union { unsigned u[4]; bf16x8 v; } pu;
        pu.u[0] = hi ? a10 : a00;
        pu.u[1] = hi ? a11 : a01;
        pu.u[2] = hi ? b10 : b00;
        pu.u[3] = hi ? b11 : b01;
        #pragma unroll
        for (int dt = 0; dt < 4; ++dt) {
            bf16x8 vf = *reinterpret_cast<const bf16x8*>(
                &VtS[(dt * 16 + lr) * 168 + kb * 32 + lg * 8]);
            acc[dt] = __builtin_amdgcn_mfma_f32_16x16x32_bf16(pu.v, vf, acc[dt], 0, 0, 0);
        }
        __builtin_amdgcn_s_setprio(0);
    }

    s_sum += __shfl_xor(s_sum, 16);
    s_sum += __shfl_xor(s_sum, 32);
    float sinv[4];
    #pragma unroll
    for (int r = 0; r < 4; ++r)
        sinv[r] = 1.f / __shfl(s_sum, lg * 4 + r);

    // ---- store O as bf16 (halves write traffic + reduce's read traffic) ----
    #pragma unroll
    for (int r = 0; r < 4; ++r) {
        int row = w * 16 + lg * 4 + r;
        unsigned short* op = so + (((size_t)blk * WSZW + row) * DD);
        #pragma unroll
        for (int dt = 0; dt < 4; ++dt) {
            float ov = acc[dt][r] * sinv[r];
            op[dt * 16 + lr] = (unsigned short)(pk2(ov, ov) & 0xFFFFu);
        }
    }
}

// ---------------- Kernel F: fused per-bh scan + CSR fill + aux finalize --------
__global__ __launch_bounds__(256) void scanfill_kernel(
    const int* __restrict__ counts, int* __restrict__ offs,
    const int* __restrict__ idxQ, int* __restrict__ csr,
    const float* __restrict__ auxp, float* __restrict__ out)
{
    __shared__ int offsL[TT];
    __shared__ int curL[TT];
    __shared__ int wsum[256];
    __shared__ float auxW[4];

    int bh = blockIdx.x;
    int t = threadIdx.x;

    // ---- aux fold (loads only on block 0; uniform barriers) ----
    float s = 0.f;
    if (bh == 0)
        for (int i = t; i < 4096; i += 256) s += auxp[i];
    #pragma unroll
    for (int off = 32; off; off >>= 1) s += __shfl_xor(s, off);
    if ((t & 63) == 0) auxW[t >> 6] = s;
    __syncthreads();
    if (bh == 0 && t == 0)
        out[(size_t)BB * HH * TT * DD] =
            (auxW[0] + auxW[1] + auxW[2] + auxW[3]) *
            (1.0f / (float)(BB * HH * 2 * TT * DD));

    // ---- exclusive scan over counts[bh] ----
    const int* cb = counts + (size_t)bh * TT;
    int* ob = offs + (size_t)bh * TT;
    int loc[16]; int sum = 0;
    #pragma unroll
    for (int i = 0; i < 16; ++i) { loc[i] = sum; sum += cb[t * 16 + i]; }
    wsum[t] = sum;
    __syncthreads();
    for (int off = 1; off < 256; off <<= 1) {
        int vv = (t >= off) ? wsum[t - off] : 0;
        __syncthreads();
        wsum[t] += vv;
        __syncthreads();
    }
    int ex = (t == 0) ? 0 : wsum[t - 1];
    #pragma unroll
    for (int i = 0; i < 16; ++i) {
        int o = ex + loc[i];
        ob[t * 16 + i] = o;
        offsL[t * 16 + i] = o;
        curL[t * 16 + i] = 0;
    }
    __syncthreads();

    // ---- CSR fill (LDS atomics) ----
    const int* iq = idxQ + ((size_t)bh << 13);
    int* cs = csr + ((size_t)bh << 13);
    for (int i = t; i < 8192; i += 256) {
        int tok = iq[i];
        int p = offsL[tok] + atomicAdd(&curL[tok], 1);
        cs[p] = i;
    }
}

// ---------------- Kernel H: gather-reduce (bf16 so), pair-batched + XCD swz ----
__global__ __launch_bounds__(256) void reduce_kernel(
    const unsigned short* __restrict__ so, const int* __restrict__ counts,
    const int* __restrict__ offs, const int* __restrict__ csr,
    float* __restrict__ out)
{
    int b0 = blockIdx.x;
    int b = (b0 & 7) * 4096 + (b0 >> 3);     // 32768 % 8 == 0 -> bijective
    int gt = b * 4 + (threadIdx.x >> 6);
    int lane = threadIdx.x & 63;
    int bh = gt >> 12;
    int n = counts[gt];
    int st = offs[gt];
    const int* cs = csr + ((size_t)bh << 13);
    const unsigned short* sob = so + (((size_t)bh << 13) * DD);
    float acc = 0.f;
    int j = 0;
    for (; j + 2 <= n; j += 2) {             // pair-batched: 2 idx, then 2 rows
        int s0 = cs[st + j], s1 = cs[st + j + 1];
        float v0 = bf2f(sob[(size_t)s0 * DD + lane]);
        float v1 = bf2f(sob[(size_t)s1 * DD + lane]);
        acc += v0 + v1;
    }
    if (j < n) acc += bf2f(sob[(size_t)cs[st + j] * DD + lane]);
    out[(size_t)gt * DD + lane] = acc / ((float)n + EPSF);
}

extern "C" void kernel_launch(void* const* d_in, const int* in_sizes, int n_in,
                              void* d_out, int out_size, void* d_ws, size_t ws_size,
                              hipStream_t stream) {
    const float* q        = (const float*)d_in[0];
    const float* k        = (const float*)d_in[1];
    const float* v        = (const float*)d_in[2];
    const float* means    = (const float*)d_in[3];
    const float* mem_key  = (const float*)d_in[4];
    const float* mem_val  = (const float*)d_in[5];
    float* out = (float*)d_out;

    const size_t nRows = (size_t)BB * HH * NCC;             // 2048
    const size_t nTok  = (size_t)BB * HH * TT;              // 131072
    float* wsf    = (float*)d_ws;
    float* distsQ = wsf;                                    // 8388608 f
    float* distsK = distsQ + (size_t)BB * HH * NCC * TT;    // 8388608 f (contiguous after distsQ)
    unsigned short* so = (unsigned short*)wsf;              // bf16, aliases dists; written after rescore
    int*   idxQ   = (int*)(distsK + (size_t)BB * HH * NCC * TT);  // 262144 i
    int*   idxK   = idxQ + nRows * WSZW;                    // 262144 i
    int*   counts = idxK + nRows * WSZW;                    // 131072 i
    float* auxp   = (float*)(counts + nTok);                // 4096 f (per-block partials)
    int*   offs   = (int*)(auxp + 4096);                    // 131072 i
    int*   csr    = offs + nTok;                            // 262144 i
    int*   candQ  = csr + nTok * 2;                         // 2048*160 i
    int*   candK  = candQ + nRows * TPK;                    // 2048*160 i (contiguous after candQ)
    uintptr_t ip  = (uintptr_t)(candK + nRows * TPK);
    ip = (ip + 15) & ~(uintptr_t)15;
    double* invn  = (double*)ip;                            // 2*131072 d (Q then K)

    hipMemsetAsync(counts, 0, nTok * sizeof(int), stream);

    dists_kernel<<<dim3(BB * HH * (2 * TT / 64)), dim3(256), 0, stream>>>(
        q, k, means, distsQ, distsK, auxp, invn);
    // single launch covers Q rows (0..2047 over distsQ/candQ) and K rows
    // (2048..4095 over distsK/candK) via buffer contiguity
    topk_kernel<<<dim3((unsigned)(2 * nRows)), dim3(256), 0, stream>>>(distsQ, candQ);
    rescore_kernel<<<dim3((unsigned)(2 * nRows)), dim3(640), 0, stream>>>(
        q, k, means, invn, candQ, candK, idxQ, idxK, counts);
    scanfill_kernel<<<dim3(BB * HH), dim3(256), 0, stream>>>(
        counts, offs, idxQ, csr, auxp, out);
    attn_kernel<<<dim3((unsigned)nRows), dim3(512), 0, stream>>>(
        q, k, v, mem_key, mem_val, idxQ, idxK, so);
    reduce_kernel<<<dim3((unsigned)(nTok / 4)), dim3(256), 0, stream>>>(
        so, counts, offs, csr, out);
}

// Round 24
// 173.362 us; speedup vs baseline: 1.5540x; 1.1068x over previous
//
#include <hip/hip_runtime.h>
#include <math.h>

#define BB 4
#define HH 8
#define TT 4096
#define DD 64
#define NCC 64
#define WSZW 128
#define TPK 160          // widened bf16 top-k; f64 rescore picks exact top-128
#define MEMN 1
#define KVW (MEMN + WSZW)   // 129
constexpr float EPSF = 1e-5f;
constexpr float SCALE = 0.125f;  // 64^-0.5

typedef __attribute__((ext_vector_type(8))) short bf16x8;
typedef __attribute__((ext_vector_type(4))) float f32x4;

// HW packed f32->bf16 (RNE), 1 instruction vs ~7 for the manual bit-twiddle
static __device__ __forceinline__ unsigned int pk2(float a, float b) {
    unsigned int r;
    asm("v_cvt_pk_bf16_f32 %0, %1, %2" : "=v"(r) : "v"(a), "v"(b));
    return r;
}
static __device__ __forceinline__ bf16x8 pack8(float4 a, float4 b) {
    union { unsigned int u[4]; bf16x8 v; } r;
    r.u[0] = pk2(a.x, a.y); r.u[1] = pk2(a.z, a.w);
    r.u[2] = pk2(b.x, b.y); r.u[3] = pk2(b.z, b.w);
    return r.v;
}
static __device__ __forceinline__ unsigned mono16(unsigned u) {
    return (u ^ ((u & 0x8000u) ? 0xFFFFu : 0x8000u)) & 0xFFFFu;
}
static __device__ __forceinline__ unsigned long long mono64(double d) {
    unsigned long long b = (unsigned long long)__double_as_longlong(d);
    return b ^ (((long long)b < 0) ? ~0ULL : 0x8000000000000000ULL);
}
static __device__ __forceinline__ float bf2f(unsigned short u) {
    return __uint_as_float(((unsigned)u) << 16);
}

// ---------------- Kernel A: dists via split-bf16 MFMA -> bf16 dists ------------
// dist intermediate stored as bf16 (halves write + topk read traffic); exact
// f64 rescore downstream makes the final top-128 bit-exact. argmax/aux use the
// full f32 accumulators. Also zeroes counts (32 ints/block; replaces memset).
__global__ __launch_bounds__(256, 4) void dists_kernel(
    const float* __restrict__ q, const float* __restrict__ k,
    const float* __restrict__ means,
    unsigned short* __restrict__ distsQ, unsigned short* __restrict__ distsK,
    float* __restrict__ aux_part, double* __restrict__ invn,
    int* __restrict__ counts)
{
    __shared__ __align__(16) unsigned short mhS[64 * 64];   // [c][d] swizzled chunks
    __shared__ __align__(16) unsigned short mlS[64 * 64];
    __shared__ __align__(16) unsigned short xhS[64 * 64];   // [tok][d]
    __shared__ __align__(16) unsigned short xlS[64 * 64];
    __shared__ float mqS[64];      // per-cluster ||m||^2
    __shared__ float ssnS[64];     // per-token ||xn||^2
    __shared__ float wMaxS[64 * 5];
    __shared__ int   wIdxS[64 * 5];

    const int chunks = (2 * TT) / 64;          // 128
    int bid0 = blockIdx.x;                     // 4096
    int bid = (bid0 & 7) * 512 + (bid0 >> 3);  // XCD-contiguous (4096 % 8 == 0)
    int bh = bid / chunks;
    int chunk = bid % chunks;
    int h = bh % HH;
    bool isQ = chunk < (TT / 64);
    int tbase = (isQ ? chunk : chunk - 64) * 64;
    const float* src = (isQ ? q : k) + ((size_t)bh * TT + tbase) * DD;
    unsigned short* dst = isQ ? distsQ : distsK;
    double* invdst = invn + (isQ ? 0 : (size_t)BB * HH * TT) + (size_t)bh * TT + tbase;

    int tid = threadIdx.x;

    // zero counts (replaces host memset): 4096 blocks x 32 ints = 131072
    if (tid < 32) counts[(size_t)bid0 * 32 + tid] = 0;

    int row = tid >> 2, part = tid & 3;        // row = cluster idx AND token idx

    // ---- stage means hi/lo (swizzled) + ||m||^2 ----
    {
        const float* mp = means + ((size_t)h * NCC + row) * DD + part * 16;
        float f[16];
        float msq = 0.f;
        #pragma unroll
        for (int i = 0; i < 4; ++i) {
            float4 va = *(const float4*)(mp + i * 4);
            f[i*4] = va.x; f[i*4+1] = va.y; f[i*4+2] = va.z; f[i*4+3] = va.w;
            msq += va.x*va.x + va.y*va.y + va.z*va.z + va.w*va.w;
        }
        msq += __shfl_xor(msq, 1);
        msq += __shfl_xor(msq, 2);
        if (part == 0) mqS[row] = msq;
        #pragma unroll
        for (int cc = 0; cc < 2; ++cc) {
            unsigned hw[4], lw[4];
            #pragma unroll
            for (int j2 = 0; j2 < 4; ++j2) {
                float a = f[cc*8 + j2*2], b = f[cc*8 + j2*2 + 1];
                unsigned p = pk2(a, b);
                float ha = __uint_as_float(p << 16);
                float hb = __uint_as_float(p & 0xFFFF0000u);
                hw[j2] = p; lw[j2] = pk2(a - ha, b - hb);
            }
            int ch = part * 2 + cc;
            int phys = ch ^ (row & 7);
            *reinterpret_cast<uint4*>(&mhS[row * 64 + phys * 8]) = (uint4){hw[0],hw[1],hw[2],hw[3]};
            *reinterpret_cast<uint4*>(&mlS[row * 64 + phys * 8]) = (uint4){lw[0],lw[1],lw[2],lw[3]};
        }
    }
    // ---- stage xn hi/lo (swizzled); f64 norm -> invn + ssn ----
    {
        const float* xp = src + (size_t)row * DD + part * 16;
        float f[16];
        double ssd = 0.0;
        #pragma unroll
        for (int i = 0; i < 4; ++i) {
            float4 va = *(const float4*)(xp + i * 4);
            f[i*4] = va.x; f[i*4+1] = va.y; f[i*4+2] = va.z; f[i*4+3] = va.w;
            ssd += (double)va.x*va.x + (double)va.y*va.y
                 + (double)va.z*va.z + (double)va.w*va.w;
        }
        ssd += __shfl_xor(ssd, 1);
        ssd += __shfl_xor(ssd, 2);
        double invd = 1.0 / fmax(sqrt(ssd), 1e-12);
        if (part == 0) {
            invdst[row] = invd;
            ssnS[row] = (float)(ssd * invd * invd);
        }
        float inv = (float)invd;
        #pragma unroll
        for (int i = 0; i < 16; ++i) f[i] *= inv;
        #pragma unroll
        for (int cc = 0; cc < 2; ++cc) {
            unsigned hw[4], lw[4];
            #pragma unroll
            for (int j2 = 0; j2 < 4; ++j2) {
                float a = f[cc*8 + j2*2], b = f[cc*8 + j2*2 + 1];
                unsigned p = pk2(a, b);
                float ha = __uint_as_float(p << 16);
                float hb = __uint_as_float(p & 0xFFFF0000u);
                hw[j2] = p; lw[j2] = pk2(a - ha, b - hb);
            }
            int ch = part * 2 + cc;
            int phys = ch ^ (row & 7);
            *reinterpret_cast<uint4*>(&xhS[row * 64 + phys * 8]) = (uint4){hw[0],hw[1],hw[2],hw[3]};
            *reinterpret_cast<uint4*>(&xlS[row * 64 + phys * 8]) = (uint4){lw[0],lw[1],lw[2],lw[3]};
        }
    }
    __syncthreads();

    int l = tid & 63, w = tid >> 6;
    int lr = l & 15, lg = l >> 4;

    // ---- A frags: cluster tile w (reused across all 4 token tiles) ----
    bf16x8 mhF[2], mlF[2];
    #pragma unroll
    for (int ks = 0; ks < 2; ++ks) {
        int r2 = w * 16 + lr;
        int phys = (ks * 4 + lg) ^ (r2 & 7);
        mhF[ks] = *reinterpret_cast<const bf16x8*>(&mhS[r2 * 64 + phys * 8]);
        mlF[ks] = *reinterpret_cast<const bf16x8*>(&mlS[r2 * 64 + phys * 8]);
    }

    // ---- GEMM: D[c = w*16+lg*4+r][tok = tt*16+lr], 6 mfma per token tile ----
    f32x4 accT[4];
    size_t rowb = (size_t)(bh * NCC) * TT;
    #pragma unroll
    for (int tt = 0; tt < 4; ++tt) {
        bf16x8 xhF[2], xlF[2];
        #pragma unroll
        for (int ks = 0; ks < 2; ++ks) {
            int r2 = tt * 16 + lr;
            int phys = (ks * 4 + lg) ^ (r2 & 7);
            xhF[ks] = *reinterpret_cast<const bf16x8*>(&xhS[r2 * 64 + phys * 8]);
            xlF[ks] = *reinterpret_cast<const bf16x8*>(&xlS[r2 * 64 + phys * 8]);
        }
        f32x4 a = (f32x4){0.f, 0.f, 0.f, 0.f};
        #pragma unroll
        for (int ks = 0; ks < 2; ++ks)
            a = __builtin_amdgcn_mfma_f32_16x16x32_bf16(mhF[ks], xhF[ks], a, 0, 0, 0);
        #pragma unroll
        for (int ks = 0; ks < 2; ++ks)
            a = __builtin_amdgcn_mfma_f32_16x16x32_bf16(mhF[ks], xlF[ks], a, 0, 0, 0);
        #pragma unroll
        for (int ks = 0; ks < 2; ++ks)
            a = __builtin_amdgcn_mfma_f32_16x16x32_bf16(mlF[ks], xhF[ks], a, 0, 0, 0);
        accT[tt] = a;
        #pragma unroll
        for (int r2 = 0; r2 < 4; ++r2) {
            int c = w * 16 + lg * 4 + r2;
            dst[rowb + (size_t)c * TT + tbase + tt * 16 + lr] =
                (unsigned short)(pk2(a[r2], a[r2]) & 0xFFFFu);
        }
    }

    // ---- argmax via shuffles (lane: token tt*16+lr, clusters w*16+lg*4+r) ----
    #pragma unroll
    for (int tt = 0; tt < 4; ++tt) {
        float bv = accT[tt][0]; int bc = w * 16 + lg * 4;
        #pragma unroll
        for (int r2 = 1; r2 < 4; ++r2)
            if (accT[tt][r2] > bv) { bv = accT[tt][r2]; bc = w * 16 + lg * 4 + r2; }
        #pragma unroll
        for (int off = 16; off <= 32; off <<= 1) {
            float ov = __shfl_xor(bv, off);
            int   oc = __shfl_xor(bc, off);
            if (ov > bv || (ov == bv && oc < bc)) { bv = ov; bc = oc; }
        }
        if (lg == 0) {
            wMaxS[(tt * 16 + lr) * 5 + w] = bv;
            wIdxS[(tt * 16 + lr) * 5 + w] = bc;
        }
    }
    __syncthreads();

    if (tid < 64) {
        float bv = -1e30f; int bc = 0;
        #pragma unroll
        for (int w2 = 0; w2 < 4; ++w2) {   // ascending cluster ranges
            float ov = wMaxS[tid * 5 + w2];
            int   oc = wIdxS[tid * 5 + w2];
            if (ov > bv || (ov == bv && oc < bc)) { bv = ov; bc = oc; }
        }
        float auxv = ssnS[tid] + mqS[bc] - 2.f * bv;
        #pragma unroll
        for (int off = 32; off; off >>= 1) auxv += __shfl_xor(auxv, off);
        if (tid == 0) aux_part[bid] = auxv;
    }
}

// ---------------- Kernel B: top-TPK per row on bf16 keys, 2-pass 12/4 radix ----
// 12-bit first digit keeps the proven exponent-spread (no hot-bin atomics);
// low 4 bits resolved by lanes 0-15. Candidate SET semantics only; rescore
// re-ranks exactly.
__global__ __launch_bounds__(256) void topk_kernel(
    const unsigned short* __restrict__ dists, int* __restrict__ idxOut)
{
    int row = blockIdx.x;
    const unsigned short* dv = dists + (size_t)row * TT;
    int t = threadIdx.x;
    int lane = t & 63, w = t >> 6;

    unsigned u[16];
    {
        const uint4* p = (const uint4*)(dv + t * 16);
        uint4 a = p[0], b = p[1];
        unsigned ws[8] = {a.x, a.y, a.z, a.w, b.x, b.y, b.z, b.w};
        #pragma unroll
        for (int i = 0; i < 8; ++i) {
            u[i*2]   = mono16(ws[i] & 0xFFFFu);
            u[i*2+1] = mono16(ws[i] >> 16);
        }
    }

    __shared__ int hist[4096];
    __shared__ int wtot[4];
    __shared__ int binSel, tgtS;
    __shared__ int nGtS, posS, eqPos;

    int target = TPK;

    // ---- pass 1: top 12 bits over 4096 bins ----
    {
        int4* hz = (int4*)&hist[t * 16];
        hz[0] = (int4){0,0,0,0}; hz[1] = (int4){0,0,0,0};
        hz[2] = (int4){0,0,0,0}; hz[3] = (int4){0,0,0,0};
        __syncthreads();
        #pragma unroll
        for (int j = 0; j < 16; ++j) atomicAdd(&hist[u[j] >> 4], 1);
        __syncthreads();
        int cnt[16], ls[16];
        {
            const int4* hp = (const int4*)&hist[t * 16];
            int4 c0 = hp[0], c1 = hp[1], c2 = hp[2], c3 = hp[3];
            cnt[0]=c0.x; cnt[1]=c0.y; cnt[2]=c0.z; cnt[3]=c0.w;
            cnt[4]=c1.x; cnt[5]=c1.y; cnt[6]=c1.z; cnt[7]=c1.w;
            cnt[8]=c2.x; cnt[9]=c2.y; cnt[10]=c2.z; cnt[11]=c2.w;
            cnt[12]=c3.x; cnt[13]=c3.y; cnt[14]=c3.z; cnt[15]=c3.w;
        }
        int run = 0;
        #pragma unroll
        for (int i = 15; i >= 0; --i) { run += cnt[i]; ls[i] = run; }
        int S = run;
        #pragma unroll
        for (int off = 1; off < 64; off <<= 1) {
            int o = __shfl_down(S, off);
            if (lane + off < 64) S += o;
        }
        if (lane == 0) wtot[w] = S;
        __syncthreads();
        int after = 0;
        for (int ww = w + 1; ww < 4; ++ww) after += wtot[ww];
        int St1 = S - run + after;
        #pragma unroll
        for (int i = 0; i < 16; ++i) {
            int sfxb = ls[i] + St1;
            if (sfxb >= target && sfxb - cnt[i] < target) {
                binSel = t * 16 + i; tgtS = target - (sfxb - cnt[i]);
            }
        }
        __syncthreads();
    }
    unsigned prefix12 = (unsigned)binSel;
    target = tgtS;
    __syncthreads();

    // ---- pass 2: low 4 bits (16 bins, lanes 0-15 of wave 0) ----
    if (t < 16) hist[t] = 0;
    __syncthreads();
    #pragma unroll
    for (int j = 0; j < 16; ++j)
        if ((u[j] >> 4) == prefix12) atomicAdd(&hist[u[j] & 0xF], 1);
    __syncthreads();
    if (t < 16) {
        int cnt = hist[t];
        int S = cnt;
        #pragma unroll
        for (int off = 1; off < 16; off <<= 1) {
            int o = __shfl_down(S, off);
            if (t + off < 16) S += o;
        }
        if (S >= target && S - cnt < target) binSel = t;
    }
    __syncthreads();
    unsigned pivot = (prefix12 << 4) | (unsigned)binSel;

    // ---- epilogue: compact >pivot, then ==pivot (unordered, capped) ----
    if (t == 0) { nGtS = 0; posS = 0; eqPos = 0; }
    __syncthreads();
    int myg = 0;
    #pragma unroll
    for (int j = 0; j < 16; ++j) myg += (u[j] > pivot) ? 1 : 0;
    if (myg) atomicAdd(&nGtS, myg);
    __syncthreads();
    int n_gt = nGtS;
    int n_need = TPK - n_gt;
    int* out = idxOut + (size_t)row * TPK;
    #pragma unroll
    for (int j = 0; j < 16; ++j) {
        if (u[j] > pivot) {
            int p = atomicAdd(&posS, 1);
            out[p] = t * 16 + j;
        } else if (u[j] == pivot) {
            int p = atomicAdd(&eqPos, 1);
            if (p < n_need) out[n_gt + p] = t * 16 + j;
        }
    }
}

// ---------------- Kernel B2: f64 rescore, branchless u32-prefix rank ----------
__global__ __launch_bounds__(640) void rescore_kernel(
    const float* __restrict__ q, const float* __restrict__ k,
    const float* __restrict__ means, const double* __restrict__ invn,
    const int* __restrict__ candQ, const int* __restrict__ candK,
    int* __restrict__ idxQ, int* __restrict__ idxK,
    int* __restrict__ counts)
{
    int bid = blockIdx.x;
    int rid = (bid & 7) * 512 + (bid >> 3);   // 4096 % 8 == 0 -> bijective
    int side = rid >> 11;            // 0=Q, 1=K
    int row = rid & 2047;            // bh*NC + c
    int c = row & (NCC - 1);
    int bh = row >> 6;
    int h = bh % HH;

    const int* cand = (side ? candK : candQ) + (size_t)row * TPK;
    int* outIdx     = (side ? idxK : idxQ) + (size_t)row * WSZW;
    const float* xbase = (side ? k : q) + (size_t)bh * TT * DD;
    const double* invp = invn + (side ? (size_t)BB * HH * TT : 0) + (size_t)bh * TT;

    __shared__ double   mD[DD];
    __shared__ unsigned hiS[TPK];
    __shared__ unsigned loS[TPK];
    __shared__ int      kiS[TPK];

    int tid = threadIdx.x;
    if (tid < DD) mD[tid] = (double)means[((size_t)h * NCC + c) * DD + tid];
    __syncthreads();

    int g = tid >> 2;                // candidate 0..159
    int qt = tid & 3;                // quarter-row 0..3
    int tok = cand[g];
    const float* xp = xbase + (size_t)tok * DD + qt * 16;
    double inv = invp[tok];          // 4 lanes same addr -> broadcast
    double d0 = 0.0, d1 = 0.0;
    #pragma unroll
    for (int i = 0; i < 2; ++i) {
        float4 va = *(const float4*)(xp + i * 4);
        int d = qt * 16 + i * 4;
        d0 += (double)va.x * mD[d]   + (double)va.y * mD[d+1]
            + (double)va.z * mD[d+2] + (double)va.w * mD[d+3];
    }
    #pragma unroll
    for (int i = 2; i < 4; ++i) {
        float4 va = *(const float4*)(xp + i * 4);
        int d = qt * 16 + i * 4;
        d1 += (double)va.x * mD[d]   + (double)va.y * mD[d+1]
            + (double)va.z * mD[d+2] + (double)va.w * mD[d+3];
    }
    double dot = d0 + d1;
    dot += __shfl_xor(dot, 1); dot += __shfl_xor(dot, 2);
    double v = dot * inv;            // identical across the 4-lane group
    unsigned long long key = mono64(v);
    unsigned myhi = (unsigned)(key >> 32), mylo = (unsigned)key;
    if (qt == 0) { hiS[g] = myhi; loS[g] = mylo; kiS[g] = tok; }
    __syncthreads();

    // phase 1: branchless rank on 32-bit prefixes (1 LDS b32 read per iter)
    int rk = 0, eq = 0;
    #pragma unroll 8
    for (int i = 0; i < TPK / 4; ++i) {
        unsigned hj = hiS[qt * (TPK / 4) + i];
        rk += (hj > myhi) ? 1 : 0;
        eq += (hj == myhi) ? 1 : 0;
    }
    rk += __shfl_xor(rk, 1); rk += __shfl_xor(rk, 2);
    eq += __shfl_xor(eq, 1); eq += __shfl_xor(eq, 2);

    // phase 2 (rare): exact 64-bit + token recount when hi-prefix ties exist
    if (eq > 1) {
        int rk2 = 0;
        for (int i = 0; i < TPK / 4; ++i) {
            int j = qt * (TPK / 4) + i;
            unsigned hj = hiS[j];
            if (hj > myhi) rk2++;
            else if (hj == myhi) {
                unsigned lj = loS[j];
                if (lj > mylo || (lj == mylo && kiS[j] < tok)) rk2++;
            }
        }
        rk2 += __shfl_xor(rk2, 1); rk2 += __shfl_xor(rk2, 2);
        rk = rk2;
    }

    if (qt == 0 && rk < WSZW) {
        outIdx[rk] = tok;
        if (side == 0) atomicAdd(&counts[bh * TT + tok], 1);
    }
}

// ---------------- Kernel C: bf16 MFMA attention, 130-row LDS, bf16 so out ------
__global__ __launch_bounds__(512, 8) void attn_kernel(
    const float* __restrict__ q, const float* __restrict__ k, const float* __restrict__ v,
    const float* __restrict__ mem_key, const float* __restrict__ mem_value,
    const int* __restrict__ idxQ, const int* __restrict__ idxK,
    unsigned short* __restrict__ so)
{
    // XCD-bijective swizzle (2048 % 8 == 0): 256 consecutive blks per XCD
    int bid = blockIdx.x;
    int blk = (bid & 7) * 256 + (bid >> 3);
    int c = blk % NCC;
    int bh = blk / NCC;
    int h = bh % HH;

    __shared__ __align__(16) unsigned short KsS[130 * 64];   // [kv][d] swizzled (temp V in P1/P2)
    __shared__ __align__(16) unsigned short VtS[64 * 168];   // [d][kv], pad 168

    int tid = threadIdx.x;
    int w = tid >> 6, l = tid & 63;
    int lr = l & 15, lg = l >> 4;

    const float* memK = mem_key   + ((size_t)h * NCC + c) * (MEMN * DD);
    const float* memV = mem_value + ((size_t)h * NCC + c) * (MEMN * DD);

    // ---- entry: resolve staging rows + issue ALL token-index gathers ----
    int stRow[3], stCh[3];
    const float *vsrcR[3], *ksrcR[3];
    #pragma unroll
    for (int s = 0; s < 3; ++s) {
        int idx = tid + s * 512;
        stRow[s] = idx >> 3; stCh[s] = idx & 7;
        vsrcR[s] = nullptr; ksrcR[s] = nullptr;
        if (idx < 1280 && stRow[s] < KVW) {
            if (stRow[s] == 0) { vsrcR[s] = memV; ksrcR[s] = memK; }
            else {
                int tk = idxK[(size_t)blk * WSZW + stRow[s] - 1];
                vsrcR[s] = v + ((size_t)bh * TT + tk) * DD;
                ksrcR[s] = k + ((size_t)bh * TT + tk) * DD;
            }
        }
    }

    // ---- Q frags (independent chase, overlaps everything) ----
    bf16x8 qf[2];
    {
        int tq = idxQ[(size_t)blk * WSZW + w * 16 + lr];
        const float* qp = q + ((size_t)bh * TT + tq) * DD;
        #pragma unroll
        for (int ks = 0; ks < 2; ++ks) {
            float4 a = *(const float4*)(qp + ks * 32 + lg * 8);
            float4 b = *(const float4*)(qp + ks * 32 + lg * 8 + 4);
            qf[ks] = pack8(a, b);
        }
    }

    // ---- V gather window (batched) ----
    uint4 vw[3];
    #pragma unroll
    for (int s = 0; s < 3; ++s) {
        vw[s] = (uint4){0,0,0,0};
        if (vsrcR[s]) {
            float4 a = *(const float4*)(vsrcR[s] + stCh[s] * 8);
            float4 b = *(const float4*)(vsrcR[s] + stCh[s] * 8 + 4);
            vw[s].x = pk2(a.x, a.y); vw[s].y = pk2(a.z, a.w);
            vw[s].z = pk2(b.x, b.y); vw[s].w = pk2(b.z, b.w);
        }
    }
    // ---- K gather window (batched) ----
    uint4 kw[3];
    #pragma unroll
    for (int s = 0; s < 3; ++s) {
        kw[s] = (uint4){0,0,0,0};
        if (ksrcR[s]) {
            float4 a = *(const float4*)(ksrcR[s] + stCh[s] * 8);
            float4 b = *(const float4*)(ksrcR[s] + stCh[s] * 8 + 4);
            kw[s].x = pk2(a.x, a.y); kw[s].y = pk2(a.z, a.w);
            kw[s].z = pk2(b.x, b.y); kw[s].w = pk2(b.z, b.w);
        }
    }

    // ---- P1: V -> row-major swizzled (valid rows only) ----
    #pragma unroll
    for (int s = 0; s < 3; ++s)
        if (vsrcR[s])
            *reinterpret_cast<uint4*>(
                &KsS[stRow[s] * 64 + ((stCh[s] ^ (stRow[s] & 7)) * 8)]) = vw[s];
    __syncthreads();

    // ---- P2: Vt column segments -> regs (clamped rows; broadcast-class) ----
    unsigned short vreg[3][8];
    #pragma unroll
    for (int s = 0; s < 3; ++s) {
        int idx = tid + s * 512;
        if (idx < 1280) {
            int d = idx & 63, rowblk = idx >> 6;
            #pragma unroll
            for (int i = 0; i < 8; ++i) {
                int row = rowblk * 8 + i;
                int pr = (row < KVW) ? row : 128;
                vreg[s][i] = KsS[pr * 64 + (((d >> 3) ^ (pr & 7)) * 8) + (d & 7)];
            }
        }
    }
    __syncthreads();

    // ---- P3: write Vt (b128 rows) + K (valid rows only) ----
    #pragma unroll
    for (int s = 0; s < 3; ++s) {
        int idx = tid + s * 512;
        if (idx < 1280) {
            int d = idx & 63, rowblk = idx >> 6;
            uint4 ow;
            ow.x = (unsigned)vreg[s][0] | ((unsigned)vreg[s][1] << 16);
            ow.y = (unsigned)vreg[s][2] | ((unsigned)vreg[s][3] << 16);
            ow.z = (unsigned)vreg[s][4] | ((unsigned)vreg[s][5] << 16);
            ow.w = (unsigned)vreg[s][6] | ((unsigned)vreg[s][7] << 16);
            *reinterpret_cast<uint4*>(&VtS[d * 168 + rowblk * 8]) = ow;
        }
    }
    #pragma unroll
    for (int s = 0; s < 3; ++s)
        if (ksrcR[s])
            *reinterpret_cast<uint4*>(
                &KsS[stRow[s] * 64 + ((stCh[s] ^ (stRow[s] & 7)) * 8)]) = kw[s];
    __syncthreads();

    // ---- compute (swapped QK^T, P in regs, Vt b128 B-frags) ----
    f32x4 acc[4];
    #pragma unroll
    for (int dt = 0; dt < 4; ++dt) acc[dt] = (f32x4){0.f, 0.f, 0.f, 0.f};
    float s_sum = 0.f;

    int src0 = lr + ((lg & 1) * 2) * 16;
    int src1 = src0 + 16;
    bool hi = (lg >> 1) != 0;

    for (int kb = 0; kb < 5; ++kb) {
        bf16x8 kf[2][2];
        #pragma unroll
        for (int kvt = 0; kvt < 2; ++kvt)
            #pragma unroll
            for (int ks = 0; ks < 2; ++ks) {
                int row = kb * 32 + kvt * 16 + lr;
                int pr = (row < KVW) ? row : 128;
                int phys = (ks * 4 + lg) ^ (pr & 7);
                kf[kvt][ks] = *reinterpret_cast<const bf16x8*>(&KsS[pr * 64 + phys * 8]);
            }
        __builtin_amdgcn_s_setprio(1);
        unsigned pk[2][2];
        #pragma unroll
        for (int kvt = 0; kvt < 2; ++kvt) {
            f32x4 sf = __builtin_amdgcn_mfma_f32_16x16x32_bf16(
                kf[kvt][0], qf[0], (f32x4){0.f,0.f,0.f,0.f}, 0, 0, 0);
            sf = __builtin_amdgcn_mfma_f32_16x16x32_bf16(kf[kvt][1], qf[1], sf, 0, 0, 0);
            float e[4];
            #pragma unroll
            for (int r = 0; r < 4; ++r) {
                int kv = kb * 32 + kvt * 16 + lg * 4 + r;
                e[r] = (kv < KVW) ? __expf(sf[r] * SCALE) : 0.f;
                s_sum += e[r];
            }
            pk[kvt][0] = pk2(e[0], e[1]);
            pk[kvt][1] = pk2(e[2], e[3]);
        }
        unsigned a00 = __shfl(pk[0][0], src0), a01 = __shfl(pk[0][1], src0);
        unsigned a10 = __shfl(pk[1][0], src0), a11 = __shfl(pk[1][1], src0);
        unsigned b00 = __shfl(pk[0][0], src1), b01 = __shfl(pk[0][1], src1);
        unsigned b10 = __shfl(pk[1][0], src1), b11 = __shfl(pk[1][1], src1);
        union { unsigned u[4]; bf16x8 v; } pu;
        pu.u[0] = hi ? a10 : a00;
        pu.u[1] = hi ? a11 : a01;
        pu.u[2] = hi ? b10 : b00;
        pu.u[3] = hi ? b11 : b01;
        #pragma unroll
        for (int dt = 0; dt < 4; ++dt) {
            bf16x8 vf = *reinterpret_cast<const bf16x8*>(
                &VtS[(dt * 16 + lr) * 168 + kb * 32 + lg * 8]);
            acc[dt] = __builtin_amdgcn_mfma_f32_16x16x32_bf16(pu.v, vf, acc[dt], 0, 0, 0);
        }
        __builtin_amdgcn_s_setprio(0);
    }

    s_sum += __shfl_xor(s_sum, 16);
    s_sum += __shfl_xor(s_sum, 32);
    float sinv[4];
    #pragma unroll
    for (int r = 0; r < 4; ++r)
        sinv[r] = 1.f / __shfl(s_sum, lg * 4 + r);

    // ---- store O as bf16 (halves write traffic + reduce's read traffic) ----
    #pragma unroll
    for (int r = 0; r < 4; ++r) {
        int row = w * 16 + lg * 4 + r;
        unsigned short* op = so + (((size_t)blk * WSZW + row) * DD);
        #pragma unroll
        for (int dt = 0; dt < 4; ++dt) {
            float ov = acc[dt][r] * sinv[r];
            op[dt * 16 + lr] = (unsigned short)(pk2(ov, ov) & 0xFFFFu);
        }
    }
}

// ---------------- Kernel F: fused per-bh scan + CSR fill + aux finalize --------
__global__ __launch_bounds__(256) void scanfill_kernel(
    const int* __restrict__ counts, int* __restrict__ offs,
    const int* __restrict__ idxQ, int* __restrict__ csr,
    const float* __restrict__ auxp, float* __restrict__ out)
{
    __shared__ int offsL[TT];
    __shared__ int curL[TT];
    __shared__ int wsum[256];
    __shared__ float auxW[4];

    int bh = blockIdx.x;
    int t = threadIdx.x;

    // ---- aux fold (loads only on block 0; uniform barriers) ----
    float s = 0.f;
    if (bh == 0)
        for (int i = t; i < 4096; i += 256) s += auxp[i];
    #pragma unroll
    for (int off = 32; off; off >>= 1) s += __shfl_xor(s, off);
    if ((t & 63) == 0) auxW[t >> 6] = s;
    __syncthreads();
    if (bh == 0 && t == 0)
        out[(size_t)BB * HH * TT * DD] =
            (auxW[0] + auxW[1] + auxW[2] + auxW[3]) *
            (1.0f / (float)(BB * HH * 2 * TT * DD));

    // ---- exclusive scan over counts[bh] ----
    const int* cb = counts + (size_t)bh * TT;
    int* ob = offs + (size_t)bh * TT;
    int loc[16]; int sum = 0;
    #pragma unroll
    for (int i = 0; i < 16; ++i) { loc[i] = sum; sum += cb[t * 16 + i]; }
    wsum[t] = sum;
    __syncthreads();
    for (int off = 1; off < 256; off <<= 1) {
        int vv = (t >= off) ? wsum[t - off] : 0;
        __syncthreads();
        wsum[t] += vv;
        __syncthreads();
    }
    int ex = (t == 0) ? 0 : wsum[t - 1];
    #pragma unroll
    for (int i = 0; i < 16; ++i) {
        int o = ex + loc[i];
        ob[t * 16 + i] = o;
        offsL[t * 16 + i] = o;
        curL[t * 16 + i] = 0;
    }
    __syncthreads();

    // ---- CSR fill (LDS atomics) ----
    const int* iq = idxQ + ((size_t)bh << 13);
    int* cs = csr + ((size_t)bh << 13);
    for (int i = t; i < 8192; i += 256) {
        int tok = iq[i];
        int p = offsL[tok] + atomicAdd(&curL[tok], 1);
        cs[p] = i;
    }
}

// ---------------- Kernel H: gather-reduce (bf16 so), pair-batched + XCD swz ----
__global__ __launch_bounds__(256) void reduce_kernel(
    const unsigned short* __restrict__ so, const int* __restrict__ counts,
    const int* __restrict__ offs, const int* __restrict__ csr,
    float* __restrict__ out)
{
    int b0 = blockIdx.x;
    int b = (b0 & 7) * 4096 + (b0 >> 3);     // 32768 % 8 == 0 -> bijective
    int gt = b * 4 + (threadIdx.x >> 6);
    int lane = threadIdx.x & 63;
    int bh = gt >> 12;
    int n = counts[gt];
    int st = offs[gt];
    const int* cs = csr + ((size_t)bh << 13);
    const unsigned short* sob = so + (((size_t)bh << 13) * DD);
    float acc = 0.f;
    int j = 0;
    for (; j + 2 <= n; j += 2) {             // pair-batched: 2 idx, then 2 rows
        int s0 = cs[st + j], s1 = cs[st + j + 1];
        float v0 = bf2f(sob[(size_t)s0 * DD + lane]);
        float v1 = bf2f(sob[(size_t)s1 * DD + lane]);
        acc += v0 + v1;
    }
    if (j < n) acc += bf2f(sob[(size_t)cs[st + j] * DD + lane]);
    out[(size_t)gt * DD + lane] = acc / ((float)n + EPSF);
}

extern "C" void kernel_launch(void* const* d_in, const int* in_sizes, int n_in,
                              void* d_out, int out_size, void* d_ws, size_t ws_size,
                              hipStream_t stream) {
    const float* q        = (const float*)d_in[0];
    const float* k        = (const float*)d_in[1];
    const float* v        = (const float*)d_in[2];
    const float* means    = (const float*)d_in[3];
    const float* mem_key  = (const float*)d_in[4];
    const float* mem_val  = (const float*)d_in[5];
    float* out = (float*)d_out;

    const size_t nRows = (size_t)BB * HH * NCC;             // 2048
    const size_t nTok  = (size_t)BB * HH * TT;              // 131072
    const size_t nDist = (size_t)BB * HH * NCC * TT;        // 16777216
    unsigned short* distsQ = (unsigned short*)d_ws;         // bf16, 16.7M
    unsigned short* distsK = distsQ + nDist;                // bf16, 16.7M (contiguous)
    unsigned short* so     = distsQ;                        // bf16, aliases dists (written after rescore)
    int*   idxQ   = (int*)(distsK + nDist);                 // 262144 i
    int*   idxK   = idxQ + nRows * WSZW;                    // 262144 i
    int*   counts = idxK + nRows * WSZW;                    // 131072 i (zeroed in dists_kernel)
    float* auxp   = (float*)(counts + nTok);                // 4096 f (per-block partials)
    int*   offs   = (int*)(auxp + 4096);                    // 131072 i
    int*   csr    = offs + nTok;                            // 262144 i
    int*   candQ  = csr + nTok * 2;                         // 2048*160 i
    int*   candK  = candQ + nRows * TPK;                    // 2048*160 i (contiguous after candQ)
    uintptr_t ip  = (uintptr_t)(candK + nRows * TPK);
    ip = (ip + 15) & ~(uintptr_t)15;
    double* invn  = (double*)ip;                            // 2*131072 d (Q then K)

    dists_kernel<<<dim3(BB * HH * (2 * TT / 64)), dim3(256), 0, stream>>>(
        q, k, means, distsQ, distsK, auxp, invn, counts);
    // single launch covers Q rows (0..2047 over distsQ/candQ) and K rows
    // (2048..4095 over distsK/candK) via buffer contiguity
    topk_kernel<<<dim3((unsigned)(2 * nRows)), dim3(256), 0, stream>>>(distsQ, candQ);
    rescore_kernel<<<dim3((unsigned)(2 * nRows)), dim3(640), 0, stream>>>(
        q, k, means, invn, candQ, candK, idxQ, idxK, counts);
    scanfill_kernel<<<dim3(BB * HH), dim3(256), 0, stream>>>(
        counts, offs, idxQ, csr, auxp, out);
    attn_kernel<<<dim3((unsigned)nRows), dim3(512), 0, stream>>>(
        q, k, v, mem_key, mem_val, idxQ, idxK, so);
    reduce_kernel<<<dim3((unsigned)(nTok / 4)), dim3(256), 0, stream>>>(
        so, counts, offs, csr, out);
}

// Round 26
// 164.238 us; speedup vs baseline: 1.6403x; 1.0556x over previous
//
#include <hip/hip_runtime.h>
#include <math.h>

#define BB 4
#define HH 8
#define TT 4096
#define DD 64
#define NCC 64
#define WSZW 128
#define TPK 160          // widened bf16 top-k; f64 rescore picks exact top-128
#define MEMN 1
#define KVW (MEMN + WSZW)   // 129
constexpr float EPSF = 1e-5f;
constexpr float SCALE = 0.125f;  // 64^-0.5

typedef __attribute__((ext_vector_type(8))) short bf16x8;
typedef __attribute__((ext_vector_type(4))) float f32x4;

// HW packed f32->bf16 (RNE), 1 instruction vs ~7 for the manual bit-twiddle
static __device__ __forceinline__ unsigned int pk2(float a, float b) {
    unsigned int r;
    asm("v_cvt_pk_bf16_f32 %0, %1, %2" : "=v"(r) : "v"(a), "v"(b));
    return r;
}
static __device__ __forceinline__ bf16x8 pack8(float4 a, float4 b) {
    union { unsigned int u[4]; bf16x8 v; } r;
    r.u[0] = pk2(a.x, a.y); r.u[1] = pk2(a.z, a.w);
    r.u[2] = pk2(b.x, b.y); r.u[3] = pk2(b.z, b.w);
    return r.v;
}
static __device__ __forceinline__ unsigned mono16(unsigned u) {
    return (u ^ ((u & 0x8000u) ? 0xFFFFu : 0x8000u)) & 0xFFFFu;
}
static __device__ __forceinline__ unsigned long long mono64(double d) {
    unsigned long long b = (unsigned long long)__double_as_longlong(d);
    return b ^ (((long long)b < 0) ? ~0ULL : 0x8000000000000000ULL);
}
static __device__ __forceinline__ float bf2f(unsigned short u) {
    return __uint_as_float(((unsigned)u) << 16);
}

// ---------------- Kernel A: dists via split-bf16 MFMA -> bf16 dists ------------
__global__ __launch_bounds__(256, 4) void dists_kernel(
    const float* __restrict__ q, const float* __restrict__ k,
    const float* __restrict__ means,
    unsigned short* __restrict__ distsQ, unsigned short* __restrict__ distsK,
    float* __restrict__ aux_part, double* __restrict__ invn,
    int* __restrict__ counts)
{
    __shared__ __align__(16) unsigned short mhS[64 * 64];   // [c][d] swizzled chunks
    __shared__ __align__(16) unsigned short mlS[64 * 64];
    __shared__ __align__(16) unsigned short xhS[64 * 64];   // [tok][d]
    __shared__ __align__(16) unsigned short xlS[64 * 64];
    __shared__ float mqS[64];      // per-cluster ||m||^2
    __shared__ float ssnS[64];     // per-token ||xn||^2
    __shared__ float wMaxS[64 * 5];
    __shared__ int   wIdxS[64 * 5];

    const int chunks = (2 * TT) / 64;          // 128
    int bid0 = blockIdx.x;                     // 4096
    int bid = (bid0 & 7) * 512 + (bid0 >> 3);  // XCD-contiguous (4096 % 8 == 0)
    int bh = bid / chunks;
    int chunk = bid % chunks;
    int h = bh % HH;
    bool isQ = chunk < (TT / 64);
    int tbase = (isQ ? chunk : chunk - 64) * 64;
    const float* src = (isQ ? q : k) + ((size_t)bh * TT + tbase) * DD;
    unsigned short* dst = isQ ? distsQ : distsK;
    double* invdst = invn + (isQ ? 0 : (size_t)BB * HH * TT) + (size_t)bh * TT + tbase;

    int tid = threadIdx.x;

    // zero counts (replaces host memset): 4096 blocks x 32 ints = 131072
    if (tid < 32) counts[(size_t)bid0 * 32 + tid] = 0;

    int row = tid >> 2, part = tid & 3;        // row = cluster idx AND token idx

    // ---- stage means hi/lo (swizzled) + ||m||^2 ----
    {
        const float* mp = means + ((size_t)h * NCC + row) * DD + part * 16;
        float f[16];
        float msq = 0.f;
        #pragma unroll
        for (int i = 0; i < 4; ++i) {
            float4 va = *(const float4*)(mp + i * 4);
            f[i*4] = va.x; f[i*4+1] = va.y; f[i*4+2] = va.z; f[i*4+3] = va.w;
            msq += va.x*va.x + va.y*va.y + va.z*va.z + va.w*va.w;
        }
        msq += __shfl_xor(msq, 1);
        msq += __shfl_xor(msq, 2);
        if (part == 0) mqS[row] = msq;
        #pragma unroll
        for (int cc = 0; cc < 2; ++cc) {
            unsigned hw[4], lw[4];
            #pragma unroll
            for (int j2 = 0; j2 < 4; ++j2) {
                float a = f[cc*8 + j2*2], b = f[cc*8 + j2*2 + 1];
                unsigned p = pk2(a, b);
                float ha = __uint_as_float(p << 16);
                float hb = __uint_as_float(p & 0xFFFF0000u);
                hw[j2] = p; lw[j2] = pk2(a - ha, b - hb);
            }
            int ch = part * 2 + cc;
            int phys = ch ^ (row & 7);
            *reinterpret_cast<uint4*>(&mhS[row * 64 + phys * 8]) = (uint4){hw[0],hw[1],hw[2],hw[3]};
            *reinterpret_cast<uint4*>(&mlS[row * 64 + phys * 8]) = (uint4){lw[0],lw[1],lw[2],lw[3]};
        }
    }
    // ---- stage xn hi/lo (swizzled); f64 norm -> invn + ssn ----
    {
        const float* xp = src + (size_t)row * DD + part * 16;
        float f[16];
        double ssd = 0.0;
        #pragma unroll
        for (int i = 0; i < 4; ++i) {
            float4 va = *(const float4*)(xp + i * 4);
            f[i*4] = va.x; f[i*4+1] = va.y; f[i*4+2] = va.z; f[i*4+3] = va.w;
            ssd += (double)va.x*va.x + (double)va.y*va.y
                 + (double)va.z*va.z + (double)va.w*va.w;
        }
        ssd += __shfl_xor(ssd, 1);
        ssd += __shfl_xor(ssd, 2);
        double invd = 1.0 / fmax(sqrt(ssd), 1e-12);
        if (part == 0) {
            invdst[row] = invd;
            ssnS[row] = (float)(ssd * invd * invd);
        }
        float inv = (float)invd;
        #pragma unroll
        for (int i = 0; i < 16; ++i) f[i] *= inv;
        #pragma unroll
        for (int cc = 0; cc < 2; ++cc) {
            unsigned hw[4], lw[4];
            #pragma unroll
            for (int j2 = 0; j2 < 4; ++j2) {
                float a = f[cc*8 + j2*2], b = f[cc*8 + j2*2 + 1];
                unsigned p = pk2(a, b);
                float ha = __uint_as_float(p << 16);
                float hb = __uint_as_float(p & 0xFFFF0000u);
                hw[j2] = p; lw[j2] = pk2(a - ha, b - hb);
            }
            int ch = part * 2 + cc;
            int phys = ch ^ (row & 7);
            *reinterpret_cast<uint4*>(&xhS[row * 64 + phys * 8]) = (uint4){hw[0],hw[1],hw[2],hw[3]};
            *reinterpret_cast<uint4*>(&xlS[row * 64 + phys * 8]) = (uint4){lw[0],lw[1],lw[2],lw[3]};
        }
    }
    __syncthreads();

    int l = tid & 63, w = tid >> 6;
    int lr = l & 15, lg = l >> 4;

    // ---- A frags: cluster tile w (reused across all 4 token tiles) ----
    bf16x8 mhF[2], mlF[2];
    #pragma unroll
    for (int ks = 0; ks < 2; ++ks) {
        int r2 = w * 16 + lr;
        int phys = (ks * 4 + lg) ^ (r2 & 7);
        mhF[ks] = *reinterpret_cast<const bf16x8*>(&mhS[r2 * 64 + phys * 8]);
        mlF[ks] = *reinterpret_cast<const bf16x8*>(&mlS[r2 * 64 + phys * 8]);
    }

    // ---- GEMM: D[c = w*16+lg*4+r][tok = tt*16+lr], 6 mfma per token tile ----
    f32x4 accT[4];
    size_t rowb = (size_t)(bh * NCC) * TT;
    #pragma unroll
    for (int tt = 0; tt < 4; ++tt) {
        bf16x8 xhF[2], xlF[2];
        #pragma unroll
        for (int ks = 0; ks < 2; ++ks) {
            int r2 = tt * 16 + lr;
            int phys = (ks * 4 + lg) ^ (r2 & 7);
            xhF[ks] = *reinterpret_cast<const bf16x8*>(&xhS[r2 * 64 + phys * 8]);
            xlF[ks] = *reinterpret_cast<const bf16x8*>(&xlS[r2 * 64 + phys * 8]);
        }
        f32x4 a = (f32x4){0.f, 0.f, 0.f, 0.f};
        #pragma unroll
        for (int ks = 0; ks < 2; ++ks)
            a = __builtin_amdgcn_mfma_f32_16x16x32_bf16(mhF[ks], xhF[ks], a, 0, 0, 0);
        #pragma unroll
        for (int ks = 0; ks < 2; ++ks)
            a = __builtin_amdgcn_mfma_f32_16x16x32_bf16(mhF[ks], xlF[ks], a, 0, 0, 0);
        #pragma unroll
        for (int ks = 0; ks < 2; ++ks)
            a = __builtin_amdgcn_mfma_f32_16x16x32_bf16(mlF[ks], xhF[ks], a, 0, 0, 0);
        accT[tt] = a;
        #pragma unroll
        for (int r2 = 0; r2 < 4; ++r2) {
            int c = w * 16 + lg * 4 + r2;
            dst[rowb + (size_t)c * TT + tbase + tt * 16 + lr] =
                (unsigned short)(pk2(a[r2], a[r2]) & 0xFFFFu);
        }
    }

    // ---- argmax via shuffles (lane: token tt*16+lr, clusters w*16+lg*4+r) ----
    #pragma unroll
    for (int tt = 0; tt < 4; ++tt) {
        float bv = accT[tt][0]; int bc = w * 16 + lg * 4;
        #pragma unroll
        for (int r2 = 1; r2 < 4; ++r2)
            if (accT[tt][r2] > bv) { bv = accT[tt][r2]; bc = w * 16 + lg * 4 + r2; }
        #pragma unroll
        for (int off = 16; off <= 32; off <<= 1) {
            float ov = __shfl_xor(bv, off);
            int   oc = __shfl_xor(bc, off);
            if (ov > bv || (ov == bv && oc < bc)) { bv = ov; bc = oc; }
        }
        if (lg == 0) {
            wMaxS[(tt * 16 + lr) * 5 + w] = bv;
            wIdxS[(tt * 16 + lr) * 5 + w] = bc;
        }
    }
    __syncthreads();

    if (tid < 64) {
        float bv = -1e30f; int bc = 0;
        #pragma unroll
        for (int w2 = 0; w2 < 4; ++w2) {   // ascending cluster ranges
            float ov = wMaxS[tid * 5 + w2];
            int   oc = wIdxS[tid * 5 + w2];
            if (ov > bv || (ov == bv && oc < bc)) { bv = ov; bc = oc; }
        }
        float auxv = ssnS[tid] + mqS[bc] - 2.f * bv;
        #pragma unroll
        for (int off = 32; off; off >>= 1) auxv += __shfl_xor(auxv, off);
        if (tid == 0) aux_part[bid] = auxv;
    }
}

// ---------------- Kernel B: top-TPK per row, bf16 keys, 512 thr, 2-pass --------
__global__ __launch_bounds__(512) void topk_kernel(
    const unsigned short* __restrict__ dists, int* __restrict__ idxOut)
{
    int row = blockIdx.x;
    const unsigned short* dv = dists + (size_t)row * TT;
    int t = threadIdx.x;
    int lane = t & 63, w = t >> 6;            // 8 waves

    unsigned u[8];
    {
        uint4 a = *(const uint4*)(dv + t * 8);
        unsigned ws[4] = {a.x, a.y, a.z, a.w};
        #pragma unroll
        for (int i = 0; i < 4; ++i) {
            u[i*2]   = mono16(ws[i] & 0xFFFFu);
            u[i*2+1] = mono16(ws[i] >> 16);
        }
    }

    __shared__ int hist[4096];
    __shared__ int wtot[8];
    __shared__ int binSel, tgtS;
    __shared__ int nGtS, posS, eqPos;

    int target = TPK;

    // ---- pass 1: top 12 bits over 4096 bins ----
    {
        int4* hz = (int4*)&hist[t * 8];
        hz[0] = (int4){0,0,0,0}; hz[1] = (int4){0,0,0,0};
        __syncthreads();
        #pragma unroll
        for (int j = 0; j < 8; ++j) atomicAdd(&hist[u[j] >> 4], 1);
        __syncthreads();
        int cnt[8], ls[8];
        {
            const int4* hp = (const int4*)&hist[t * 8];
            int4 c0 = hp[0], c1 = hp[1];
            cnt[0]=c0.x; cnt[1]=c0.y; cnt[2]=c0.z; cnt[3]=c0.w;
            cnt[4]=c1.x; cnt[5]=c1.y; cnt[6]=c1.z; cnt[7]=c1.w;
        }
        int run = 0;
        #pragma unroll
        for (int i = 7; i >= 0; --i) { run += cnt[i]; ls[i] = run; }
        int S = run;
        #pragma unroll
        for (int off = 1; off < 64; off <<= 1) {
            int o = __shfl_down(S, off);
            if (lane + off < 64) S += o;
        }
        if (lane == 0) wtot[w] = S;
        __syncthreads();
        int after = 0;
        for (int ww = w + 1; ww < 8; ++ww) after += wtot[ww];
        int St1 = S - run + after;
        #pragma unroll
        for (int i = 0; i < 8; ++i) {
            int sfxb = ls[i] + St1;
            if (sfxb >= target && sfxb - cnt[i] < target) {
                binSel = t * 8 + i; tgtS = target - (sfxb - cnt[i]);
            }
        }
        __syncthreads();
    }
    unsigned prefix12 = (unsigned)binSel;
    target = tgtS;
    __syncthreads();

    // ---- pass 2: low 4 bits (16 bins, lanes 0-15 of wave 0) ----
    if (t < 16) hist[t] = 0;
    __syncthreads();
    #pragma unroll
    for (int j = 0; j < 8; ++j)
        if ((u[j] >> 4) == prefix12) atomicAdd(&hist[u[j] & 0xF], 1);
    __syncthreads();
    if (t < 16) {
        int cnt = hist[t];
        int S = cnt;
        #pragma unroll
        for (int off = 1; off < 16; off <<= 1) {
            int o = __shfl_down(S, off);
            if (t + off < 16) S += o;
        }
        if (S >= target && S - cnt < target) binSel = t;
    }
    __syncthreads();
    unsigned pivot = (prefix12 << 4) | (unsigned)binSel;

    // ---- epilogue: compact >pivot, then ==pivot (unordered, capped) ----
    if (t == 0) { nGtS = 0; posS = 0; eqPos = 0; }
    __syncthreads();
    int myg = 0;
    #pragma unroll
    for (int j = 0; j < 8; ++j) myg += (u[j] > pivot) ? 1 : 0;
    if (myg) atomicAdd(&nGtS, myg);
    __syncthreads();
    int n_gt = nGtS;
    int n_need = TPK - n_gt;
    int* out = idxOut + (size_t)row * TPK;
    #pragma unroll
    for (int j = 0; j < 8; ++j) {
        if (u[j] > pivot) {
            int p = atomicAdd(&posS, 1);
            out[p] = t * 8 + j;
        } else if (u[j] == pivot) {
            int p = atomicAdd(&eqPos, 1);
            if (p < n_need) out[n_gt + p] = t * 8 + j;
        }
    }
}

// ---------------- Kernel B2: f64 rescore, branchless u32-prefix rank ----------
__global__ __launch_bounds__(640) void rescore_kernel(
    const float* __restrict__ q, const float* __restrict__ k,
    const float* __restrict__ means, const double* __restrict__ invn,
    const int* __restrict__ candQ, const int* __restrict__ candK,
    int* __restrict__ idxQ, int* __restrict__ idxK,
    int* __restrict__ counts)
{
    int bid = blockIdx.x;
    int rid = (bid & 7) * 512 + (bid >> 3);   // 4096 % 8 == 0 -> bijective
    int side = rid >> 11;            // 0=Q, 1=K
    int row = rid & 2047;            // bh*NC + c
    int c = row & (NCC - 1);
    int bh = row >> 6;
    int h = bh % HH;

    const int* cand = (side ? candK : candQ) + (size_t)row * TPK;
    int* outIdx     = (side ? idxK : idxQ) + (size_t)row * WSZW;
    const float* xbase = (side ? k : q) + (size_t)bh * TT * DD;
    const double* invp = invn + (side ? (size_t)BB * HH * TT : 0) + (size_t)bh * TT;

    __shared__ double   mD[DD];
    __shared__ unsigned hiS[TPK];
    __shared__ unsigned loS[TPK];
    __shared__ int      kiS[TPK];

    int tid = threadIdx.x;
    if (tid < DD) mD[tid] = (double)means[((size_t)h * NCC + c) * DD + tid];
    __syncthreads();

    int g = tid >> 2;                // candidate 0..159
    int qt = tid & 3;                // quarter-row 0..3
    int tok = cand[g];
    const float* xp = xbase + (size_t)tok * DD + qt * 16;
    double inv = invp[tok];          // 4 lanes same addr -> broadcast
    double d0 = 0.0, d1 = 0.0;
    #pragma unroll
    for (int i = 0; i < 2; ++i) {
        float4 va = *(const float4*)(xp + i * 4);
        int d = qt * 16 + i * 4;
        d0 += (double)va.x * mD[d]   + (double)va.y * mD[d+1]
            + (double)va.z * mD[d+2] + (double)va.w * mD[d+3];
    }
    #pragma unroll
    for (int i = 2; i < 4; ++i) {
        float4 va = *(const float4*)(xp + i * 4);
        int d = qt * 16 + i * 4;
        d1 += (double)va.x * mD[d]   + (double)va.y * mD[d+1]
            + (double)va.z * mD[d+2] + (double)va.w * mD[d+3];
    }
    double dot = d0 + d1;
    dot += __shfl_xor(dot, 1); dot += __shfl_xor(dot, 2);
    double v = dot * inv;            // identical across the 4-lane group
    unsigned long long key = mono64(v);
    unsigned myhi = (unsigned)(key >> 32), mylo = (unsigned)key;
    if (qt == 0) { hiS[g] = myhi; loS[g] = mylo; kiS[g] = tok; }
    __syncthreads();

    // phase 1: branchless rank on 32-bit prefixes (1 LDS b32 read per iter)
    int rk = 0, eq = 0;
    #pragma unroll 8
    for (int i = 0; i < TPK / 4; ++i) {
        unsigned hj = hiS[qt * (TPK / 4) + i];
        rk += (hj > myhi) ? 1 : 0;
        eq += (hj == myhi) ? 1 : 0;
    }
    rk += __shfl_xor(rk, 1); rk += __shfl_xor(rk, 2);
    eq += __shfl_xor(eq, 1); eq += __shfl_xor(eq, 2);

    // phase 2 (rare): exact 64-bit + token recount when hi-prefix ties exist
    if (eq > 1) {
        int rk2 = 0;
        for (int i = 0; i < TPK / 4; ++i) {
            int j = qt * (TPK / 4) + i;
            unsigned hj = hiS[j];
            if (hj > myhi) rk2++;
            else if (hj == myhi) {
                unsigned lj = loS[j];
                if (lj > mylo || (lj == mylo && kiS[j] < tok)) rk2++;
            }
        }
        rk2 += __shfl_xor(rk2, 1); rk2 += __shfl_xor(rk2, 2);
        rk = rk2;
    }

    if (qt == 0 && rk < WSZW) {
        outIdx[rk] = tok;
        if (side == 0) atomicAdd(&counts[bh * TT + tok], 1);
    }
}

// ---------------- Kernel C: bf16 MFMA attention, 130-row LDS, bf16 so out ------
// (byte-identical to round 24's passing version: VtS stride 168 = 16B-aligned;
// PV reads are 2-way bank-aliased which is free on CDNA4)
__global__ __launch_bounds__(512, 8) void attn_kernel(
    const float* __restrict__ q, const float* __restrict__ k, const float* __restrict__ v,
    const float* __restrict__ mem_key, const float* __restrict__ mem_value,
    const int* __restrict__ idxQ, const int* __restrict__ idxK,
    unsigned short* __restrict__ so)
{
    // XCD-bijective swizzle (2048 % 8 == 0): 256 consecutive blks per XCD
    int bid = blockIdx.x;
    int blk = (bid & 7) * 256 + (bid >> 3);
    int c = blk % NCC;
    int bh = blk / NCC;
    int h = bh % HH;

    __shared__ __align__(16) unsigned short KsS[130 * 64];   // [kv][d] swizzled (temp V in P1/P2)
    __shared__ __align__(16) unsigned short VtS[64 * 168];   // [d][kv], pad 168

    int tid = threadIdx.x;
    int w = tid >> 6, l = tid & 63;
    int lr = l & 15, lg = l >> 4;

    const float* memK = mem_key   + ((size_t)h * NCC + c) * (MEMN * DD);
    const float* memV = mem_value + ((size_t)h * NCC + c) * (MEMN * DD);

    // ---- entry: resolve staging rows + issue ALL token-index gathers ----
    int stRow[3], stCh[3];
    const float *vsrcR[3], *ksrcR[3];
    #pragma unroll
    for (int s = 0; s < 3; ++s) {
        int idx = tid + s * 512;
        stRow[s] = idx >> 3; stCh[s] = idx & 7;
        vsrcR[s] = nullptr; ksrcR[s] = nullptr;
        if (idx < 1280 && stRow[s] < KVW) {
            if (stRow[s] == 0) { vsrcR[s] = memV; ksrcR[s] = memK; }
            else {
                int tk = idxK[(size_t)blk * WSZW + stRow[s] - 1];
                vsrcR[s] = v + ((size_t)bh * TT + tk) * DD;
                ksrcR[s] = k + ((size_t)bh * TT + tk) * DD;
            }
        }
    }

    // ---- Q frags (independent chase, overlaps everything) ----
    bf16x8 qf[2];
    {
        int tq = idxQ[(size_t)blk * WSZW + w * 16 + lr];
        const float* qp = q + ((size_t)bh * TT + tq) * DD;
        #pragma unroll
        for (int ks = 0; ks < 2; ++ks) {
            float4 a = *(const float4*)(qp + ks * 32 + lg * 8);
            float4 b = *(const float4*)(qp + ks * 32 + lg * 8 + 4);
            qf[ks] = pack8(a, b);
        }
    }

    // ---- V gather window (batched) ----
    uint4 vw[3];
    #pragma unroll
    for (int s = 0; s < 3; ++s) {
        vw[s] = (uint4){0,0,0,0};
        if (vsrcR[s]) {
            float4 a = *(const float4*)(vsrcR[s] + stCh[s] * 8);
            float4 b = *(const float4*)(vsrcR[s] + stCh[s] * 8 + 4);
            vw[s].x = pk2(a.x, a.y); vw[s].y = pk2(a.z, a.w);
            vw[s].z = pk2(b.x, b.y); vw[s].w = pk2(b.z, b.w);
        }
    }
    // ---- K gather window (batched) ----
    uint4 kw[3];
    #pragma unroll
    for (int s = 0; s < 3; ++s) {
        kw[s] = (uint4){0,0,0,0};
        if (ksrcR[s]) {
            float4 a = *(const float4*)(ksrcR[s] + stCh[s] * 8);
            float4 b = *(const float4*)(ksrcR[s] + stCh[s] * 8 + 4);
            kw[s].x = pk2(a.x, a.y); kw[s].y = pk2(a.z, a.w);
            kw[s].z = pk2(b.x, b.y); kw[s].w = pk2(b.z, b.w);
        }
    }

    // ---- P1: V -> row-major swizzled (valid rows only) ----
    #pragma unroll
    for (int s = 0; s < 3; ++s)
        if (vsrcR[s])
            *reinterpret_cast<uint4*>(
                &KsS[stRow[s] * 64 + ((stCh[s] ^ (stRow[s] & 7)) * 8)]) = vw[s];
    __syncthreads();

    // ---- P2: Vt column segments -> regs (clamped rows; broadcast-class) ----
    unsigned short vreg[3][8];
    #pragma unroll
    for (int s = 0; s < 3; ++s) {
        int idx = tid + s * 512;
        if (idx < 1280) {
            int d = idx & 63, rowblk = idx >> 6;
            #pragma unroll
            for (int i = 0; i < 8; ++i) {
                int row = rowblk * 8 + i;
                int pr = (row < KVW) ? row : 128;
                vreg[s][i] = KsS[pr * 64 + (((d >> 3) ^ (pr & 7)) * 8) + (d & 7)];
            }
        }
    }
    __syncthreads();

    // ---- P3: write Vt (b128 rows) + K (valid rows only) ----
    #pragma unroll
    for (int s = 0; s < 3; ++s) {
        int idx = tid + s * 512;
        if (idx < 1280) {
            int d = idx & 63, rowblk = idx >> 6;
            uint4 ow;
            ow.x = (unsigned)vreg[s][0] | ((unsigned)vreg[s][1] << 16);
            ow.y = (unsigned)vreg[s][2] | ((unsigned)vreg[s][3] << 16);
            ow.z = (unsigned)vreg[s][4] | ((unsigned)vreg[s][5] << 16);
            ow.w = (unsigned)vreg[s][6] | ((unsigned)vreg[s][7] << 16);
            *reinterpret_cast<uint4*>(&VtS[d * 168 + rowblk * 8]) = ow;
        }
    }
    #pragma unroll
    for (int s = 0; s < 3; ++s)
        if (ksrcR[s])
            *reinterpret_cast<uint4*>(
                &KsS[stRow[s] * 64 + ((stCh[s] ^ (stRow[s] & 7)) * 8)]) = kw[s];
    __syncthreads();

    // ---- compute (swapped QK^T, P in regs, Vt b128 B-frags) ----
    f32x4 acc[4];
    #pragma unroll
    for (int dt = 0; dt < 4; ++dt) acc[dt] = (f32x4){0.f, 0.f, 0.f, 0.f};
    float s_sum = 0.f;

    int src0 = lr + ((lg & 1) * 2) * 16;
    int src1 = src0 + 16;
    bool hi = (lg >> 1) != 0;

    for (int kb = 0; kb < 5; ++kb) {
        bf16x8 kf[2][2];
        #pragma unroll
        for (int kvt = 0; kvt < 2; ++kvt)
            #pragma unroll
            for (int ks = 0; ks < 2; ++ks) {
                int row = kb * 32 + kvt * 16 + lr;
                int pr = (row < KVW) ? row : 128;
                int phys = (ks * 4 + lg) ^ (pr & 7);
                kf[kvt][ks] = *reinterpret_cast<const bf16x8*>(&KsS[pr * 64 + phys * 8]);
            }
        __builtin_amdgcn_s_setprio(1);
        unsigned pk[2][2];
        #pragma unroll
        for (int kvt = 0; kvt < 2; ++kvt) {
            f32x4 sf = __builtin_amdgcn_mfma_f32_16x16x32_bf16(
                kf[kvt][0], qf[0], (f32x4){0.f,0.f,0.f,0.f}, 0, 0, 0);
            sf = __builtin_amdgcn_mfma_f32_16x16x32_bf16(kf[kvt][1], qf[1], sf, 0, 0, 0);
            float e[4];
            #pragma unroll
            for (int r = 0; r < 4; ++r) {
                int kv = kb * 32 + kvt * 16 + lg * 4 + r;
                e[r] = (kv < KVW) ? __expf(sf[r] * SCALE) : 0.f;
                s_sum += e[r];
            }
            pk[kvt][0] = pk2(e[0], e[1]);
            pk[kvt][1] = pk2(e[2], e[3]);
        }
        unsigned a00 = __shfl(pk[0][0], src0), a01 = __shfl(pk[0][1], src0);
        unsigned a10 = __shfl(pk[1][0], src0), a11 = __shfl(pk[1][1], src0);
        unsigned b00 = __shfl(pk[0][0], src1), b01 = __shfl(pk[0][1], src1);
        unsigned b10 = __shfl(pk[1][0], src1), b11 = __shfl(pk[1][1], src1);
        union { unsigned u[4]; bf16x8 v; } pu;
        pu.u[0] = hi ? a10 : a00;
        pu.u[1] = hi ? a11 : a01;
        pu.u[2] = hi ? b10 : b00;
        pu.u[3] = hi ? b11 : b01;
        #pragma unroll
        for (int dt = 0; dt < 4; ++dt) {
            bf16x8 vf = *reinterpret_cast<const bf16x8*>(
                &VtS[(dt * 16 + lr) * 168 + kb * 32 + lg * 8]);
            acc[dt] = __builtin_amdgcn_mfma_f32_16x16x32_bf16(pu.v, vf, acc[dt], 0, 0, 0);
        }
        __builtin_amdgcn_s_setprio(0);
    }

    s_sum += __shfl_xor(s_sum, 16);
    s_sum += __shfl_xor(s_sum, 32);
    float sinv[4];
    #pragma unroll
    for (int r = 0; r < 4; ++r)
        sinv[r] = 1.f / __shfl(s_sum, lg * 4 + r);

    // ---- store O as bf16 (halves write traffic + reduce's read traffic) ----
    #pragma unroll
    for (int r = 0; r < 4; ++r) {
        int row = w * 16 + lg * 4 + r;
        unsigned short* op = so + (((size_t)blk * WSZW + row) * DD);
        #pragma unroll
        for (int dt = 0; dt < 4; ++dt) {
            float ov = acc[dt][r] * sinv[r];
            op[dt * 16 + lr] = (unsigned short)(pk2(ov, ov) & 0xFFFFu);
        }
    }
}

// ---------------- Kernel F: fused scan + CSR fill + aux, shfl-scan, 1024 thr ---
__global__ __launch_bounds__(1024) void scanfill_kernel(
    const int* __restrict__ counts, int* __restrict__ offs,
    const int* __restrict__ idxQ, int* __restrict__ csr,
    const float* __restrict__ auxp, float* __restrict__ out)
{
    __shared__ int offsL[TT];
    __shared__ int curL[TT];
    __shared__ int wsum[16];
    __shared__ float auxW[16];

    int bh = blockIdx.x;
    int t = threadIdx.x;
    int lane = t & 63, w = t >> 6;           // 16 waves

    // ---- aux fold (loads only on block 0; uniform barriers) ----
    float s = 0.f;
    if (bh == 0)
        for (int i = t; i < 4096; i += 1024) s += auxp[i];
    #pragma unroll
    for (int off = 32; off; off >>= 1) s += __shfl_xor(s, off);
    if (lane == 0) auxW[w] = s;
    __syncthreads();
    if (bh == 0 && t == 0) {
        float a = 0.f;
        #pragma unroll
        for (int i = 0; i < 16; ++i) a += auxW[i];
        out[(size_t)BB * HH * TT * DD] =
            a * (1.0f / (float)(BB * HH * 2 * TT * DD));
    }

    // ---- exclusive scan over counts[bh] via shfl (2 barriers total) ----
    const int* cb = counts + (size_t)bh * TT;
    int* ob = offs + (size_t)bh * TT;
    int loc[4]; int sum = 0;
    #pragma unroll
    for (int i = 0; i < 4; ++i) { loc[i] = sum; sum += cb[t * 4 + i]; }
    // wave-inclusive scan of per-thread sums
    int incl = sum;
    #pragma unroll
    for (int off = 1; off < 64; off <<= 1) {
        int o = __shfl_up(incl, off);
        if (lane >= off) incl += o;
    }
    if (lane == 63) wsum[w] = incl;          // wave totals
    __syncthreads();
    if (t < 16) {                            // wave 0: exclusive scan of 16 totals
        int v2 = wsum[t];
        int inc2 = v2;
        #pragma unroll
        for (int off = 1; off < 16; off <<= 1) {
            int o = __shfl_up(inc2, off);
            if (t >= off) inc2 += o;
        }
        wsum[t] = inc2 - v2;                 // exclusive
    }
    __syncthreads();
    int ex = wsum[w] + incl - sum;           // thread's exclusive prefix
    #pragma unroll
    for (int i = 0; i < 4; ++i) {
        int o = ex + loc[i];
        ob[t * 4 + i] = o;
        offsL[t * 4 + i] = o;
        curL[t * 4 + i] = 0;
    }
    __syncthreads();

    // ---- CSR fill (LDS atomics) ----
    const int* iq = idxQ + ((size_t)bh << 13);
    int* cs = csr + ((size_t)bh << 13);
    for (int i = t; i < 8192; i += 1024) {
        int tok = iq[i];
        int p = offsL[tok] + atomicAdd(&curL[tok], 1);
        cs[p] = i;
    }
}

// ---------------- Kernel H: gather-reduce (bf16 so), pair-batched + XCD swz ----
__global__ __launch_bounds__(256) void reduce_kernel(
    const unsigned short* __restrict__ so, const int* __restrict__ counts,
    const int* __restrict__ offs, const int* __restrict__ csr,
    float* __restrict__ out)
{
    int b0 = blockIdx.x;
    int b = (b0 & 7) * 4096 + (b0 >> 3);     // 32768 % 8 == 0 -> bijective
    int gt = b * 4 + (threadIdx.x >> 6);
    int lane = threadIdx.x & 63;
    int bh = gt >> 12;
    int n = counts[gt];
    int st = offs[gt];
    const int* cs = csr + ((size_t)bh << 13);
    const unsigned short* sob = so + (((size_t)bh << 13) * DD);
    float acc = 0.f;
    int j = 0;
    for (; j + 2 <= n; j += 2) {             // pair-batched: 2 idx, then 2 rows
        int s0 = cs[st + j], s1 = cs[st + j + 1];
        float v0 = bf2f(sob[(size_t)s0 * DD + lane]);
        float v1 = bf2f(sob[(size_t)s1 * DD + lane]);
        acc += v0 + v1;
    }
    if (j < n) acc += bf2f(sob[(size_t)cs[st + j] * DD + lane]);
    out[(size_t)gt * DD + lane] = acc / ((float)n + EPSF);
}

extern "C" void kernel_launch(void* const* d_in, const int* in_sizes, int n_in,
                              void* d_out, int out_size, void* d_ws, size_t ws_size,
                              hipStream_t stream) {
    const float* q        = (const float*)d_in[0];
    const float* k        = (const float*)d_in[1];
    const float* v        = (const float*)d_in[2];
    const float* means    = (const float*)d_in[3];
    const float* mem_key  = (const float*)d_in[4];
    const float* mem_val  = (const float*)d_in[5];
    float* out = (float*)d_out;

    const size_t nRows = (size_t)BB * HH * NCC;             // 2048
    const size_t nTok  = (size_t)BB * HH * TT;              // 131072
    const size_t nDist = (size_t)BB * HH * NCC * TT;        // 16777216
    unsigned short* distsQ = (unsigned short*)d_ws;         // bf16, 16.7M
    unsigned short* distsK = distsQ + nDist;                // bf16, 16.7M (contiguous)
    unsigned short* so     = distsQ;                        // bf16, aliases dists (written after rescore)
    int*   idxQ   = (int*)(distsK + nDist);                 // 262144 i
    int*   idxK   = idxQ + nRows * WSZW;                    // 262144 i
    int*   counts = idxK + nRows * WSZW;                    // 131072 i (zeroed in dists_kernel)
    float* auxp   = (float*)(counts + nTok);                // 4096 f (per-block partials)
    int*   offs   = (int*)(auxp + 4096);                    // 131072 i
    int*   csr    = offs + nTok;                            // 262144 i
    int*   candQ  = csr + nTok * 2;                         // 2048*160 i
    int*   candK  = candQ + nRows * TPK;                    // 2048*160 i (contiguous after candQ)
    uintptr_t ip  = (uintptr_t)(candK + nRows * TPK);
    ip = (ip + 15) & ~(uintptr_t)15;
    double* invn  = (double*)ip;                            // 2*131072 d (Q then K)

    dists_kernel<<<dim3(BB * HH * (2 * TT / 64)), dim3(256), 0, stream>>>(
        q, k, means, distsQ, distsK, auxp, invn, counts);
    // single launch covers Q rows (0..2047 over distsQ/candQ) and K rows
    // (2048..4095 over distsK/candK) via buffer contiguity
    topk_kernel<<<dim3((unsigned)(2 * nRows)), dim3(512), 0, stream>>>(distsQ, candQ);
    rescore_kernel<<<dim3((unsigned)(2 * nRows)), dim3(640), 0, stream>>>(
        q, k, means, invn, candQ, candK, idxQ, idxK, counts);
    scanfill_kernel<<<dim3(BB * HH), dim3(1024), 0, stream>>>(
        counts, offs, idxQ, csr, auxp, out);
    attn_kernel<<<dim3((unsigned)nRows), dim3(512), 0, stream>>>(
        q, k, v, mem_key, mem_val, idxQ, idxK, so);
    reduce_kernel<<<dim3((unsigned)(nTok / 4)), dim3(256), 0, stream>>>(
        so, counts, offs, csr, out);
}

// Round 27
// 160.116 us; speedup vs baseline: 1.6826x; 1.0257x over previous
//
#include <hip/hip_runtime.h>
#include <math.h>

#define BB 4
#define HH 8
#define TT 4096
#define DD 64
#define NCC 64
#define WSZW 128
#define TPK 160          // widened bf16 top-k; f64 rescore picks exact top-128
#define MEMN 1
#define KVW (MEMN + WSZW)   // 129
constexpr float EPSF = 1e-5f;
constexpr float SCALE = 0.125f;  // 64^-0.5

typedef __attribute__((ext_vector_type(8))) short bf16x8;
typedef __attribute__((ext_vector_type(4))) float f32x4;

// HW packed f32->bf16 (RNE), 1 instruction vs ~7 for the manual bit-twiddle
static __device__ __forceinline__ unsigned int pk2(float a, float b) {
    unsigned int r;
    asm("v_cvt_pk_bf16_f32 %0, %1, %2" : "=v"(r) : "v"(a), "v"(b));
    return r;
}
static __device__ __forceinline__ bf16x8 pack8(float4 a, float4 b) {
    union { unsigned int u[4]; bf16x8 v; } r;
    r.u[0] = pk2(a.x, a.y); r.u[1] = pk2(a.z, a.w);
    r.u[2] = pk2(b.x, b.y); r.u[3] = pk2(b.z, b.w);
    return r.v;
}
static __device__ __forceinline__ unsigned mono16(unsigned u) {
    return (u ^ ((u & 0x8000u) ? 0xFFFFu : 0x8000u)) & 0xFFFFu;
}
static __device__ __forceinline__ unsigned long long mono64(double d) {
    unsigned long long b = (unsigned long long)__double_as_longlong(d);
    return b ^ (((long long)b < 0) ? ~0ULL : 0x8000000000000000ULL);
}
static __device__ __forceinline__ float bf2f(unsigned short u) {
    return __uint_as_float(((unsigned)u) << 16);
}

// ---------------- Kernel A: dists via split-bf16 MFMA -> bf16 dists ------------
__global__ __launch_bounds__(256, 4) void dists_kernel(
    const float* __restrict__ q, const float* __restrict__ k,
    const float* __restrict__ means,
    unsigned short* __restrict__ distsQ, unsigned short* __restrict__ distsK,
    float* __restrict__ aux_part, double* __restrict__ invn,
    int* __restrict__ counts)
{
    __shared__ __align__(16) unsigned short mhS[64 * 64];   // [c][d] swizzled chunks
    __shared__ __align__(16) unsigned short mlS[64 * 64];
    __shared__ __align__(16) unsigned short xhS[64 * 64];   // [tok][d]
    __shared__ __align__(16) unsigned short xlS[64 * 64];
    __shared__ float mqS[64];      // per-cluster ||m||^2
    __shared__ float ssnS[64];     // per-token ||xn||^2
    __shared__ float wMaxS[64 * 5];
    __shared__ int   wIdxS[64 * 5];

    const int chunks = (2 * TT) / 64;          // 128
    int bid0 = blockIdx.x;                     // 4096
    int bid = (bid0 & 7) * 512 + (bid0 >> 3);  // XCD-contiguous (4096 % 8 == 0)
    int bh = bid / chunks;
    int chunk = bid % chunks;
    int h = bh % HH;
    bool isQ = chunk < (TT / 64);
    int tbase = (isQ ? chunk : chunk - 64) * 64;
    const float* src = (isQ ? q : k) + ((size_t)bh * TT + tbase) * DD;
    unsigned short* dst = isQ ? distsQ : distsK;
    double* invdst = invn + (isQ ? 0 : (size_t)BB * HH * TT) + (size_t)bh * TT + tbase;

    int tid = threadIdx.x;

    // zero counts (replaces host memset): 4096 blocks x 32 ints = 131072
    if (tid < 32) counts[(size_t)bid0 * 32 + tid] = 0;

    int row = tid >> 2, part = tid & 3;        // row = cluster idx AND token idx

    // ---- stage means hi/lo (swizzled) + ||m||^2 ----
    {
        const float* mp = means + ((size_t)h * NCC + row) * DD + part * 16;
        float f[16];
        float msq = 0.f;
        #pragma unroll
        for (int i = 0; i < 4; ++i) {
            float4 va = *(const float4*)(mp + i * 4);
            f[i*4] = va.x; f[i*4+1] = va.y; f[i*4+2] = va.z; f[i*4+3] = va.w;
            msq += va.x*va.x + va.y*va.y + va.z*va.z + va.w*va.w;
        }
        msq += __shfl_xor(msq, 1);
        msq += __shfl_xor(msq, 2);
        if (part == 0) mqS[row] = msq;
        #pragma unroll
        for (int cc = 0; cc < 2; ++cc) {
            unsigned hw[4], lw[4];
            #pragma unroll
            for (int j2 = 0; j2 < 4; ++j2) {
                float a = f[cc*8 + j2*2], b = f[cc*8 + j2*2 + 1];
                unsigned p = pk2(a, b);
                float ha = __uint_as_float(p << 16);
                float hb = __uint_as_float(p & 0xFFFF0000u);
                hw[j2] = p; lw[j2] = pk2(a - ha, b - hb);
            }
            int ch = part * 2 + cc;
            int phys = ch ^ (row & 7);
            *reinterpret_cast<uint4*>(&mhS[row * 64 + phys * 8]) = (uint4){hw[0],hw[1],hw[2],hw[3]};
            *reinterpret_cast<uint4*>(&mlS[row * 64 + phys * 8]) = (uint4){lw[0],lw[1],lw[2],lw[3]};
        }
    }
    // ---- stage xn hi/lo (swizzled); f64 norm -> invn + ssn ----
    {
        const float* xp = src + (size_t)row * DD + part * 16;
        float f[16];
        double ssd = 0.0;
        #pragma unroll
        for (int i = 0; i < 4; ++i) {
            float4 va = *(const float4*)(xp + i * 4);
            f[i*4] = va.x; f[i*4+1] = va.y; f[i*4+2] = va.z; f[i*4+3] = va.w;
            ssd += (double)va.x*va.x + (double)va.y*va.y
                 + (double)va.z*va.z + (double)va.w*va.w;
        }
        ssd += __shfl_xor(ssd, 1);
        ssd += __shfl_xor(ssd, 2);
        double invd = 1.0 / fmax(sqrt(ssd), 1e-12);
        if (part == 0) {
            invdst[row] = invd;
            ssnS[row] = (float)(ssd * invd * invd);
        }
        float inv = (float)invd;
        #pragma unroll
        for (int i = 0; i < 16; ++i) f[i] *= inv;
        #pragma unroll
        for (int cc = 0; cc < 2; ++cc) {
            unsigned hw[4], lw[4];
            #pragma unroll
            for (int j2 = 0; j2 < 4; ++j2) {
                float a = f[cc*8 + j2*2], b = f[cc*8 + j2*2 + 1];
                unsigned p = pk2(a, b);
                float ha = __uint_as_float(p << 16);
                float hb = __uint_as_float(p & 0xFFFF0000u);
                hw[j2] = p; lw[j2] = pk2(a - ha, b - hb);
            }
            int ch = part * 2 + cc;
            int phys = ch ^ (row & 7);
            *reinterpret_cast<uint4*>(&xhS[row * 64 + phys * 8]) = (uint4){hw[0],hw[1],hw[2],hw[3]};
            *reinterpret_cast<uint4*>(&xlS[row * 64 + phys * 8]) = (uint4){lw[0],lw[1],lw[2],lw[3]};
        }
    }
    __syncthreads();

    int l = tid & 63, w = tid >> 6;
    int lr = l & 15, lg = l >> 4;

    // ---- A frags: cluster tile w (reused across all 4 token tiles) ----
    bf16x8 mhF[2], mlF[2];
    #pragma unroll
    for (int ks = 0; ks < 2; ++ks) {
        int r2 = w * 16 + lr;
        int phys = (ks * 4 + lg) ^ (r2 & 7);
        mhF[ks] = *reinterpret_cast<const bf16x8*>(&mhS[r2 * 64 + phys * 8]);
        mlF[ks] = *reinterpret_cast<const bf16x8*>(&mlS[r2 * 64 + phys * 8]);
    }

    // ---- GEMM: D[c = w*16+lg*4+r][tok = tt*16+lr], 6 mfma per token tile ----
    f32x4 accT[4];
    size_t rowb = (size_t)(bh * NCC) * TT;
    #pragma unroll
    for (int tt = 0; tt < 4; ++tt) {
        bf16x8 xhF[2], xlF[2];
        #pragma unroll
        for (int ks = 0; ks < 2; ++ks) {
            int r2 = tt * 16 + lr;
            int phys = (ks * 4 + lg) ^ (r2 & 7);
            xhF[ks] = *reinterpret_cast<const bf16x8*>(&xhS[r2 * 64 + phys * 8]);
            xlF[ks] = *reinterpret_cast<const bf16x8*>(&xlS[r2 * 64 + phys * 8]);
        }
        f32x4 a = (f32x4){0.f, 0.f, 0.f, 0.f};
        #pragma unroll
        for (int ks = 0; ks < 2; ++ks)
            a = __builtin_amdgcn_mfma_f32_16x16x32_bf16(mhF[ks], xhF[ks], a, 0, 0, 0);
        #pragma unroll
        for (int ks = 0; ks < 2; ++ks)
            a = __builtin_amdgcn_mfma_f32_16x16x32_bf16(mhF[ks], xlF[ks], a, 0, 0, 0);
        #pragma unroll
        for (int ks = 0; ks < 2; ++ks)
            a = __builtin_amdgcn_mfma_f32_16x16x32_bf16(mlF[ks], xhF[ks], a, 0, 0, 0);
        accT[tt] = a;
        #pragma unroll
        for (int r2 = 0; r2 < 4; ++r2) {
            int c = w * 16 + lg * 4 + r2;
            dst[rowb + (size_t)c * TT + tbase + tt * 16 + lr] =
                (unsigned short)(pk2(a[r2], a[r2]) & 0xFFFFu);
        }
    }

    // ---- argmax via shuffles (lane: token tt*16+lr, clusters w*16+lg*4+r) ----
    #pragma unroll
    for (int tt = 0; tt < 4; ++tt) {
        float bv = accT[tt][0]; int bc = w * 16 + lg * 4;
        #pragma unroll
        for (int r2 = 1; r2 < 4; ++r2)
            if (accT[tt][r2] > bv) { bv = accT[tt][r2]; bc = w * 16 + lg * 4 + r2; }
        #pragma unroll
        for (int off = 16; off <= 32; off <<= 1) {
            float ov = __shfl_xor(bv, off);
            int   oc = __shfl_xor(bc, off);
            if (ov > bv || (ov == bv && oc < bc)) { bv = ov; bc = oc; }
        }
        if (lg == 0) {
            wMaxS[(tt * 16 + lr) * 5 + w] = bv;
            wIdxS[(tt * 16 + lr) * 5 + w] = bc;
        }
    }
    __syncthreads();

    if (tid < 64) {
        float bv = -1e30f; int bc = 0;
        #pragma unroll
        for (int w2 = 0; w2 < 4; ++w2) {   // ascending cluster ranges
            float ov = wMaxS[tid * 5 + w2];
            int   oc = wIdxS[tid * 5 + w2];
            if (ov > bv || (ov == bv && oc < bc)) { bv = ov; bc = oc; }
        }
        float auxv = ssnS[tid] + mqS[bc] - 2.f * bv;
        #pragma unroll
        for (int off = 32; off; off >>= 1) auxv += __shfl_xor(auxv, off);
        if (tid == 0) aux_part[bid] = auxv;
    }
}

// ---------------- Kernel B: top-TPK per row, bf16 keys, 512 thr, 2-pass --------
__global__ __launch_bounds__(512) void topk_kernel(
    const unsigned short* __restrict__ dists, int* __restrict__ idxOut)
{
    int row = blockIdx.x;
    const unsigned short* dv = dists + (size_t)row * TT;
    int t = threadIdx.x;
    int lane = t & 63, w = t >> 6;            // 8 waves

    unsigned u[8];
    {
        uint4 a = *(const uint4*)(dv + t * 8);
        unsigned ws[4] = {a.x, a.y, a.z, a.w};
        #pragma unroll
        for (int i = 0; i < 4; ++i) {
            u[i*2]   = mono16(ws[i] & 0xFFFFu);
            u[i*2+1] = mono16(ws[i] >> 16);
        }
    }

    __shared__ int hist[4096];
    __shared__ int wtot[8];
    __shared__ int binSel, tgtS;
    __shared__ int nGtS, posS, eqPos;

    int target = TPK;

    // ---- pass 1: top 12 bits over 4096 bins ----
    {
        int4* hz = (int4*)&hist[t * 8];
        hz[0] = (int4){0,0,0,0}; hz[1] = (int4){0,0,0,0};
        __syncthreads();
        #pragma unroll
        for (int j = 0; j < 8; ++j) atomicAdd(&hist[u[j] >> 4], 1);
        __syncthreads();
        int cnt[8], ls[8];
        {
            const int4* hp = (const int4*)&hist[t * 8];
            int4 c0 = hp[0], c1 = hp[1];
            cnt[0]=c0.x; cnt[1]=c0.y; cnt[2]=c0.z; cnt[3]=c0.w;
            cnt[4]=c1.x; cnt[5]=c1.y; cnt[6]=c1.z; cnt[7]=c1.w;
        }
        int run = 0;
        #pragma unroll
        for (int i = 7; i >= 0; --i) { run += cnt[i]; ls[i] = run; }
        int S = run;
        #pragma unroll
        for (int off = 1; off < 64; off <<= 1) {
            int o = __shfl_down(S, off);
            if (lane + off < 64) S += o;
        }
        if (lane == 0) wtot[w] = S;
        __syncthreads();
        int after = 0;
        for (int ww = w + 1; ww < 8; ++ww) after += wtot[ww];
        int St1 = S - run + after;
        #pragma unroll
        for (int i = 0; i < 8; ++i) {
            int sfxb = ls[i] + St1;
            if (sfxb >= target && sfxb - cnt[i] < target) {
                binSel = t * 8 + i; tgtS = target - (sfxb - cnt[i]);
            }
        }
        __syncthreads();
    }
    unsigned prefix12 = (unsigned)binSel;
    target = tgtS;
    __syncthreads();

    // ---- pass 2: low 4 bits (16 bins, lanes 0-15 of wave 0) ----
    if (t < 16) hist[t] = 0;
    __syncthreads();
    #pragma unroll
    for (int j = 0; j < 8; ++j)
        if ((u[j] >> 4) == prefix12) atomicAdd(&hist[u[j] & 0xF], 1);
    __syncthreads();
    if (t < 16) {
        int cnt = hist[t];
        int S = cnt;
        #pragma unroll
        for (int off = 1; off < 16; off <<= 1) {
            int o = __shfl_down(S, off);
            if (t + off < 16) S += o;
        }
        if (S >= target && S - cnt < target) binSel = t;
    }
    __syncthreads();
    unsigned pivot = (prefix12 << 4) | (unsigned)binSel;

    // ---- epilogue: compact >pivot, then ==pivot (unordered, capped) ----
    if (t == 0) { nGtS = 0; posS = 0; eqPos = 0; }
    __syncthreads();
    int myg = 0;
    #pragma unroll
    for (int j = 0; j < 8; ++j) myg += (u[j] > pivot) ? 1 : 0;
    if (myg) atomicAdd(&nGtS, myg);
    __syncthreads();
    int n_gt = nGtS;
    int n_need = TPK - n_gt;
    int* out = idxOut + (size_t)row * TPK;
    #pragma unroll
    for (int j = 0; j < 8; ++j) {
        if (u[j] > pivot) {
            int p = atomicAdd(&posS, 1);
            out[p] = t * 8 + j;
        } else if (u[j] == pivot) {
            int p = atomicAdd(&eqPos, 1);
            if (p < n_need) out[n_gt + p] = t * 8 + j;
        }
    }
}

// ---------------- Kernel B2: f64 rescore, branchless u32-prefix rank ----------
__global__ __launch_bounds__(640) void rescore_kernel(
    const float* __restrict__ q, const float* __restrict__ k,
    const float* __restrict__ means, const double* __restrict__ invn,
    const int* __restrict__ candQ, const int* __restrict__ candK,
    int* __restrict__ idxQ, int* __restrict__ idxK,
    int* __restrict__ counts)
{
    int bid = blockIdx.x;
    int rid = (bid & 7) * 512 + (bid >> 3);   // 4096 % 8 == 0 -> bijective
    int side = rid >> 11;            // 0=Q, 1=K
    int row = rid & 2047;            // bh*NC + c
    int c = row & (NCC - 1);
    int bh = row >> 6;
    int h = bh % HH;

    const int* cand = (side ? candK : candQ) + (size_t)row * TPK;
    int* outIdx     = (side ? idxK : idxQ) + (size_t)row * WSZW;
    const float* xbase = (side ? k : q) + (size_t)bh * TT * DD;
    const double* invp = invn + (side ? (size_t)BB * HH * TT : 0) + (size_t)bh * TT;

    __shared__ double   mD[DD];
    __shared__ unsigned hiS[TPK];
    __shared__ unsigned loS[TPK];
    __shared__ int      kiS[TPK];

    int tid = threadIdx.x;
    if (tid < DD) mD[tid] = (double)means[((size_t)h * NCC + c) * DD + tid];
    __syncthreads();

    int g = tid >> 2;                // candidate 0..159
    int qt = tid & 3;                // quarter-row 0..3
    int tok = cand[g];
    const float* xp = xbase + (size_t)tok * DD + qt * 16;
    double inv = invp[tok];          // 4 lanes same addr -> broadcast
    double d0 = 0.0, d1 = 0.0;
    #pragma unroll
    for (int i = 0; i < 2; ++i) {
        float4 va = *(const float4*)(xp + i * 4);
        int d = qt * 16 + i * 4;
        d0 += (double)va.x * mD[d]   + (double)va.y * mD[d+1]
            + (double)va.z * mD[d+2] + (double)va.w * mD[d+3];
    }
    #pragma unroll
    for (int i = 2; i < 4; ++i) {
        float4 va = *(const float4*)(xp + i * 4);
        int d = qt * 16 + i * 4;
        d1 += (double)va.x * mD[d]   + (double)va.y * mD[d+1]
            + (double)va.z * mD[d+2] + (double)va.w * mD[d+3];
    }
    double dot = d0 + d1;
    dot += __shfl_xor(dot, 1); dot += __shfl_xor(dot, 2);
    double v = dot * inv;            // identical across the 4-lane group
    unsigned long long key = mono64(v);
    unsigned myhi = (unsigned)(key >> 32), mylo = (unsigned)key;
    if (qt == 0) { hiS[g] = myhi; loS[g] = mylo; kiS[g] = tok; }
    __syncthreads();

    // phase 1: branchless rank on 32-bit prefixes (1 LDS b32 read per iter)
    int rk = 0, eq = 0;
    #pragma unroll 8
    for (int i = 0; i < TPK / 4; ++i) {
        unsigned hj = hiS[qt * (TPK / 4) + i];
        rk += (hj > myhi) ? 1 : 0;
        eq += (hj == myhi) ? 1 : 0;
    }
    rk += __shfl_xor(rk, 1); rk += __shfl_xor(rk, 2);
    eq += __shfl_xor(eq, 1); eq += __shfl_xor(eq, 2);

    // phase 2 (rare): exact 64-bit + token recount when hi-prefix ties exist
    if (eq > 1) {
        int rk2 = 0;
        for (int i = 0; i < TPK / 4; ++i) {
            int j = qt * (TPK / 4) + i;
            unsigned hj = hiS[j];
            if (hj > myhi) rk2++;
            else if (hj == myhi) {
                unsigned lj = loS[j];
                if (lj > mylo || (lj == mylo && kiS[j] < tok)) rk2++;
            }
        }
        rk2 += __shfl_xor(rk2, 1); rk2 += __shfl_xor(rk2, 2);
        rk = rk2;
    }

    if (qt == 0 && rk < WSZW) {
        outIdx[rk] = tok;
        if (side == 0) atomicAdd(&counts[bh * TT + tok], 1);
    }
}

// ---------------- Kernel C: fused attn (blocks 0..2047) + scanfill (2048..2079) -
// scanfill has no dependency on attn (both consume rescore outputs), so folding
// it into the same dispatch runs it concurrently on spare CUs, removing the
// 32-block serial bubble. LDS overlaid via raw byte buffer.
__global__ __launch_bounds__(512, 8) void attn_scanfill_kernel(
    const float* __restrict__ q, const float* __restrict__ k, const float* __restrict__ v,
    const float* __restrict__ mem_key, const float* __restrict__ mem_value,
    const int* __restrict__ idxQ, const int* __restrict__ idxK,
    unsigned short* __restrict__ so,
    const int* __restrict__ counts, int* __restrict__ offs, int* __restrict__ csr,
    const float* __restrict__ auxp, float* __restrict__ out)
{
    __shared__ __align__(16) unsigned char smemRaw[38144];
    int bid = blockIdx.x;

    if (bid >= 2048) {
        // ================= scanfill path (512 threads, 8 waves) =================
        int bh = bid - 2048;
        int t = threadIdx.x;
        int lane = t & 63, w = t >> 6;
        int* offsL = (int*)smemRaw;                   // 16384 B
        int* curL  = (int*)(smemRaw + 16384);         // 16384 B
        int* wsum  = (int*)(smemRaw + 32768);         // 32 B
        float* auxW = (float*)(smemRaw + 32800);      // 32 B

        // aux fold (loads only on bh==0; uniform barriers)
        float s = 0.f;
        if (bh == 0)
            for (int i = t; i < 4096; i += 512) s += auxp[i];
        #pragma unroll
        for (int off = 32; off; off >>= 1) s += __shfl_xor(s, off);
        if (lane == 0) auxW[w] = s;
        __syncthreads();
        if (bh == 0 && t == 0) {
            float a = 0.f;
            #pragma unroll
            for (int i = 0; i < 8; ++i) a += auxW[i];
            out[(size_t)BB * HH * TT * DD] =
                a * (1.0f / (float)(BB * HH * 2 * TT * DD));
        }

        // exclusive scan over counts[bh] via shfl
        const int* cb = counts + (size_t)bh * TT;
        int* ob = offs + (size_t)bh * TT;
        int loc[8]; int sum = 0;
        #pragma unroll
        for (int i = 0; i < 8; ++i) { loc[i] = sum; sum += cb[t * 8 + i]; }
        int incl = sum;
        #pragma unroll
        for (int off = 1; off < 64; off <<= 1) {
            int o = __shfl_up(incl, off);
            if (lane >= off) incl += o;
        }
        if (lane == 63) wsum[w] = incl;
        __syncthreads();
        if (t < 8) {
            int v2 = wsum[t];
            int inc2 = v2;
            #pragma unroll
            for (int off = 1; off < 8; off <<= 1) {
                int o = __shfl_up(inc2, off);
                if (t >= off) inc2 += o;
            }
            wsum[t] = inc2 - v2;                 // exclusive
        }
        __syncthreads();
        int ex = wsum[w] + incl - sum;
        #pragma unroll
        for (int i = 0; i < 8; ++i) {
            int o = ex + loc[i];
            ob[t * 8 + i] = o;
            offsL[t * 8 + i] = o;
            curL[t * 8 + i] = 0;
        }
        __syncthreads();

        // CSR fill (LDS atomics)
        const int* iq = idxQ + ((size_t)bh << 13);
        int* cs = csr + ((size_t)bh << 13);
        for (int i = t; i < 8192; i += 512) {
            int tok = iq[i];
            int p = offsL[tok] + atomicAdd(&curL[tok], 1);
            cs[p] = i;
        }
        return;
    }

    // ================= attn path (identical to round-26 passing version) ========
    unsigned short* KsS = (unsigned short*)smemRaw;            // 130*64 = 16640 B
    unsigned short* VtS = (unsigned short*)(smemRaw + 16640);  // 64*168*2 = 21504 B

    // XCD-bijective swizzle (2048 % 8 == 0): 256 consecutive blks per XCD
    int blk = (bid & 7) * 256 + (bid >> 3);
    int c = blk % NCC;
    int bh = blk / NCC;
    int h = bh % HH;

    int tid = threadIdx.x;
    int w = tid >> 6, l = tid & 63;
    int lr = l & 15, lg = l >> 4;

    const float* memK = mem_key   + ((size_t)h * NCC + c) * (MEMN * DD);
    const float* memV = mem_value + ((size_t)h * NCC + c) * (MEMN * DD);

    // ---- entry: resolve staging rows + issue ALL token-index gathers ----
    int stRow[3], stCh[3];
    const float *vsrcR[3], *ksrcR[3];
    #pragma unroll
    for (int s = 0; s < 3; ++s) {
        int idx = tid + s * 512;
        stRow[s] = idx >> 3; stCh[s] = idx & 7;
        vsrcR[s] = nullptr; ksrcR[s] = nullptr;
        if (idx < 1280 && stRow[s] < KVW) {
            if (stRow[s] == 0) { vsrcR[s] = memV; ksrcR[s] = memK; }
            else {
                int tk = idxK[(size_t)blk * WSZW + stRow[s] - 1];
                vsrcR[s] = v + ((size_t)bh * TT + tk) * DD;
                ksrcR[s] = k + ((size_t)bh * TT + tk) * DD;
            }
        }
    }

    // ---- Q frags (independent chase, overlaps everything) ----
    bf16x8 qf[2];
    {
        int tq = idxQ[(size_t)blk * WSZW + w * 16 + lr];
        const float* qp = q + ((size_t)bh * TT + tq) * DD;
        #pragma unroll
        for (int ks = 0; ks < 2; ++ks) {
            float4 a = *(const float4*)(qp + ks * 32 + lg * 8);
            float4 b = *(const float4*)(qp + ks * 32 + lg * 8 + 4);
            qf[ks] = pack8(a, b);
        }
    }

    // ---- V gather window (batched) ----
    uint4 vw[3];
    #pragma unroll
    for (int s = 0; s < 3; ++s) {
        vw[s] = (uint4){0,0,0,0};
        if (vsrcR[s]) {
            float4 a = *(const float4*)(vsrcR[s] + stCh[s] * 8);
            float4 b = *(const float4*)(vsrcR[s] + stCh[s] * 8 + 4);
            vw[s].x = pk2(a.x, a.y); vw[s].y = pk2(a.z, a.w);
            vw[s].z = pk2(b.x, b.y); vw[s].w = pk2(b.z, b.w);
        }
    }
    // ---- K gather window (batched) ----
    uint4 kw[3];
    #pragma unroll
    for (int s = 0; s < 3; ++s) {
        kw[s] = (uint4){0,0,0,0};
        if (ksrcR[s]) {
            float4 a = *(const float4*)(ksrcR[s] + stCh[s] * 8);
            float4 b = *(const float4*)(ksrcR[s] + stCh[s] * 8 + 4);
            kw[s].x = pk2(a.x, a.y); kw[s].y = pk2(a.z, a.w);
            kw[s].z = pk2(b.x, b.y); kw[s].w = pk2(b.z, b.w);
        }
    }

    // ---- P1: V -> row-major swizzled (valid rows only) ----
    #pragma unroll
    for (int s = 0; s < 3; ++s)
        if (vsrcR[s])
            *reinterpret_cast<uint4*>(
                &KsS[stRow[s] * 64 + ((stCh[s] ^ (stRow[s] & 7)) * 8)]) = vw[s];
    __syncthreads();

    // ---- P2: Vt column segments -> regs (clamped rows; broadcast-class) ----
    unsigned short vreg[3][8];
    #pragma unroll
    for (int s = 0; s < 3; ++s) {
        int idx = tid + s * 512;
        if (idx < 1280) {
            int d = idx & 63, rowblk = idx >> 6;
            #pragma unroll
            for (int i = 0; i < 8; ++i) {
                int row = rowblk * 8 + i;
                int pr = (row < KVW) ? row : 128;
                vreg[s][i] = KsS[pr * 64 + (((d >> 3) ^ (pr & 7)) * 8) + (d & 7)];
            }
        }
    }
    __syncthreads();

    // ---- P3: write Vt (b128 rows) + K (valid rows only) ----
    #pragma unroll
    for (int s = 0; s < 3; ++s) {
        int idx = tid + s * 512;
        if (idx < 1280) {
            int d = idx & 63, rowblk = idx >> 6;
            uint4 ow;
            ow.x = (unsigned)vreg[s][0] | ((unsigned)vreg[s][1] << 16);
            ow.y = (unsigned)vreg[s][2] | ((unsigned)vreg[s][3] << 16);
            ow.z = (unsigned)vreg[s][4] | ((unsigned)vreg[s][5] << 16);
            ow.w = (unsigned)vreg[s][6] | ((unsigned)vreg[s][7] << 16);
            *reinterpret_cast<uint4*>(&VtS[d * 168 + rowblk * 8]) = ow;
        }
    }
    #pragma unroll
    for (int s = 0; s < 3; ++s)
        if (ksrcR[s])
            *reinterpret_cast<uint4*>(
                &KsS[stRow[s] * 64 + ((stCh[s] ^ (stRow[s] & 7)) * 8)]) = kw[s];
    __syncthreads();

    // ---- compute (swapped QK^T, P in regs, Vt b128 B-frags) ----
    f32x4 acc[4];
    #pragma unroll
    for (int dt = 0; dt < 4; ++dt) acc[dt] = (f32x4){0.f, 0.f, 0.f, 0.f};
    float s_sum = 0.f;

    int src0 = lr + ((lg & 1) * 2) * 16;
    int src1 = src0 + 16;
    bool hi = (lg >> 1) != 0;

    for (int kb = 0; kb < 5; ++kb) {
        bf16x8 kf[2][2];
        #pragma unroll
        for (int kvt = 0; kvt < 2; ++kvt)
            #pragma unroll
            for (int ks = 0; ks < 2; ++ks) {
                int row = kb * 32 + kvt * 16 + lr;
                int pr = (row < KVW) ? row : 128;
                int phys = (ks * 4 + lg) ^ (pr & 7);
                kf[kvt][ks] = *reinterpret_cast<const bf16x8*>(&KsS[pr * 64 + phys * 8]);
            }
        __builtin_amdgcn_s_setprio(1);
        unsigned pk[2][2];
        #pragma unroll
        for (int kvt = 0; kvt < 2; ++kvt) {
            f32x4 sf = __builtin_amdgcn_mfma_f32_16x16x32_bf16(
                kf[kvt][0], qf[0], (f32x4){0.f,0.f,0.f,0.f}, 0, 0, 0);
            sf = __builtin_amdgcn_mfma_f32_16x16x32_bf16(kf[kvt][1], qf[1], sf, 0, 0, 0);
            float e[4];
            #pragma unroll
            for (int r = 0; r < 4; ++r) {
                int kv = kb * 32 + kvt * 16 + lg * 4 + r;
                e[r] = (kv < KVW) ? __expf(sf[r] * SCALE) : 0.f;
                s_sum += e[r];
            }
            pk[kvt][0] = pk2(e[0], e[1]);
            pk[kvt][1] = pk2(e[2], e[3]);
        }
        unsigned a00 = __shfl(pk[0][0], src0), a01 = __shfl(pk[0][1], src0);
        unsigned a10 = __shfl(pk[1][0], src0), a11 = __shfl(pk[1][1], src0);
        unsigned b00 = __shfl(pk[0][0], src1), b01 = __shfl(pk[0][1], src1);
        unsigned b10 = __shfl(pk[1][0], src1), b11 = __shfl(pk[1][1], src1);
        union { unsigned u[4]; bf16x8 v; } pu;
        pu.u[0] = hi ? a10 : a00;
        pu.u[1] = hi ? a11 : a01;
        pu.u[2] = hi ? b10 : b00;
        pu.u[3] = hi ? b11 : b01;
        #pragma unroll
        for (int dt = 0; dt < 4; ++dt) {
            bf16x8 vf = *reinterpret_cast<const bf16x8*>(
                &VtS[(dt * 16 + lr) * 168 + kb * 32 + lg * 8]);
            acc[dt] = __builtin_amdgcn_mfma_f32_16x16x32_bf16(pu.v, vf, acc[dt], 0, 0, 0);
        }
        __builtin_amdgcn_s_setprio(0);
    }

    s_sum += __shfl_xor(s_sum, 16);
    s_sum += __shfl_xor(s_sum, 32);
    float sinv[4];
    #pragma unroll
    for (int r = 0; r < 4; ++r)
        sinv[r] = 1.f / __shfl(s_sum, lg * 4 + r);

    // ---- store O as bf16 ----
    #pragma unroll
    for (int r = 0; r < 4; ++r) {
        int row = w * 16 + lg * 4 + r;
        unsigned short* op = so + (((size_t)blk * WSZW + row) * DD);
        #pragma unroll
        for (int dt = 0; dt < 4; ++dt) {
            float ov = acc[dt][r] * sinv[r];
            op[dt * 16 + lr] = (unsigned short)(pk2(ov, ov) & 0xFFFFu);
        }
    }
}

// ---------------- Kernel H: gather-reduce (bf16 so), pair-batched + XCD swz ----
__global__ __launch_bounds__(256) void reduce_kernel(
    const unsigned short* __restrict__ so, const int* __restrict__ counts,
    const int* __restrict__ offs, const int* __restrict__ csr,
    float* __restrict__ out)
{
    int b0 = blockIdx.x;
    int b = (b0 & 7) * 4096 + (b0 >> 3);     // 32768 % 8 == 0 -> bijective
    int gt = b * 4 + (threadIdx.x >> 6);
    int lane = threadIdx.x & 63;
    int bh = gt >> 12;
    int n = counts[gt];
    int st = offs[gt];
    const int* cs = csr + ((size_t)bh << 13);
    const unsigned short* sob = so + (((size_t)bh << 13) * DD);
    float acc = 0.f;
    int j = 0;
    for (; j + 2 <= n; j += 2) {             // pair-batched: 2 idx, then 2 rows
        int s0 = cs[st + j], s1 = cs[st + j + 1];
        float v0 = bf2f(sob[(size_t)s0 * DD + lane]);
        float v1 = bf2f(sob[(size_t)s1 * DD + lane]);
        acc += v0 + v1;
    }
    if (j < n) acc += bf2f(sob[(size_t)cs[st + j] * DD + lane]);
    out[(size_t)gt * DD + lane] = acc / ((float)n + EPSF);
}

extern "C" void kernel_launch(void* const* d_in, const int* in_sizes, int n_in,
                              void* d_out, int out_size, void* d_ws, size_t ws_size,
                              hipStream_t stream) {
    const float* q        = (const float*)d_in[0];
    const float* k        = (const float*)d_in[1];
    const float* v        = (const float*)d_in[2];
    const float* means    = (const float*)d_in[3];
    const float* mem_key  = (const float*)d_in[4];
    const float* mem_val  = (const float*)d_in[5];
    float* out = (float*)d_out;

    const size_t nRows = (size_t)BB * HH * NCC;             // 2048
    const size_t nTok  = (size_t)BB * HH * TT;              // 131072
    const size_t nDist = (size_t)BB * HH * NCC * TT;        // 16777216
    unsigned short* distsQ = (unsigned short*)d_ws;         // bf16, 16.7M
    unsigned short* distsK = distsQ + nDist;                // bf16, 16.7M (contiguous)
    unsigned short* so     = distsQ;                        // bf16, aliases dists (written after rescore)
    int*   idxQ   = (int*)(distsK + nDist);                 // 262144 i
    int*   idxK   = idxQ + nRows * WSZW;                    // 262144 i
    int*   counts = idxK + nRows * WSZW;                    // 131072 i (zeroed in dists_kernel)
    float* auxp   = (float*)(counts + nTok);                // 4096 f (per-block partials)
    int*   offs   = (int*)(auxp + 4096);                    // 131072 i
    int*   csr    = offs + nTok;                            // 262144 i
    int*   candQ  = csr + nTok * 2;                         // 2048*160 i
    int*   candK  = candQ + nRows * TPK;                    // 2048*160 i (contiguous after candQ)
    uintptr_t ip  = (uintptr_t)(candK + nRows * TPK);
    ip = (ip + 15) & ~(uintptr_t)15;
    double* invn  = (double*)ip;                            // 2*131072 d (Q then K)

    dists_kernel<<<dim3(BB * HH * (2 * TT / 64)), dim3(256), 0, stream>>>(
        q, k, means, distsQ, distsK, auxp, invn, counts);
    // single launch covers Q rows (0..2047 over distsQ/candQ) and K rows
    // (2048..4095 over distsK/candK) via buffer contiguity
    topk_kernel<<<dim3((unsigned)(2 * nRows)), dim3(512), 0, stream>>>(distsQ, candQ);
    rescore_kernel<<<dim3((unsigned)(2 * nRows)), dim3(640), 0, stream>>>(
        q, k, means, invn, candQ, candK, idxQ, idxK, counts);
    attn_scanfill_kernel<<<dim3((unsigned)(nRows + BB * HH)), dim3(512), 0, stream>>>(
        q, k, v, mem_key, mem_val, idxQ, idxK, so,
        counts, offs, csr, auxp, out);
    reduce_kernel<<<dim3((unsigned)(nTok / 4)), dim3(256), 0, stream>>>(
        so, counts, offs, csr, out);
}

// Round 28
// 159.113 us; speedup vs baseline: 1.6932x; 1.0063x over previous
//
#include <hip/hip_runtime.h>
#include <math.h>

#define BB 4
#define HH 8
#define TT 4096
#define DD 64
#define NCC 64
#define WSZW 128
#define TPK 160          // widened bf16 top-k; f64 rescore picks exact top-128
#define MEMN 1
#define KVW (MEMN + WSZW)   // 129
constexpr float EPSF = 1e-5f;
constexpr float SCALE = 0.125f;  // 64^-0.5

typedef __attribute__((ext_vector_type(8))) short bf16x8;
typedef __attribute__((ext_vector_type(4))) float f32x4;

// HW packed f32->bf16 (RNE), 1 instruction vs ~7 for the manual bit-twiddle
static __device__ __forceinline__ unsigned int pk2(float a, float b) {
    unsigned int r;
    asm("v_cvt_pk_bf16_f32 %0, %1, %2" : "=v"(r) : "v"(a), "v"(b));
    return r;
}
static __device__ __forceinline__ bf16x8 pack8(float4 a, float4 b) {
    union { unsigned int u[4]; bf16x8 v; } r;
    r.u[0] = pk2(a.x, a.y); r.u[1] = pk2(a.z, a.w);
    r.u[2] = pk2(b.x, b.y); r.u[3] = pk2(b.z, b.w);
    return r.v;
}
static __device__ __forceinline__ unsigned mono16(unsigned u) {
    return (u ^ ((u & 0x8000u) ? 0xFFFFu : 0x8000u)) & 0xFFFFu;
}
static __device__ __forceinline__ unsigned long long mono64(double d) {
    unsigned long long b = (unsigned long long)__double_as_longlong(d);
    return b ^ (((long long)b < 0) ? ~0ULL : 0x8000000000000000ULL);
}
static __device__ __forceinline__ float bf2f(unsigned short u) {
    return __uint_as_float(((unsigned)u) << 16);
}

// ---------------- Kernel A: dists via split-bf16 MFMA -> bf16 dists ------------
__global__ __launch_bounds__(256, 4) void dists_kernel(
    const float* __restrict__ q, const float* __restrict__ k,
    const float* __restrict__ means,
    unsigned short* __restrict__ distsQ, unsigned short* __restrict__ distsK,
    float* __restrict__ aux_part, double* __restrict__ invn,
    int* __restrict__ counts)
{
    __shared__ __align__(16) unsigned short mhS[64 * 64];   // [c][d] swizzled chunks
    __shared__ __align__(16) unsigned short mlS[64 * 64];
    __shared__ __align__(16) unsigned short xhS[64 * 64];   // [tok][d]
    __shared__ __align__(16) unsigned short xlS[64 * 64];
    __shared__ float mqS[64];      // per-cluster ||m||^2
    __shared__ float ssnS[64];     // per-token ||xn||^2
    __shared__ float wMaxS[64 * 5];
    __shared__ int   wIdxS[64 * 5];

    const int chunks = (2 * TT) / 64;          // 128
    int bid0 = blockIdx.x;                     // 4096
    int bid = (bid0 & 7) * 512 + (bid0 >> 3);  // XCD-contiguous (4096 % 8 == 0)
    int bh = bid / chunks;
    int chunk = bid % chunks;
    int h = bh % HH;
    bool isQ = chunk < (TT / 64);
    int tbase = (isQ ? chunk : chunk - 64) * 64;
    const float* src = (isQ ? q : k) + ((size_t)bh * TT + tbase) * DD;
    unsigned short* dst = isQ ? distsQ : distsK;
    double* invdst = invn + (isQ ? 0 : (size_t)BB * HH * TT) + (size_t)bh * TT + tbase;

    int tid = threadIdx.x;

    // zero counts (replaces host memset): 4096 blocks x 32 ints = 131072
    if (tid < 32) counts[(size_t)bid0 * 32 + tid] = 0;

    int row = tid >> 2, part = tid & 3;        // row = cluster idx AND token idx

    // ---- stage means hi/lo (swizzled) + ||m||^2 ----
    {
        const float* mp = means + ((size_t)h * NCC + row) * DD + part * 16;
        float f[16];
        float msq = 0.f;
        #pragma unroll
        for (int i = 0; i < 4; ++i) {
            float4 va = *(const float4*)(mp + i * 4);
            f[i*4] = va.x; f[i*4+1] = va.y; f[i*4+2] = va.z; f[i*4+3] = va.w;
            msq += va.x*va.x + va.y*va.y + va.z*va.z + va.w*va.w;
        }
        msq += __shfl_xor(msq, 1);
        msq += __shfl_xor(msq, 2);
        if (part == 0) mqS[row] = msq;
        #pragma unroll
        for (int cc = 0; cc < 2; ++cc) {
            unsigned hw[4], lw[4];
            #pragma unroll
            for (int j2 = 0; j2 < 4; ++j2) {
                float a = f[cc*8 + j2*2], b = f[cc*8 + j2*2 + 1];
                unsigned p = pk2(a, b);
                float ha = __uint_as_float(p << 16);
                float hb = __uint_as_float(p & 0xFFFF0000u);
                hw[j2] = p; lw[j2] = pk2(a - ha, b - hb);
            }
            int ch = part * 2 + cc;
            int phys = ch ^ (row & 7);
            *reinterpret_cast<uint4*>(&mhS[row * 64 + phys * 8]) = (uint4){hw[0],hw[1],hw[2],hw[3]};
            *reinterpret_cast<uint4*>(&mlS[row * 64 + phys * 8]) = (uint4){lw[0],lw[1],lw[2],lw[3]};
        }
    }
    // ---- stage xn hi/lo (swizzled); f64 norm -> invn + ssn ----
    {
        const float* xp = src + (size_t)row * DD + part * 16;
        float f[16];
        double ssd = 0.0;
        #pragma unroll
        for (int i = 0; i < 4; ++i) {
            float4 va = *(const float4*)(xp + i * 4);
            f[i*4] = va.x; f[i*4+1] = va.y; f[i*4+2] = va.z; f[i*4+3] = va.w;
            ssd += (double)va.x*va.x + (double)va.y*va.y
                 + (double)va.z*va.z + (double)va.w*va.w;
        }
        ssd += __shfl_xor(ssd, 1);
        ssd += __shfl_xor(ssd, 2);
        double invd = 1.0 / fmax(sqrt(ssd), 1e-12);
        if (part == 0) {
            invdst[row] = invd;
            ssnS[row] = (float)(ssd * invd * invd);
        }
        float inv = (float)invd;
        #pragma unroll
        for (int i = 0; i < 16; ++i) f[i] *= inv;
        #pragma unroll
        for (int cc = 0; cc < 2; ++cc) {
            unsigned hw[4], lw[4];
            #pragma unroll
            for (int j2 = 0; j2 < 4; ++j2) {
                float a = f[cc*8 + j2*2], b = f[cc*8 + j2*2 + 1];
                unsigned p = pk2(a, b);
                float ha = __uint_as_float(p << 16);
                float hb = __uint_as_float(p & 0xFFFF0000u);
                hw[j2] = p; lw[j2] = pk2(a - ha, b - hb);
            }
            int ch = part * 2 + cc;
            int phys = ch ^ (row & 7);
            *reinterpret_cast<uint4*>(&xhS[row * 64 + phys * 8]) = (uint4){hw[0],hw[1],hw[2],hw[3]};
            *reinterpret_cast<uint4*>(&xlS[row * 64 + phys * 8]) = (uint4){lw[0],lw[1],lw[2],lw[3]};
        }
    }
    __syncthreads();

    int l = tid & 63, w = tid >> 6;
    int lr = l & 15, lg = l >> 4;

    // ---- A frags: cluster tile w (reused across all 4 token tiles) ----
    bf16x8 mhF[2], mlF[2];
    #pragma unroll
    for (int ks = 0; ks < 2; ++ks) {
        int r2 = w * 16 + lr;
        int phys = (ks * 4 + lg) ^ (r2 & 7);
        mhF[ks] = *reinterpret_cast<const bf16x8*>(&mhS[r2 * 64 + phys * 8]);
        mlF[ks] = *reinterpret_cast<const bf16x8*>(&mlS[r2 * 64 + phys * 8]);
    }

    // ---- GEMM: D[c = w*16+lg*4+r][tok = tt*16+lr], 6 mfma per token tile ----
    f32x4 accT[4];
    size_t rowb = (size_t)(bh * NCC) * TT;
    #pragma unroll
    for (int tt = 0; tt < 4; ++tt) {
        bf16x8 xhF[2], xlF[2];
        #pragma unroll
        for (int ks = 0; ks < 2; ++ks) {
            int r2 = tt * 16 + lr;
            int phys = (ks * 4 + lg) ^ (r2 & 7);
            xhF[ks] = *reinterpret_cast<const bf16x8*>(&xhS[r2 * 64 + phys * 8]);
            xlF[ks] = *reinterpret_cast<const bf16x8*>(&xlS[r2 * 64 + phys * 8]);
        }
        f32x4 a = (f32x4){0.f, 0.f, 0.f, 0.f};
        #pragma unroll
        for (int ks = 0; ks < 2; ++ks)
            a = __builtin_amdgcn_mfma_f32_16x16x32_bf16(mhF[ks], xhF[ks], a, 0, 0, 0);
        #pragma unroll
        for (int ks = 0; ks < 2; ++ks)
            a = __builtin_amdgcn_mfma_f32_16x16x32_bf16(mhF[ks], xlF[ks], a, 0, 0, 0);
        #pragma unroll
        for (int ks = 0; ks < 2; ++ks)
            a = __builtin_amdgcn_mfma_f32_16x16x32_bf16(mlF[ks], xhF[ks], a, 0, 0, 0);
        accT[tt] = a;
        #pragma unroll
        for (int r2 = 0; r2 < 4; ++r2) {
            int c = w * 16 + lg * 4 + r2;
            dst[rowb + (size_t)c * TT + tbase + tt * 16 + lr] =
                (unsigned short)(pk2(a[r2], a[r2]) & 0xFFFFu);
        }
    }

    // ---- argmax via shuffles (lane: token tt*16+lr, clusters w*16+lg*4+r) ----
    #pragma unroll
    for (int tt = 0; tt < 4; ++tt) {
        float bv = accT[tt][0]; int bc = w * 16 + lg * 4;
        #pragma unroll
        for (int r2 = 1; r2 < 4; ++r2)
            if (accT[tt][r2] > bv) { bv = accT[tt][r2]; bc = w * 16 + lg * 4 + r2; }
        #pragma unroll
        for (int off = 16; off <= 32; off <<= 1) {
            float ov = __shfl_xor(bv, off);
            int   oc = __shfl_xor(bc, off);
            if (ov > bv || (ov == bv && oc < bc)) { bv = ov; bc = oc; }
        }
        if (lg == 0) {
            wMaxS[(tt * 16 + lr) * 5 + w] = bv;
            wIdxS[(tt * 16 + lr) * 5 + w] = bc;
        }
    }
    __syncthreads();

    if (tid < 64) {
        float bv = -1e30f; int bc = 0;
        #pragma unroll
        for (int w2 = 0; w2 < 4; ++w2) {   // ascending cluster ranges
            float ov = wMaxS[tid * 5 + w2];
            int   oc = wIdxS[tid * 5 + w2];
            if (ov > bv || (ov == bv && oc < bc)) { bv = ov; bc = oc; }
        }
        float auxv = ssnS[tid] + mqS[bc] - 2.f * bv;
        #pragma unroll
        for (int off = 32; off; off >>= 1) auxv += __shfl_xor(auxv, off);
        if (tid == 0) aux_part[bid] = auxv;
    }
}

// ---------------- Kernel B: fused topk (LDS candidates) + f64 rescore ----------
// Per block = one (side,row): 2-pass 12/4 radix topk writes the 160-candidate
// set to LDS, then the exact f64 rescore runs in the same block (512 threads,
// 4 lanes/candidate in 2 passes of 128+32 groups). Removes the full-grid
// barrier between topk and rescore + the candidate global round-trip.
__global__ __launch_bounds__(512) void topk_rescore_kernel(
    const unsigned short* __restrict__ dists,
    const float* __restrict__ q, const float* __restrict__ k,
    const float* __restrict__ means, const double* __restrict__ invn,
    int* __restrict__ idxQ, int* __restrict__ idxK,
    int* __restrict__ counts)
{
    int bid = blockIdx.x;
    int rid = (bid & 7) * 512 + (bid >> 3);   // 4096 % 8 == 0 -> bijective
    int side = rid >> 11;            // 0=Q, 1=K
    int row = rid & 2047;            // bh*NC + c
    int c = row & (NCC - 1);
    int bh = row >> 6;
    int h = bh % HH;

    const unsigned short* dv = dists + ((size_t)side * 2048 + row) * TT;
    int* outIdx = (side ? idxK : idxQ) + (size_t)row * WSZW;
    const float* xbase = (side ? k : q) + (size_t)bh * TT * DD;
    const double* invp = invn + (side ? (size_t)BB * HH * TT : 0) + (size_t)bh * TT;

    __shared__ int hist[4096];
    __shared__ int wtot[8];
    __shared__ int binSel, tgtS;
    __shared__ int nGtS, posS, eqPos;
    __shared__ int candL[TPK];
    __shared__ double   mD[DD];
    __shared__ unsigned hiS[TPK];
    __shared__ unsigned loS[TPK];
    __shared__ int      kiS[TPK];

    int t = threadIdx.x;
    int lane = t & 63, w = t >> 6;            // 8 waves

    // stage means f64 early (covered by topk barriers before first use)
    if (t < DD) mD[t] = (double)means[((size_t)h * NCC + c) * DD + t];

    unsigned u[8];
    {
        uint4 a = *(const uint4*)(dv + t * 8);
        unsigned ws[4] = {a.x, a.y, a.z, a.w};
        #pragma unroll
        for (int i = 0; i < 4; ++i) {
            u[i*2]   = mono16(ws[i] & 0xFFFFu);
            u[i*2+1] = mono16(ws[i] >> 16);
        }
    }

    int target = TPK;

    // ---- pass 1: top 12 bits over 4096 bins ----
    {
        int4* hz = (int4*)&hist[t * 8];
        hz[0] = (int4){0,0,0,0}; hz[1] = (int4){0,0,0,0};
        __syncthreads();
        #pragma unroll
        for (int j = 0; j < 8; ++j) atomicAdd(&hist[u[j] >> 4], 1);
        __syncthreads();
        int cnt[8], ls[8];
        {
            const int4* hp = (const int4*)&hist[t * 8];
            int4 c0 = hp[0], c1 = hp[1];
            cnt[0]=c0.x; cnt[1]=c0.y; cnt[2]=c0.z; cnt[3]=c0.w;
            cnt[4]=c1.x; cnt[5]=c1.y; cnt[6]=c1.z; cnt[7]=c1.w;
        }
        int run = 0;
        #pragma unroll
        for (int i = 7; i >= 0; --i) { run += cnt[i]; ls[i] = run; }
        int S = run;
        #pragma unroll
        for (int off = 1; off < 64; off <<= 1) {
            int o = __shfl_down(S, off);
            if (lane + off < 64) S += o;
        }
        if (lane == 0) wtot[w] = S;
        __syncthreads();
        int after = 0;
        for (int ww = w + 1; ww < 8; ++ww) after += wtot[ww];
        int St1 = S - run + after;
        #pragma unroll
        for (int i = 0; i < 8; ++i) {
            int sfxb = ls[i] + St1;
            if (sfxb >= target && sfxb - cnt[i] < target) {
                binSel = t * 8 + i; tgtS = target - (sfxb - cnt[i]);
            }
        }
        __syncthreads();
    }
    unsigned prefix12 = (unsigned)binSel;
    target = tgtS;
    __syncthreads();

    // ---- pass 2: low 4 bits (16 bins, lanes 0-15 of wave 0) ----
    if (t < 16) hist[t] = 0;
    __syncthreads();
    #pragma unroll
    for (int j = 0; j < 8; ++j)
        if ((u[j] >> 4) == prefix12) atomicAdd(&hist[u[j] & 0xF], 1);
    __syncthreads();
    if (t < 16) {
        int cnt = hist[t];
        int S = cnt;
        #pragma unroll
        for (int off = 1; off < 16; off <<= 1) {
            int o = __shfl_down(S, off);
            if (t + off < 16) S += o;
        }
        if (S >= target && S - cnt < target) binSel = t;
    }
    __syncthreads();
    unsigned pivot = (prefix12 << 4) | (unsigned)binSel;

    // ---- epilogue: compact candidates into LDS ----
    if (t == 0) { nGtS = 0; posS = 0; eqPos = 0; }
    __syncthreads();
    int myg = 0;
    #pragma unroll
    for (int j = 0; j < 8; ++j) myg += (u[j] > pivot) ? 1 : 0;
    if (myg) atomicAdd(&nGtS, myg);
    __syncthreads();
    int n_gt = nGtS;
    int n_need = TPK - n_gt;
    #pragma unroll
    for (int j = 0; j < 8; ++j) {
        if (u[j] > pivot) {
            int p = atomicAdd(&posS, 1);
            candL[p] = t * 8 + j;
        } else if (u[j] == pivot) {
            int p = atomicAdd(&eqPos, 1);
            if (p < n_need) candL[n_gt + p] = t * 8 + j;
        }
    }
    __syncthreads();

    // ---- rescore: f64 dot, 4 lanes/candidate, 2 passes (128 + 32 groups) ----
    int qt = t & 3;
    #pragma unroll
    for (int base = 0; base < TPK; base += 128) {
        int g = base + (t >> 2);
        if (g < TPK) {
            int tok = candL[g];
            const float* xp = xbase + (size_t)tok * DD + qt * 16;
            double inv = invp[tok];
            double d0 = 0.0, d1 = 0.0;
            #pragma unroll
            for (int i = 0; i < 2; ++i) {
                float4 va = *(const float4*)(xp + i * 4);
                int d = qt * 16 + i * 4;
                d0 += (double)va.x * mD[d]   + (double)va.y * mD[d+1]
                    + (double)va.z * mD[d+2] + (double)va.w * mD[d+3];
            }
            #pragma unroll
            for (int i = 2; i < 4; ++i) {
                float4 va = *(const float4*)(xp + i * 4);
                int d = qt * 16 + i * 4;
                d1 += (double)va.x * mD[d]   + (double)va.y * mD[d+1]
                    + (double)va.z * mD[d+2] + (double)va.w * mD[d+3];
            }
            double dot = d0 + d1;
            dot += __shfl_xor(dot, 1); dot += __shfl_xor(dot, 2);
            double vv = dot * inv;
            unsigned long long key = mono64(vv);
            if (qt == 0) {
                hiS[g] = (unsigned)(key >> 32);
                loS[g] = (unsigned)key;
                kiS[g] = tok;
            }
        }
    }
    __syncthreads();

    // ---- rank (branchless u32 prefixes; rare exact fallback) ----
    #pragma unroll
    for (int base = 0; base < TPK; base += 128) {
        int g = base + (t >> 2);
        if (g < TPK) {
            unsigned myhi = hiS[g], mylo = loS[g];
            int tok = kiS[g];
            int rk = 0, eq = 0;
            #pragma unroll 8
            for (int i = 0; i < TPK / 4; ++i) {
                unsigned hj = hiS[qt * (TPK / 4) + i];
                rk += (hj > myhi) ? 1 : 0;
                eq += (hj == myhi) ? 1 : 0;
            }
            rk += __shfl_xor(rk, 1); rk += __shfl_xor(rk, 2);
            eq += __shfl_xor(eq, 1); eq += __shfl_xor(eq, 2);
            if (eq > 1) {
                int rk2 = 0;
                for (int i = 0; i < TPK / 4; ++i) {
                    int j = qt * (TPK / 4) + i;
                    unsigned hj = hiS[j];
                    if (hj > myhi) rk2++;
                    else if (hj == myhi) {
                        unsigned lj = loS[j];
                        if (lj > mylo || (lj == mylo && kiS[j] < tok)) rk2++;
                    }
                }
                rk2 += __shfl_xor(rk2, 1); rk2 += __shfl_xor(rk2, 2);
                rk = rk2;
            }
            if (qt == 0 && rk < WSZW) {
                outIdx[rk] = tok;
                if (side == 0) atomicAdd(&counts[bh * TT + tok], 1);
            }
        }
    }
}

// ---------------- Kernel C: fused attn (blocks 0..2047) + scanfill (2048..2079) -
__global__ __launch_bounds__(512, 8) void attn_scanfill_kernel(
    const float* __restrict__ q, const float* __restrict__ k, const float* __restrict__ v,
    const float* __restrict__ mem_key, const float* __restrict__ mem_value,
    const int* __restrict__ idxQ, const int* __restrict__ idxK,
    unsigned short* __restrict__ so,
    const int* __restrict__ counts, int* __restrict__ offs, int* __restrict__ csr,
    const float* __restrict__ auxp, float* __restrict__ out)
{
    __shared__ __align__(16) unsigned char smemRaw[38144];
    int bid = blockIdx.x;

    if (bid >= 2048) {
        // ================= scanfill path (512 threads, 8 waves) =================
        int bh = bid - 2048;
        int t = threadIdx.x;
        int lane = t & 63, w = t >> 6;
        int* offsL = (int*)smemRaw;                   // 16384 B
        int* curL  = (int*)(smemRaw + 16384);         // 16384 B
        int* wsum  = (int*)(smemRaw + 32768);         // 32 B
        float* auxW = (float*)(smemRaw + 32800);      // 32 B

        // aux fold (loads only on bh==0; uniform barriers)
        float s = 0.f;
        if (bh == 0)
            for (int i = t; i < 4096; i += 512) s += auxp[i];
        #pragma unroll
        for (int off = 32; off; off >>= 1) s += __shfl_xor(s, off);
        if (lane == 0) auxW[w] = s;
        __syncthreads();
        if (bh == 0 && t == 0) {
            float a = 0.f;
            #pragma unroll
            for (int i = 0; i < 8; ++i) a += auxW[i];
            out[(size_t)BB * HH * TT * DD] =
                a * (1.0f / (float)(BB * HH * 2 * TT * DD));
        }

        // exclusive scan over counts[bh] via shfl
        const int* cb = counts + (size_t)bh * TT;
        int* ob = offs + (size_t)bh * TT;
        int loc[8]; int sum = 0;
        #pragma unroll
        for (int i = 0; i < 8; ++i) { loc[i] = sum; sum += cb[t * 8 + i]; }
        int incl = sum;
        #pragma unroll
        for (int off = 1; off < 64; off <<= 1) {
            int o = __shfl_up(incl, off);
            if (lane >= off) incl += o;
        }
        if (lane == 63) wsum[w] = incl;
        __syncthreads();
        if (t < 8) {
            int v2 = wsum[t];
            int inc2 = v2;
            #pragma unroll
            for (int off = 1; off < 8; off <<= 1) {
                int o = __shfl_up(inc2, off);
                if (t >= off) inc2 += o;
            }
            wsum[t] = inc2 - v2;                 // exclusive
        }
        __syncthreads();
        int ex = wsum[w] + incl - sum;
        #pragma unroll
        for (int i = 0; i < 8; ++i) {
            int o = ex + loc[i];
            ob[t * 8 + i] = o;
            offsL[t * 8 + i] = o;
            curL[t * 8 + i] = 0;
        }
        __syncthreads();

        // CSR fill (LDS atomics)
        const int* iq = idxQ + ((size_t)bh << 13);
        int* cs = csr + ((size_t)bh << 13);
        for (int i = t; i < 8192; i += 512) {
            int tok = iq[i];
            int p = offsL[tok] + atomicAdd(&curL[tok], 1);
            cs[p] = i;
        }
        return;
    }

    // ================= attn path ================================================
    unsigned short* KsS = (unsigned short*)smemRaw;            // 130*64 = 16640 B
    unsigned short* VtS = (unsigned short*)(smemRaw + 16640);  // 64*168*2 = 21504 B

    // XCD-bijective swizzle (2048 % 8 == 0): 256 consecutive blks per XCD
    int blk = (bid & 7) * 256 + (bid >> 3);
    int c = blk % NCC;
    int bh = blk / NCC;
    int h = bh % HH;

    int tid = threadIdx.x;
    int w = tid >> 6, l = tid & 63;
    int lr = l & 15, lg = l >> 4;

    const float* memK = mem_key   + ((size_t)h * NCC + c) * (MEMN * DD);
    const float* memV = mem_value + ((size_t)h * NCC + c) * (MEMN * DD);

    // ---- entry: resolve staging rows + issue ALL token-index gathers ----
    int stRow[3], stCh[3];
    const float *vsrcR[3], *ksrcR[3];
    #pragma unroll
    for (int s = 0; s < 3; ++s) {
        int idx = tid + s * 512;
        stRow[s] = idx >> 3; stCh[s] = idx & 7;
        vsrcR[s] = nullptr; ksrcR[s] = nullptr;
        if (idx < 1280 && stRow[s] < KVW) {
            if (stRow[s] == 0) { vsrcR[s] = memV; ksrcR[s] = memK; }
            else {
                int tk = idxK[(size_t)blk * WSZW + stRow[s] - 1];
                vsrcR[s] = v + ((size_t)bh * TT + tk) * DD;
                ksrcR[s] = k + ((size_t)bh * TT + tk) * DD;
            }
        }
    }

    // ---- Q frags (independent chase, overlaps everything) ----
    bf16x8 qf[2];
    {
        int tq = idxQ[(size_t)blk * WSZW + w * 16 + lr];
        const float* qp = q + ((size_t)bh * TT + tq) * DD;
        #pragma unroll
        for (int ks = 0; ks < 2; ++ks) {
            float4 a = *(const float4*)(qp + ks * 32 + lg * 8);
            float4 b = *(const float4*)(qp + ks * 32 + lg * 8 + 4);
            qf[ks] = pack8(a, b);
        }
    }

    // ---- V gather window (batched) ----
    uint4 vw[3];
    #pragma unroll
    for (int s = 0; s < 3; ++s) {
        vw[s] = (uint4){0,0,0,0};
        if (vsrcR[s]) {
            float4 a = *(const float4*)(vsrcR[s] + stCh[s] * 8);
            float4 b = *(const float4*)(vsrcR[s] + stCh[s] * 8 + 4);
            vw[s].x = pk2(a.x, a.y); vw[s].y = pk2(a.z, a.w);
            vw[s].z = pk2(b.x, b.y); vw[s].w = pk2(b.z, b.w);
        }
    }
    // ---- K gather window (batched) ----
    uint4 kw[3];
    #pragma unroll
    for (int s = 0; s < 3; ++s) {
        kw[s] = (uint4){0,0,0,0};
        if (ksrcR[s]) {
            float4 a = *(const float4*)(ksrcR[s] + stCh[s] * 8);
            float4 b = *(const float4*)(ksrcR[s] + stCh[s] * 8 + 4);
            kw[s].x = pk2(a.x, a.y); kw[s].y = pk2(a.z, a.w);
            kw[s].z = pk2(b.x, b.y); kw[s].w = pk2(b.z, b.w);
        }
    }

    // ---- P1: V -> row-major swizzled (valid rows only) ----
    #pragma unroll
    for (int s = 0; s < 3; ++s)
        if (vsrcR[s])
            *reinterpret_cast<uint4*>(
                &KsS[stRow[s] * 64 + ((stCh[s] ^ (stRow[s] & 7)) * 8)]) = vw[s];
    __syncthreads();

    // ---- P2: Vt column segments -> regs (clamped rows; broadcast-class) ----
    unsigned short vreg[3][8];
    #pragma unroll
    for (int s = 0; s < 3; ++s) {
        int idx = tid + s * 512;
        if (idx < 1280) {
            int d = idx & 63, rowblk = idx >> 6;
            #pragma unroll
            for (int i = 0; i < 8; ++i) {
                int row = rowblk * 8 + i;
                int pr = (row < KVW) ? row : 128;
                vreg[s][i] = KsS[pr * 64 + (((d >> 3) ^ (pr & 7)) * 8) + (d & 7)];
            }
        }
    }
    __syncthreads();

    // ---- P3: write Vt (b128 rows) + K (valid rows only) ----
    #pragma unroll
    for (int s = 0; s < 3; ++s) {
        int idx = tid + s * 512;
        if (idx < 1280) {
            int d = idx & 63, rowblk = idx >> 6;
            uint4 ow;
            ow.x = (unsigned)vreg[s][0] | ((unsigned)vreg[s][1] << 16);
            ow.y = (unsigned)vreg[s][2] | ((unsigned)vreg[s][3] << 16);
            ow.z = (unsigned)vreg[s][4] | ((unsigned)vreg[s][5] << 16);
            ow.w = (unsigned)vreg[s][6] | ((unsigned)vreg[s][7] << 16);
            *reinterpret_cast<uint4*>(&VtS[d * 168 + rowblk * 8]) = ow;
        }
    }
    #pragma unroll
    for (int s = 0; s < 3; ++s)
        if (ksrcR[s])
            *reinterpret_cast<uint4*>(
                &KsS[stRow[s] * 64 + ((stCh[s] ^ (stRow[s] & 7)) * 8)]) = kw[s];
    __syncthreads();

    // ---- compute (swapped QK^T, P in regs, Vt b128 B-frags) ----
    f32x4 acc[4];
    #pragma unroll
    for (int dt = 0; dt < 4; ++dt) acc[dt] = (f32x4){0.f, 0.f, 0.f, 0.f};
    float s_sum = 0.f;

    int src0 = lr + ((lg & 1) * 2) * 16;
    int src1 = src0 + 16;
    bool hi = (lg >> 1) != 0;

    for (int kb = 0; kb < 5; ++kb) {
        bf16x8 kf[2][2];
        #pragma unroll
        for (int kvt = 0; kvt < 2; ++kvt)
            #pragma unroll
            for (int ks = 0; ks < 2; ++ks) {
                int row = kb * 32 + kvt * 16 + lr;
                int pr = (row < KVW) ? row : 128;
                int phys = (ks * 4 + lg) ^ (pr & 7);
                kf[kvt][ks] = *reinterpret_cast<const bf16x8*>(&KsS[pr * 64 + phys * 8]);
            }
        __builtin_amdgcn_s_setprio(1);
        unsigned pk[2][2];
        #pragma unroll
        for (int kvt = 0; kvt < 2; ++kvt) {
            f32x4 sf = __builtin_amdgcn_mfma_f32_16x16x32_bf16(
                kf[kvt][0], qf[0], (f32x4){0.f,0.f,0.f,0.f}, 0, 0, 0);
            sf = __builtin_amdgcn_mfma_f32_16x16x32_bf16(kf[kvt][1], qf[1], sf, 0, 0, 0);
            float e[4];
            #pragma unroll
            for (int r = 0; r < 4; ++r) {
                int kv = kb * 32 + kvt * 16 + lg * 4 + r;
                e[r] = (kv < KVW) ? __expf(sf[r] * SCALE) : 0.f;
                s_sum += e[r];
            }
            pk[kvt][0] = pk2(e[0], e[1]);
            pk[kvt][1] = pk2(e[2], e[3]);
        }
        unsigned a00 = __shfl(pk[0][0], src0), a01 = __shfl(pk[0][1], src0);
        unsigned a10 = __shfl(pk[1][0], src0), a11 = __shfl(pk[1][1], src0);
        unsigned b00 = __shfl(pk[0][0], src1), b01 = __shfl(pk[0][1], src1);
        unsigned b10 = __shfl(pk[1][0], src1), b11 = __shfl(pk[1][1], src1);
        union { unsigned u[4]; bf16x8 v; } pu;
        pu.u[0] = hi ? a10 : a00;
        pu.u[1] = hi ? a11 : a01;
        pu.u[2] = hi ? b10 : b00;
        pu.u[3] = hi ? b11 : b01;
        #pragma unroll
        for (int dt = 0; dt < 4; ++dt) {
            bf16x8 vf = *reinterpret_cast<const bf16x8*>(
                &VtS[(dt * 16 + lr) * 168 + kb * 32 + lg * 8]);
            acc[dt] = __builtin_amdgcn_mfma_f32_16x16x32_bf16(pu.v, vf, acc[dt], 0, 0, 0);
        }
        __builtin_amdgcn_s_setprio(0);
    }

    s_sum += __shfl_xor(s_sum, 16);
    s_sum += __shfl_xor(s_sum, 32);
    float sinv[4];
    #pragma unroll
    for (int r = 0; r < 4; ++r)
        sinv[r] = 1.f / __shfl(s_sum, lg * 4 + r);

    // ---- store O as bf16 ----
    #pragma unroll
    for (int r = 0; r < 4; ++r) {
        int row = w * 16 + lg * 4 + r;
        unsigned short* op = so + (((size_t)blk * WSZW + row) * DD);
        #pragma unroll
        for (int dt = 0; dt < 4; ++dt) {
            float ov = acc[dt][r] * sinv[r];
            op[dt * 16 + lr] = (unsigned short)(pk2(ov, ov) & 0xFFFFu);
        }
    }
}

// ---------------- Kernel H: gather-reduce (bf16 so), pair-batched + XCD swz ----
__global__ __launch_bounds__(256) void reduce_kernel(
    const unsigned short* __restrict__ so, const int* __restrict__ counts,
    const int* __restrict__ offs, const int* __restrict__ csr,
    float* __restrict__ out)
{
    int b0 = blockIdx.x;
    int b = (b0 & 7) * 4096 + (b0 >> 3);     // 32768 % 8 == 0 -> bijective
    int gt = b * 4 + (threadIdx.x >> 6);
    int lane = threadIdx.x & 63;
    int bh = gt >> 12;
    int n = counts[gt];
    int st = offs[gt];
    const int* cs = csr + ((size_t)bh << 13);
    const unsigned short* sob = so + (((size_t)bh << 13) * DD);
    float acc = 0.f;
    int j = 0;
    for (; j + 2 <= n; j += 2) {             // pair-batched: 2 idx, then 2 rows
        int s0 = cs[st + j], s1 = cs[st + j + 1];
        float v0 = bf2f(sob[(size_t)s0 * DD + lane]);
        float v1 = bf2f(sob[(size_t)s1 * DD + lane]);
        acc += v0 + v1;
    }
    if (j < n) acc += bf2f(sob[(size_t)cs[st + j] * DD + lane]);
    out[(size_t)gt * DD + lane] = acc / ((float)n + EPSF);
}

extern "C" void kernel_launch(void* const* d_in, const int* in_sizes, int n_in,
                              void* d_out, int out_size, void* d_ws, size_t ws_size,
                              hipStream_t stream) {
    const float* q        = (const float*)d_in[0];
    const float* k        = (const float*)d_in[1];
    const float* v        = (const float*)d_in[2];
    const float* means    = (const float*)d_in[3];
    const float* mem_key  = (const float*)d_in[4];
    const float* mem_val  = (const float*)d_in[5];
    float* out = (float*)d_out;

    const size_t nRows = (size_t)BB * HH * NCC;             // 2048
    const size_t nTok  = (size_t)BB * HH * TT;              // 131072
    const size_t nDist = (size_t)BB * HH * NCC * TT;        // 16777216
    unsigned short* distsQ = (unsigned short*)d_ws;         // bf16, 16.7M (distsK contiguous after)
    unsigned short* distsK = distsQ + nDist;
    unsigned short* so     = distsQ;                        // bf16, aliases dists (written after rescore)
    int*   idxQ   = (int*)(distsK + nDist);                 // 262144 i
    int*   idxK   = idxQ + nRows * WSZW;                    // 262144 i
    int*   counts = idxK + nRows * WSZW;                    // 131072 i (zeroed in dists_kernel)
    float* auxp   = (float*)(counts + nTok);                // 4096 f (per-block partials)
    int*   offs   = (int*)(auxp + 4096);                    // 131072 i
    int*   csr    = offs + nTok;                            // 262144 i
    uintptr_t ip  = (uintptr_t)(csr + nTok * 2);
    ip = (ip + 15) & ~(uintptr_t)15;
    double* invn  = (double*)ip;                            // 2*131072 d (Q then K)

    dists_kernel<<<dim3(BB * HH * (2 * TT / 64)), dim3(256), 0, stream>>>(
        q, k, means, distsQ, distsK, auxp, invn, counts);
    topk_rescore_kernel<<<dim3((unsigned)(2 * nRows)), dim3(512), 0, stream>>>(
        distsQ, q, k, means, invn, idxQ, idxK, counts);
    attn_scanfill_kernel<<<dim3((unsigned)(nRows + BB * HH)), dim3(512), 0, stream>>>(
        q, k, v, mem_key, mem_val, idxQ, idxK, so,
        counts, offs, csr, auxp, out);
    reduce_kernel<<<dim3((unsigned)(nTok / 4)), dim3(256), 0, stream>>>(
        so, counts, offs, csr, out);
}